// Round 8
// baseline (1282.249 us; speedup 1.0000x reference)
//
#include <hip/hip_runtime.h>
#include <stdint.h>

#define Bc 512
#define Lc 128
#define Kc 6
#define AFc 39
#define BFc 10
#define FPc 200
#define Rc 3
#define Tc 2
constexpr int BL = Bc * Lc;          // 65536
constexpr int KP = 224;              // padded K / F for MFMA
constexpr float SLOPE = 0.01f;
constexpr float NEGC = -9e8f;

typedef __attribute__((ext_vector_type(8))) __bf16 bf16x8;
typedef __attribute__((ext_vector_type(16))) float f32x16;

__device__ __forceinline__ float leaky(float x) { return x >= 0.f ? x : SLOPE * x; }
__device__ __forceinline__ float sigm(float x) { return 1.f / (1.f + __expf(-x)); }
__device__ __forceinline__ float eluf(float x) { return x > 0.f ? x : expm1f(x); }
__device__ __forceinline__ float wave_sum(float v) {
  #pragma unroll
  for (int m = 32; m >= 1; m >>= 1) v += __shfl_xor(v, m);
  return v;
}
__device__ __forceinline__ float bflo(uint32_t u) { return __uint_as_float(u << 16); }
__device__ __forceinline__ float bfhi(uint32_t u) { return __uint_as_float(u & 0xffff0000u); }
__device__ __forceinline__ unsigned short f2bu(float x) {
  __bf16 b = (__bf16)x;
  return __builtin_bit_cast(unsigned short, b);
}
__device__ __forceinline__ void glds16(const void* g, void* l) {
  __builtin_amdgcn_global_load_lds((const __attribute__((address_space(1))) uint32_t*)g,
      (__attribute__((address_space(3))) uint32_t*)l, 16, 0, 0);
}
__device__ __forceinline__ f32x16 zero16() {
  f32x16 z;
  #pragma unroll
  for (int i = 0; i < 16; ++i) z[i] = 0.f;
  return z;
}

// -------------------- weight transpose: out[c*R + r] = in[r*C + c] --------------------
__global__ void transpose_k(const float* __restrict__ in, float* __restrict__ out, int R, int C) {
  int n = R * C;
  for (int i = blockIdx.x * blockDim.x + threadIdx.x; i < n; i += gridDim.x * blockDim.x) {
    int r = i / C, c = i - r * C;
    out[c * R + r] = in[i];
  }
}

// -------------------- pack GRU weights into staging-linear tiles ---------------------
__global__ void pack_gru_k(const float* __restrict__ Wih, const float* __restrict__ Whh,
                           __bf16* __restrict__ Wpk) {
  int i = blockIdx.x * 256 + threadIdx.x;
  if (i >= Rc * 6 * 7 * 7 * 1024) return;
  int j = i & 7, fl = (i >> 3) & 31, c = (i >> 8) & 3;
  int T = i >> 10;
  int kt = T % 7; T /= 7;
  int ft = T % 7; T /= 7;
  int g = T % 6;  int r = T / 6;
  int f = ft * 32 + fl, k = kt * 32 + c * 8 + j;
  float v = 0.f;
  if (f < FPc && k < FPc) {
    if (g < 3) v = Wih[((size_t)r * 3 * FPc + g * FPc + f) * FPc + k];
    else       v = Whh[((size_t)r * 3 * FPc + (g - 3) * FPc + f) * FPc + k];
  }
  Wpk[i] = (__bf16)v;
}

// Apk layout: [r][ft7][kt7]{1024: [c4][f32][j8]}
__global__ void pack_att_k(const float* __restrict__ W, __bf16* __restrict__ Apk) {
  int i = blockIdx.x * 256 + threadIdx.x;
  if (i >= Rc * 7 * 7 * 1024) return;
  int j = i & 7, fl = (i >> 3) & 31, c = (i >> 8) & 3;
  int T = i >> 10;
  int kt = T % 7; T /= 7;
  int ft = T % 7; int r = T / 7;
  int f = ft * 32 + fl, k = kt * 32 + c * 8 + j;
  float v = (f < FPc && k < FPc) ? W[((size_t)r * FPc + f) * FPc + k] : 0.f;
  Apk[i] = (__bf16)v;
}

// -------------------- generic small GEMM (f32): Y[rows][200] ------------------------
template<int KD, int EPI>
__global__ __launch_bounds__(256) void gemm8x1(
    const float* __restrict__ X, const float* __restrict__ WT,
    const float* __restrict__ bias, const float* __restrict__ sumw,
    float* __restrict__ Y, __bf16* __restrict__ Yb) {
  constexpr int TR = 8, LDP = 12;
  __shared__ float xT[KD * LDP];
  const int row0 = blockIdx.x * TR;
  const int tid = threadIdx.x;
  for (int e = tid; e < TR * KD; e += 256) {
    int r = e / KD, g = e - r * KD;
    xT[g * LDP + r] = X[(size_t)row0 * KD + e];
  }
  __syncthreads();
  const int f = tid;
  if (f < FPc) {
    float acc[TR];
    #pragma unroll
    for (int r = 0; r < TR; ++r) acc[r] = 0.f;
    #pragma unroll 4
    for (int g = 0; g < KD; ++g) {
      float w = WT[(size_t)g * FPc + f];
      float4 x0 = *reinterpret_cast<const float4*>(&xT[g * LDP]);
      float4 x1 = *reinterpret_cast<const float4*>(&xT[g * LDP + 4]);
      acc[0] = fmaf(x0.x, w, acc[0]); acc[1] = fmaf(x0.y, w, acc[1]);
      acc[2] = fmaf(x0.z, w, acc[2]); acc[3] = fmaf(x0.w, w, acc[3]);
      acc[4] = fmaf(x1.x, w, acc[4]); acc[5] = fmaf(x1.y, w, acc[5]);
      acc[6] = fmaf(x1.z, w, acc[6]); acc[7] = fmaf(x1.w, w, acc[7]);
    }
    #pragma unroll
    for (int r = 0; r < TR; ++r) {
      if (EPI == 0) {
        Yb[(size_t)(row0 + r) * FPc + f] = (__bf16)acc[r];
      } else if (EPI == 1) {
        float v = acc[r] + bias[f];
        Y[(size_t)(row0 + r) * FPc + f] = v;                 // raw atom_lin (viz)
        Yb[(size_t)(row0 + r) * KP + f] = (__bf16)leaky(v);  // h0
      } else {
        float v = fmaf(sumw[row0 + r], bias[f], acc[r]);
        Y[(size_t)(row0 + r) * FPc + f] = eluf(v);
      }
    }
  } else if (EPI == 1 && f < KP) {
    #pragma unroll
    for (int r = 0; r < TR; ++r) Yb[(size_t)(row0 + r) * KP + f] = (__bf16)0.f;
  }
}

// -------------------- fused attend + GRU: barrier-free, LDS transpose ----------------
// block = 256 thr (4 waves x 32 rows = 128 rows). LDS = xc transpose buf 57344 B.
// attend: WN frags in regs, Apk B direct from L2, epilogue -> LDS in gru A-frag layout.
// gru: xc frags from LDS, h frags + B tiles direct from global/L2. No barriers at all
// (LDS regions are per-wave disjoint: wave writes+reads only its own 32-row group).
__global__ __launch_bounds__(256, 2) void attgru_mfma(
    const __bf16* __restrict__ WNb, const __bf16* __restrict__ Apk,
    const float* __restrict__ attb, const float* __restrict__ SW,
    const __bf16* __restrict__ Hin, __bf16* __restrict__ Hout,
    const __bf16* __restrict__ Wpk,
    const float* __restrict__ bih, const float* __restrict__ bhh,
    float* __restrict__ actOut) {
  __shared__ __align__(16) __bf16 xcL[28672];    // [wv4][kt7][1024] = 57344 B
  const int tid = threadIdx.x, wv = tid >> 6, lane = tid & 63;
  const size_t row0 = (size_t)blockIdx.x * 128;
  const int fl = lane & 31;

  // ---- attend phase: xc = elu(WN @ attW.T + sumw*b) -> LDS (A-frag layout) ----
  {
    bf16x8 af[7][2];
    const __bf16* sw_ = WNb + (row0 + wv * 32 + fl) * KP + (lane >> 5) * 8;
    #pragma unroll
    for (int kt = 0; kt < 7; ++kt)
      #pragma unroll
      for (int h = 0; h < 2; ++h)
        af[kt][h] = *(const bf16x8*)(sw_ + kt * 32 + h * 16);

    // write offset for (row rl, k=f): (k>>5)*1024 + ((k>>4)&1)*512 + ((k>>3)&1)*256 + rl*8 + (k&7)
    const int xbase = wv * 7168 + ((fl >> 4) & 1) * 512 + ((fl >> 3) & 1) * 256 + (fl & 7);
    #pragma unroll
    for (int ft = 0; ft < 7; ++ft) {
      f32x16 acc = zero16();
      #pragma unroll
      for (int kt = 0; kt < 7; ++kt) {
        const __bf16* bt = Apk + ((size_t)ft * 7 + kt) * 1024 + lane * 8;
        bf16x8 b0 = *(const bf16x8*)(bt);
        bf16x8 b1 = *(const bf16x8*)(bt + 512);
        acc = __builtin_amdgcn_mfma_f32_32x32x16_bf16(af[kt][0], b0, acc, 0, 0, 0);
        acc = __builtin_amdgcn_mfma_f32_32x32x16_bf16(af[kt][1], b1, acc, 0, 0, 0);
      }
      const int f = ft * 32 + fl;
      const bool fok = f < FPc;
      const float bf = fok ? attb[f] : 0.f;
      #pragma unroll
      for (int reg = 0; reg < 16; ++reg) {
        int rl = (reg & 3) + 8 * (reg >> 2) + 4 * (lane >> 5);
        float v = fok ? eluf(acc[reg] + SW[row0 + wv * 32 + rl] * bf) : 0.f;
        xcL[xbase + ft * 1024 + rl * 8] = (__bf16)v;
      }
    }
  }
  // (no s_barrier: each wave reads back only what it wrote; compiler orders via lgkmcnt)

  // ---- GRU phase ----
  const __bf16* hrow = Hin + (row0 + wv * 32 + fl) * KP + (lane >> 5) * 8;
  #pragma unroll 1
  for (int ft = 0; ft < 7; ++ft) {
    f32x16 gacc[6];
    #pragma unroll
    for (int g = 0; g < 6; ++g) gacc[g] = zero16();
    #pragma unroll
    for (int kt = 0; kt < 7; ++kt) {
      bf16x8 xc0 = *(const bf16x8*)(xcL + wv * 7168 + kt * 1024 + lane * 8);
      bf16x8 xc1 = *(const bf16x8*)(xcL + wv * 7168 + kt * 1024 + 512 + lane * 8);
      bf16x8 h0 = *(const bf16x8*)(hrow + kt * 32);
      bf16x8 h1 = *(const bf16x8*)(hrow + kt * 32 + 16);
      const __bf16* wb = Wpk + ((size_t)ft * 7 + kt) * 1024 + lane * 8;
      #pragma unroll
      for (int h = 0; h < 2; ++h) {
        bf16x8 xch = h ? xc1 : xc0;
        bf16x8 hh = h ? h1 : h0;
        const __bf16* bb = wb + h * 512;
        bf16x8 b0 = *(const bf16x8*)(bb);
        bf16x8 b1 = *(const bf16x8*)(bb + 7 * 7 * 1024);
        bf16x8 b2 = *(const bf16x8*)(bb + 2 * 7 * 7 * 1024);
        bf16x8 b3 = *(const bf16x8*)(bb + 3 * 7 * 7 * 1024);
        bf16x8 b4 = *(const bf16x8*)(bb + 4 * 7 * 7 * 1024);
        bf16x8 b5 = *(const bf16x8*)(bb + 5 * 7 * 7 * 1024);
        gacc[0] = __builtin_amdgcn_mfma_f32_32x32x16_bf16(xch, b0, gacc[0], 0, 0, 0);
        gacc[1] = __builtin_amdgcn_mfma_f32_32x32x16_bf16(xch, b1, gacc[1], 0, 0, 0);
        gacc[2] = __builtin_amdgcn_mfma_f32_32x32x16_bf16(xch, b2, gacc[2], 0, 0, 0);
        gacc[3] = __builtin_amdgcn_mfma_f32_32x32x16_bf16(hh, b3, gacc[3], 0, 0, 0);
        gacc[4] = __builtin_amdgcn_mfma_f32_32x32x16_bf16(hh, b4, gacc[4], 0, 0, 0);
        gacc[5] = __builtin_amdgcn_mfma_f32_32x32x16_bf16(hh, b5, gacc[5], 0, 0, 0);
      }
    }
    const int f = ft * 32 + fl;
    const bool fok = f < FPc;
    float bir = 0, biz = 0, bin_ = 0, bhr = 0, bhz = 0, bhn = 0;
    if (fok) {
      bir = bih[f]; biz = bih[FPc + f]; bin_ = bih[2 * FPc + f];
      bhr = bhh[f]; bhz = bhh[FPc + f]; bhn = bhh[2 * FPc + f];
    }
    #pragma unroll
    for (int reg = 0; reg < 16; ++reg) {
      int rl = (reg & 3) + 8 * (reg >> 2) + 4 * (lane >> 5);
      size_t row = row0 + wv * 32 + rl;
      if (fok) {
        float ho = (float)Hin[row * KP + f];
        float rg_ = sigm(gacc[0][reg] + bir + gacc[3][reg] + bhr);
        float zg  = sigm(gacc[1][reg] + biz + gacc[4][reg] + bhz);
        float ng  = tanhf(gacc[2][reg] + bin_ + rg_ * (gacc[5][reg] + bhn));
        float hp = (1.f - zg) * ng + zg * ho;
        Hout[row * KP + f] = (__bf16)hp;
        actOut[row * FPc + f] = fmaxf(hp, 0.f);
      } else {
        Hout[row * KP + f] = (__bf16)0.f;
      }
    }
  }
}

// -------------------- attn round r>=1: per-molecule block ---------------------------
__global__ __launch_bounds__(256) void attn_molN(
    const __bf16* __restrict__ Hb,       // [BL][KP]
    const int* __restrict__ adl,
    const float* __restrict__ alW,       // +r*2*FP
    const float* __restrict__ albp,      // +r
    float* __restrict__ attnOut, __bf16* __restrict__ WNb, float* __restrict__ SW) {
  __shared__ __align__(16) __bf16 actL[128 * 224];
  __shared__ float saL[128], snL[128];
  const int b = blockIdx.x;
  const int tid = threadIdx.x, wv = tid >> 6, lane = tid & 63;
  const bool l36 = lane < 36;

  {
    const uint4* src = (const uint4*)(Hb + (size_t)b * 128 * KP);
    uint4* dst = (uint4*)actL;
    for (int i = tid; i < 128 * 224 / 8; i += 256) {
      uint4 v = src[i];
      uint32_t c[4] = {v.x, v.y, v.z, v.w};
      #pragma unroll
      for (int j = 0; j < 4; ++j) {
        uint32_t lo = c[j] & 0xffffu, hi = c[j] >> 16;
        if (lo & 0x8000u) lo = 0;
        if (hi & 0x8000u) hi = 0;
        c[j] = lo | (hi << 16);
      }
      dst[i] = make_uint4(c[0], c[1], c[2], c[3]);
    }
  }
  float wa0x = alW[2 * lane], wa0y = alW[2 * lane + 1];
  float wa1x = l36 ? alW[128 + 2 * lane] : 0.f, wa1y = l36 ? alW[129 + 2 * lane] : 0.f;
  float wn0x = alW[FPc + 2 * lane], wn0y = alW[FPc + 2 * lane + 1];
  float wn1x = l36 ? alW[FPc + 128 + 2 * lane] : 0.f, wn1y = l36 ? alW[FPc + 129 + 2 * lane] : 0.f;
  const float ab = albp[0];
  __syncthreads();

  for (int i = 0; i < 32; ++i) {
    int l = wv * 32 + i;
    const uint32_t* rowp = (const uint32_t*)(actL + l * 224);
    uint32_t u0 = rowp[lane];
    uint32_t u1 = l36 ? rowp[64 + lane] : 0u;
    float x0 = bflo(u0), y0 = bfhi(u0), x1 = bflo(u1), y1 = bfhi(u1);
    float psa = x0 * wa0x + y0 * wa0y + x1 * wa1x + y1 * wa1y;
    float psn = x0 * wn0x + y0 * wn0y + x1 * wn1x + y1 * wn1y;
    psa = wave_sum(psa);
    psn = wave_sum(psn);
    if (lane == 0) { saL[l] = psa; snL[l] = psn; }
  }
  __syncthreads();

  for (int i = 0; i < 32; ++i) {
    const int row = wv * 32 + i;
    const size_t grow = (size_t)b * 128 + row;
    int gk = (lane < Kc) ? adl[grow * Kc + lane] : 0;
    int ai[Kc];
    #pragma unroll
    for (int k = 0; k < Kc; ++k) ai[k] = __shfl(gk, k);
    const float sarow = saL[row];
    float s[Kc]; bool pad[Kc]; float mx = -3.0e38f;
    #pragma unroll
    for (int k = 0; k < Kc; ++k) {
      pad[k] = (ai[k] == Lc - 1);
      s[k] = leaky(sarow + snL[ai[k]] + ab) + (pad[k] ? NEGC : 0.f);
      mx = fmaxf(mx, s[k]);
    }
    float e[Kc], sum = 0.f;
    #pragma unroll
    for (int k = 0; k < Kc; ++k) { e[k] = __expf(s[k] - mx); sum += e[k]; }
    float inv = 1.f / sum;
    float w[Kc], sw = 0.f;
    #pragma unroll
    for (int k = 0; k < Kc; ++k) { w[k] = pad[k] ? 0.f : e[k] * inv; sw += w[k]; }
    if (lane < Kc) attnOut[grow * Kc + lane] = w[lane];
    if (lane == 0) SW[grow] = sw;
    float a0 = 0.f, b0 = 0.f, a1 = 0.f, b1 = 0.f;
    #pragma unroll
    for (int k = 0; k < Kc; ++k) {
      const uint32_t* nr = (const uint32_t*)(actL + ai[k] * 224);
      uint32_t u0 = nr[lane];
      uint32_t u1 = l36 ? nr[64 + lane] : 0u;
      a0 = fmaf(w[k], bflo(u0), a0); b0 = fmaf(w[k], bfhi(u0), b0);
      a1 = fmaf(w[k], bflo(u1), a1); b1 = fmaf(w[k], bfhi(u1), b1);
    }
    __bf16* wr = WNb + grow * KP;
    ushort2 o0; o0.x = f2bu(a0); o0.y = f2bu(b0);
    *(ushort2*)(wr + 2 * lane) = o0;
    if (lane < 48) {
      float va = l36 ? a1 : 0.f, vb = l36 ? b1 : 0.f;
      ushort2 o1; o1.x = f2bu(va); o1.y = f2bu(vb);
      *(ushort2*)(wr + 128 + 2 * lane) = o1;
    }
  }
}

// -------------------- attn round r==0: per-molecule block, 8 waves, v-reg cache -----
__global__ __launch_bounds__(512) void attn_mol0(
    const __bf16* __restrict__ Pb, const __bf16* __restrict__ Qb,
    const float* __restrict__ nbb, const __bf16* __restrict__ Hb0,
    const int* __restrict__ adl, const int* __restrict__ bdl,
    const float* __restrict__ alW, const float* __restrict__ albp,
    float* __restrict__ attnOut, __bf16* __restrict__ WNb, float* __restrict__ SW) {
  __shared__ __align__(16) __bf16 Pl[128 * 200];
  __shared__ __align__(16) __bf16 Ql[128 * 200];
  __shared__ float nbbL[200];
  __shared__ float saL[128];
  const int b = blockIdx.x;
  const int tid = threadIdx.x, wv = tid >> 6, lane = tid & 63;
  const bool l36 = lane < 36;

  {
    const uint4* sp = (const uint4*)(Pb + (size_t)b * 128 * FPc);
    const uint4* sq = (const uint4*)(Qb + (size_t)b * 128 * FPc);
    uint4* dp = (uint4*)Pl;
    uint4* dq = (uint4*)Ql;
    for (int i = tid; i < 128 * 200 / 8; i += 512) { dp[i] = sp[i]; dq[i] = sq[i]; }
    for (int i = tid; i < FPc; i += 512) nbbL[i] = nbb[i];
  }
  float wa0x = alW[2 * lane], wa0y = alW[2 * lane + 1];
  float wa1x = l36 ? alW[128 + 2 * lane] : 0.f, wa1y = l36 ? alW[129 + 2 * lane] : 0.f;
  float wn0x = alW[FPc + 2 * lane], wn0y = alW[FPc + 2 * lane + 1];
  float wn1x = l36 ? alW[FPc + 128 + 2 * lane] : 0.f, wn1y = l36 ? alW[FPc + 129 + 2 * lane] : 0.f;
  const float ab = albp[0];

  for (int i = 0; i < 16; ++i) {
    int l = wv * 16 + i;
    const uint32_t* hr = (const uint32_t*)(Hb0 + ((size_t)b * 128 + l) * KP);
    uint32_t u0 = hr[lane];
    uint32_t u1 = l36 ? hr[64 + lane] : 0u;
    float psa = bflo(u0) * wa0x + bfhi(u0) * wa0y + bflo(u1) * wa1x + bfhi(u1) * wa1y;
    psa = wave_sum(psa);
    if (lane == 0) saL[l] = psa;
  }
  __syncthreads();

  const float n0x = nbbL[2 * lane], n0y = nbbL[2 * lane + 1];
  const float n1x = l36 ? nbbL[128 + 2 * lane] : 0.f, n1y = l36 ? nbbL[129 + 2 * lane] : 0.f;

  for (int i = 0; i < 16; ++i) {
    const int row = wv * 16 + i;
    const size_t grow = (size_t)b * 128 + row;
    int gk = (lane < Kc) ? adl[grow * Kc + lane] : 0;
    int hk = (lane < Kc) ? bdl[grow * Kc + lane] : 0;
    int ai[Kc], bi[Kc];
    #pragma unroll
    for (int k = 0; k < Kc; ++k) { ai[k] = __shfl(gk, k); bi[k] = __shfl(hk, k); }
    float v0x[Kc], v0y[Kc], v1x[Kc], v1y[Kc], p[Kc];
    #pragma unroll
    for (int k = 0; k < Kc; ++k) {
      const uint32_t* pr = (const uint32_t*)(Pl + ai[k] * 200);
      const uint32_t* qr = (const uint32_t*)(Ql + bi[k] * 200);
      uint32_t up0 = pr[lane], uq0 = qr[lane];
      uint32_t up1 = l36 ? pr[64 + lane] : 0u, uq1 = l36 ? qr[64 + lane] : 0u;
      v0x[k] = leaky(bflo(up0) + bflo(uq0) + n0x);
      v0y[k] = leaky(bfhi(up0) + bfhi(uq0) + n0y);
      v1x[k] = l36 ? leaky(bflo(up1) + bflo(uq1) + n1x) : 0.f;
      v1y[k] = l36 ? leaky(bfhi(up1) + bfhi(uq1) + n1y) : 0.f;
      p[k] = v0x[k] * wn0x + v0y[k] * wn0y + v1x[k] * wn1x + v1y[k] * wn1y;
    }
    #pragma unroll
    for (int k = 0; k < Kc; ++k) p[k] = wave_sum(p[k]);
    const float sarow = saL[row];
    float s[Kc]; bool pad[Kc]; float mx = -3.0e38f;
    #pragma unroll
    for (int k = 0; k < Kc; ++k) {
      pad[k] = (ai[k] == Lc - 1);
      s[k] = leaky(sarow + p[k] + ab) + (pad[k] ? NEGC : 0.f);
      mx = fmaxf(mx, s[k]);
    }
    float e[Kc], sum = 0.f;
    #pragma unroll
    for (int k = 0; k < Kc; ++k) { e[k] = __expf(s[k] - mx); sum += e[k]; }
    float inv = 1.f / sum;
    float w[Kc], sw = 0.f;
    #pragma unroll
    for (int k = 0; k < Kc; ++k) { w[k] = pad[k] ? 0.f : e[k] * inv; sw += w[k]; }
    if (lane < Kc) attnOut[grow * Kc + lane] = w[lane];
    if (lane == 0) SW[grow] = sw;
    float a0 = 0.f, b0v = 0.f, a1 = 0.f, b1v = 0.f;
    #pragma unroll
    for (int k = 0; k < Kc; ++k) {
      a0  = fmaf(w[k], v0x[k], a0);
      b0v = fmaf(w[k], v0y[k], b0v);
      a1  = fmaf(w[k], v1x[k], a1);
      b1v = fmaf(w[k], v1y[k], b1v);
    }
    __bf16* wr = WNb + grow * KP;
    ushort2 o0; o0.x = f2bu(a0); o0.y = f2bu(b0v);
    *(ushort2*)(wr + 2 * lane) = o0;
    if (lane < 48) {
      float va = l36 ? a1 : 0.f, vb = l36 ? b1v : 0.f;
      ushort2 o1; o1.x = f2bu(va); o1.y = f2bu(vb);
      *(ushort2*)(wr + 128 + 2 * lane) = o1;
    }
  }
}

// -------------------- fused GRU f32 (mol path, 512 rows) -----------------------------
__global__ __launch_bounds__(256) void gru8(
    const float* __restrict__ XC, float* __restrict__ H,
    const float* __restrict__ WihT, const float* __restrict__ WhhT,
    const float* __restrict__ bih, const float* __restrict__ bhh,
    float* __restrict__ actOut, float* __restrict__ unbOut, float* __restrict__ vizOut) {
  constexpr int TR = 8, LDP = 12;
  __shared__ float xc[FPc * LDP];
  __shared__ float xh[FPc * LDP];
  const int row0 = blockIdx.x * TR;
  const int tid = threadIdx.x;
  for (int e = tid; e < TR * FPc; e += 256) {
    int r = e / FPc, g = e - r * FPc;
    xc[g * LDP + r] = XC[(size_t)row0 * FPc + e];
    xh[g * LDP + r] = H[(size_t)row0 * FPc + e];
  }
  __syncthreads();
  const int f = tid;
  if (f < FPc) {
    float air[8], aiz[8], ain[8], ahr[8], ahz[8], ahn[8];
    const float bir = bih[f], biz = bih[f + 200], bin_ = bih[f + 400];
    const float bhr = bhh[f], bhz = bhh[f + 200], bhn = bhh[f + 400];
    #pragma unroll
    for (int r = 0; r < 8; ++r) {
      air[r] = bir; aiz[r] = biz; ain[r] = bin_;
      ahr[r] = bhr; ahz[r] = bhz; ahn[r] = bhn;
    }
    #pragma unroll 2
    for (int g = 0; g < FPc; ++g) {
      const float* wi = &WihT[(size_t)g * 600 + f];
      const float* wh = &WhhT[(size_t)g * 600 + f];
      float wir = wi[0], wiz = wi[200], win = wi[400];
      float whr = wh[0], whz = wh[200], whn = wh[400];
      float4 c0 = *reinterpret_cast<const float4*>(&xc[g * LDP]);
      float4 c1 = *reinterpret_cast<const float4*>(&xc[g * LDP + 4]);
      float4 h0 = *reinterpret_cast<const float4*>(&xh[g * LDP]);
      float4 h1 = *reinterpret_cast<const float4*>(&xh[g * LDP + 4]);
      float cx[8] = {c0.x, c0.y, c0.z, c0.w, c1.x, c1.y, c1.z, c1.w};
      float hx[8] = {h0.x, h0.y, h0.z, h0.w, h1.x, h1.y, h1.z, h1.w};
      #pragma unroll
      for (int r = 0; r < 8; ++r) {
        air[r] = fmaf(cx[r], wir, air[r]);
        aiz[r] = fmaf(cx[r], wiz, aiz[r]);
        ain[r] = fmaf(cx[r], win, ain[r]);
        ahr[r] = fmaf(hx[r], whr, ahr[r]);
        ahz[r] = fmaf(hx[r], whz, ahz[r]);
        ahn[r] = fmaf(hx[r], whn, ahn[r]);
      }
    }
    #pragma unroll
    for (int r = 0; r < 8; ++r) {
      float rg = sigm(air[r] + ahr[r]);
      float zg = sigm(aiz[r] + ahz[r]);
      float ng = tanhf(fmaf(rg, ahn[r], ain[r]));
      float hv = xh[f * LDP + r];
      float hp = (1.f - zg) * ng + zg * hv;
      size_t idx = (size_t)(row0 + r) * FPc + f;
      H[idx] = hp;
      float a = fmaxf(hp, 0.f);
      if (actOut) actOut[idx] = a;
      if (unbOut) unbOut[idx] = hp;
      if (vizOut) vizOut[idx] = a;
    }
  }
}

// -------------------- mol-level sum over atoms ---------------------------------------
__global__ __launch_bounds__(256) void mol_sum_k(
    const __bf16* __restrict__ Hb, const float* __restrict__ ACT, const float* __restrict__ mask,
    float* __restrict__ unb0, float* __restrict__ viz0,
    float* __restrict__ molfeat, float* __restrict__ actmol) {
  const int b = blockIdx.x;
  __shared__ float mk[Lc];
  for (int l = threadIdx.x; l < Lc; l += 256) mk[l] = mask[b * Lc + l];
  __syncthreads();
  const int f = threadIdx.x;
  if (f < FPc) {
    float s1 = 0.f, s2 = 0.f;
    for (int l = 0; l < Lc; ++l) {
      float m = mk[l];
      s1 = fmaf((float)Hb[((size_t)b * Lc + l) * KP + f], m, s1);
      s2 = fmaf(ACT[((size_t)b * Lc + l) * FPc + f], m, s2);
    }
    unb0[b * FPc + f] = s1;
    viz0[b * FPc + f] = s2;
    molfeat[b * FPc + f] = s2;
    actmol[b * FPc + f] = fmaxf(s2, 0.f);
  }
}

// -------------------- mol-level attention over L atoms -------------------------------
__global__ __launch_bounds__(256) void mol_attn_k(
    const float* __restrict__ act, const float* __restrict__ actmol,
    const float* __restrict__ malW, const float* __restrict__ malb,
    const float* __restrict__ mask,
    float* __restrict__ attnOut, float* __restrict__ wact, float* __restrict__ msumw) {
  const int b = blockIdx.x;
  __shared__ float sa_s;
  __shared__ float sn[Lc];
  __shared__ float wl[Lc];
  __shared__ float redmx[2], redsum[2], redsw[2];
  const int wv = threadIdx.x >> 6, lane = threadIdx.x & 63;
  if (wv == 0) {
    float p = 0.f;
    for (int f = lane; f < FPc; f += 64) p = fmaf(actmol[b * FPc + f], malW[f], p);
    float s = wave_sum(p);
    if (lane == 0) sa_s = s;
  }
  for (int l = wv; l < Lc; l += 4) {
    float p = 0.f;
    for (int f = lane; f < FPc; f += 64)
      p = fmaf(act[((size_t)b * Lc + l) * FPc + f], malW[FPc + f], p);
    float s = wave_sum(p);
    if (lane == 0) sn[l] = s;
  }
  __syncthreads();
  const int l = threadIdx.x;
  float sc = -3.0e38f, mval = 0.f;
  if (l < Lc) {
    mval = mask[b * Lc + l];
    sc = leaky(sa_s + sn[l] + malb[0]) + (mval == 0.f ? NEGC : 0.f);
  }
  float m = sc;
  #pragma unroll
  for (int o = 32; o >= 1; o >>= 1) m = fmaxf(m, __shfl_xor(m, o));
  if (lane == 0 && wv < 2) redmx[wv] = m;
  __syncthreads();
  float mx = fmaxf(redmx[0], redmx[1]);
  float e = (l < Lc) ? __expf(sc - mx) : 0.f;
  float s = e;
  #pragma unroll
  for (int o = 32; o >= 1; o >>= 1) s += __shfl_xor(s, o);
  if (lane == 0 && wv < 2) redsum[wv] = s;
  __syncthreads();
  float tot = redsum[0] + redsum[1];
  float w = 0.f;
  if (l < Lc) {
    w = e / tot * mval;
    wl[l] = w;
    attnOut[(size_t)b * Lc + l] = w;
  }
  float swp = w;
  #pragma unroll
  for (int o = 32; o >= 1; o >>= 1) swp += __shfl_xor(swp, o);
  if (lane == 0 && wv < 2) redsw[wv] = swp;
  __syncthreads();
  if (threadIdx.x == 0) msumw[b] = redsw[0] + redsw[1];
  const int f = threadIdx.x;
  if (f < FPc) {
    float a = 0.f;
    for (int l2 = 0; l2 < Lc; ++l2)
      a = fmaf(wl[l2], act[((size_t)b * Lc + l2) * FPc + f], a);
    wact[b * FPc + f] = a;
  }
}

// -------------------- final prediction -----------------------------------------------
__global__ __launch_bounds__(256) void pred_k(
    const float* __restrict__ molfeat, const float* __restrict__ outW,
    const float* __restrict__ outb, float* __restrict__ pred) {
  const int wv = threadIdx.x >> 6, lane = threadIdx.x & 63;
  const int b = blockIdx.x * 4 + wv;
  if (b < Bc) {
    float p = 0.f;
    for (int f = lane; f < FPc; f += 64) p = fmaf(molfeat[b * FPc + f], outW[f], p);
    float s = wave_sum(p);
    if (lane == 0) pred[b] = s + outb[0];
  }
}

extern "C" void kernel_launch(void* const* d_in, const int* in_sizes, int n_in,
                              void* d_out, int out_size, void* d_ws, size_t ws_size,
                              hipStream_t stream) {
  const float* atom_list = (const float*)d_in[0];
  const float* bond_list = (const float*)d_in[1];
  const int*   adl       = (const int*)d_in[2];
  const int*   bdl       = (const int*)d_in[3];
  const float* mask      = (const float*)d_in[4];
  const float* atom_fc_W = (const float*)d_in[5];
  const float* atom_fc_b = (const float*)d_in[6];
  const float* nb_W      = (const float*)d_in[7];
  const float* nb_b      = (const float*)d_in[8];
  const float* align_W   = (const float*)d_in[9];
  const float* align_b   = (const float*)d_in[10];
  const float* attend_W  = (const float*)d_in[11];
  const float* attend_b  = (const float*)d_in[12];
  const float* gru_Wih   = (const float*)d_in[13];
  const float* gru_Whh   = (const float*)d_in[14];
  const float* gru_bih   = (const float*)d_in[15];
  const float* gru_bhh   = (const float*)d_in[16];
  const float* mal_W     = (const float*)d_in[17];
  const float* mal_b     = (const float*)d_in[18];
  const float* matt_W    = (const float*)d_in[19];
  const float* matt_b    = (const float*)d_in[20];
  const float* mWih      = (const float*)d_in[21];
  const float* mWhh      = (const float*)d_in[22];
  const float* mbih      = (const float*)d_in[23];
  const float* mbhh      = (const float*)d_in[24];
  const float* out_W     = (const float*)d_in[25];
  const float* out_b     = (const float*)d_in[26];

  float* out  = (float*)d_out;
  float* AV   = out;                                  // (4,B,L,FP)
  float* ATTN = AV + (size_t)4 * BL * FPc;            // (3,B,L,K)
  float* MV   = ATTN + (size_t)Rc * BL * Kc;          // (3,B,FP)
  float* MU   = MV + (size_t)3 * Bc * FPc;            // (3,B,FP)
  float* MA   = MU + (size_t)3 * Bc * FPc;            // (2,B,L)
  float* PRED = MA + (size_t)Tc * Bc * Lc;            // (B,1)

  char* w = (char*)d_ws;
  __bf16* Hb0  = (__bf16*)w; w += (size_t)BL * KP * 2;
  __bf16* Hb1  = (__bf16*)w; w += (size_t)BL * KP * 2;
  __bf16* WNb  = (__bf16*)w; w += (size_t)BL * KP * 2;
  __bf16* Pb   = (__bf16*)w; w += (size_t)BL * FPc * 2;
  __bf16* Qb   = (__bf16*)w; w += (size_t)BL * FPc * 2;
  __bf16* Wpk  = (__bf16*)w; w += (size_t)Rc * 6 * 49 * 1024 * 2;
  __bf16* Apk  = (__bf16*)w; w += (size_t)Rc * 49 * 1024 * 2;
  float* SW    = (float*)w;  w += (size_t)BL * 4;
  float* MOLF  = (float*)w;  w += (size_t)Bc * FPc * 4;
  float* ACTM  = (float*)w;  w += (size_t)Bc * FPc * 4;
  float* WACT  = (float*)w;  w += (size_t)Bc * FPc * 4;
  float* MCTX  = (float*)w;  w += (size_t)Bc * FPc * 4;
  float* MSW   = (float*)w;  w += (size_t)Bc * 4;
  float* atomfcT = (float*)w; w += (size_t)AFc * FPc * 4;
  float* naT     = (float*)w; w += (size_t)(AFc + BFc) * FPc * 4;
  float* mattT   = (float*)w; w += (size_t)FPc * FPc * 4;
  float* mWihT   = (float*)w; w += (size_t)FPc * 600 * 4;
  float* mWhhT   = (float*)w; w += (size_t)FPc * 600 * 4;

  transpose_k<<<64, 256, 0, stream>>>(atom_fc_W, atomfcT, FPc, AFc);
  transpose_k<<<64, 256, 0, stream>>>(nb_W, naT, FPc, AFc + BFc);
  transpose_k<<<64, 256, 0, stream>>>(matt_W, mattT, FPc, FPc);
  transpose_k<<<64, 256, 0, stream>>>(mWih, mWihT, 600, FPc);
  transpose_k<<<64, 256, 0, stream>>>(mWhh, mWhhT, 600, FPc);
  pack_gru_k<<<(Rc * 6 * 49 * 1024 + 255) / 256, 256, 0, stream>>>(gru_Wih, gru_Whh, Wpk);
  pack_att_k<<<(Rc * 49 * 1024 + 255) / 256, 256, 0, stream>>>(attend_W, Apk);

  gemm8x1<AFc, 1><<<BL / 8, 256, 0, stream>>>(atom_list, atomfcT, atom_fc_b, nullptr, AV, Hb0);
  gemm8x1<AFc, 0><<<BL / 8, 256, 0, stream>>>(atom_list, naT, nullptr, nullptr, nullptr, Pb);
  gemm8x1<BFc, 0><<<BL / 8, 256, 0, stream>>>(bond_list, naT + AFc * FPc, nullptr, nullptr, nullptr, Qb);

  __bf16* Hbuf[2] = {Hb0, Hb1};
  for (int r = 0; r < Rc; ++r) {
    if (r == 0) {
      attn_mol0<<<Bc, 512, 0, stream>>>(Pb, Qb, nb_b, Hb0, adl, bdl,
          align_W, align_b, ATTN, WNb, SW);
    } else {
      attn_molN<<<Bc, 256, 0, stream>>>(Hbuf[r & 1], adl,
          align_W + (size_t)r * 2 * FPc, align_b + r,
          ATTN + (size_t)r * BL * Kc, WNb, SW);
    }
    attgru_mfma<<<BL / 128, 256, 0, stream>>>(WNb, Apk + (size_t)r * 49 * 1024,
        attend_b + (size_t)r * FPc, SW,
        Hbuf[r & 1], Hbuf[(r + 1) & 1],
        Wpk + (size_t)r * 6 * 49 * 1024, gru_bih + (size_t)r * 3 * FPc, gru_bhh + (size_t)r * 3 * FPc,
        AV + (size_t)(r + 1) * BL * FPc);
  }

  mol_sum_k<<<Bc, 256, 0, stream>>>(Hbuf[Rc & 1], AV + (size_t)3 * BL * FPc, mask, MU, MV, MOLF, ACTM);
  for (int t = 0; t < Tc; ++t) {
    mol_attn_k<<<Bc, 256, 0, stream>>>(AV + (size_t)3 * BL * FPc, ACTM, mal_W, mal_b, mask,
        MA + (size_t)t * Bc * Lc, WACT, MSW);
    gemm8x1<FPc, 2><<<Bc / 8, 256, 0, stream>>>(WACT, mattT, matt_b, MSW, MCTX, nullptr);
    gru8<<<Bc / 8, 256, 0, stream>>>(MCTX, MOLF, mWihT, mWhhT, mbih, mbhh,
        ACTM, MU + (size_t)(t + 1) * Bc * FPc, MV + (size_t)(t + 1) * Bc * FPc);
  }
  pred_k<<<Bc / 4, 256, 0, stream>>>(MOLF, out_W, out_b, PRED);
}

// Round 9
// 1054.144 us; speedup vs baseline: 1.2164x; 1.2164x over previous
//
#include <hip/hip_runtime.h>
#include <stdint.h>

#define Bc 512
#define Lc 128
#define Kc 6
#define AFc 39
#define BFc 10
#define FPc 200
#define Rc 3
#define Tc 2
constexpr int BL = Bc * Lc;          // 65536
constexpr int KP = 224;              // padded K / F for MFMA
constexpr float SLOPE = 0.01f;
constexpr float NEGC = -9e8f;

typedef __attribute__((ext_vector_type(8))) __bf16 bf16x8;
typedef __attribute__((ext_vector_type(16))) float f32x16;

__device__ __forceinline__ float leaky(float x) { return x >= 0.f ? x : SLOPE * x; }
__device__ __forceinline__ float sigm(float x) { return 1.f / (1.f + __expf(-x)); }
__device__ __forceinline__ float eluf(float x) { return x > 0.f ? x : expm1f(x); }
__device__ __forceinline__ float wave_sum(float v) {
  #pragma unroll
  for (int m = 32; m >= 1; m >>= 1) v += __shfl_xor(v, m);
  return v;
}
__device__ __forceinline__ float bflo(uint32_t u) { return __uint_as_float(u << 16); }
__device__ __forceinline__ float bfhi(uint32_t u) { return __uint_as_float(u & 0xffff0000u); }
__device__ __forceinline__ unsigned short f2bu(float x) {
  __bf16 b = (__bf16)x;
  return __builtin_bit_cast(unsigned short, b);
}
__device__ __forceinline__ void glds16(const void* g, void* l) {
  __builtin_amdgcn_global_load_lds((const __attribute__((address_space(1))) uint32_t*)g,
      (__attribute__((address_space(3))) uint32_t*)l, 16, 0, 0);
}
__device__ __forceinline__ f32x16 zero16() {
  f32x16 z;
  #pragma unroll
  for (int i = 0; i < 16; ++i) z[i] = 0.f;
  return z;
}

// -------------------- weight transpose: out[c*R + r] = in[r*C + c] --------------------
__global__ void transpose_k(const float* __restrict__ in, float* __restrict__ out, int R, int C) {
  int n = R * C;
  for (int i = blockIdx.x * blockDim.x + threadIdx.x; i < n; i += gridDim.x * blockDim.x) {
    int r = i / C, c = i - r * C;
    out[c * R + r] = in[i];
  }
}

// -------------------- pack GRU weights into staging-linear tiles ---------------------
__global__ void pack_gru_k(const float* __restrict__ Wih, const float* __restrict__ Whh,
                           __bf16* __restrict__ Wpk) {
  int i = blockIdx.x * 256 + threadIdx.x;
  if (i >= Rc * 6 * 7 * 7 * 1024) return;
  int j = i & 7, fl = (i >> 3) & 31, c = (i >> 8) & 3;
  int T = i >> 10;
  int kt = T % 7; T /= 7;
  int ft = T % 7; T /= 7;
  int g = T % 6;  int r = T / 6;
  int f = ft * 32 + fl, k = kt * 32 + c * 8 + j;
  float v = 0.f;
  if (f < FPc && k < FPc) {
    if (g < 3) v = Wih[((size_t)r * 3 * FPc + g * FPc + f) * FPc + k];
    else       v = Whh[((size_t)r * 3 * FPc + (g - 3) * FPc + f) * FPc + k];
  }
  Wpk[i] = (__bf16)v;
}

// Apk layout: [r][ft7][kt7]{1024: [c4][f32][j8]}
__global__ void pack_att_k(const float* __restrict__ W, __bf16* __restrict__ Apk) {
  int i = blockIdx.x * 256 + threadIdx.x;
  if (i >= Rc * 7 * 7 * 1024) return;
  int j = i & 7, fl = (i >> 3) & 31, c = (i >> 8) & 3;
  int T = i >> 10;
  int kt = T % 7; T /= 7;
  int ft = T % 7; int r = T / 7;
  int f = ft * 32 + fl, k = kt * 32 + c * 8 + j;
  float v = (f < FPc && k < FPc) ? W[((size_t)r * FPc + f) * FPc + k] : 0.f;
  Apk[i] = (__bf16)v;
}

// -------------------- generic small GEMM (f32): Y[rows][200] ------------------------
template<int KD, int EPI>
__global__ __launch_bounds__(256) void gemm8x1(
    const float* __restrict__ X, const float* __restrict__ WT,
    const float* __restrict__ bias, const float* __restrict__ sumw,
    float* __restrict__ Y, __bf16* __restrict__ Yb) {
  constexpr int TR = 8, LDP = 12;
  __shared__ float xT[KD * LDP];
  const int row0 = blockIdx.x * TR;
  const int tid = threadIdx.x;
  for (int e = tid; e < TR * KD; e += 256) {
    int r = e / KD, g = e - r * KD;
    xT[g * LDP + r] = X[(size_t)row0 * KD + e];
  }
  __syncthreads();
  const int f = tid;
  if (f < FPc) {
    float acc[TR];
    #pragma unroll
    for (int r = 0; r < TR; ++r) acc[r] = 0.f;
    #pragma unroll 4
    for (int g = 0; g < KD; ++g) {
      float w = WT[(size_t)g * FPc + f];
      float4 x0 = *reinterpret_cast<const float4*>(&xT[g * LDP]);
      float4 x1 = *reinterpret_cast<const float4*>(&xT[g * LDP + 4]);
      acc[0] = fmaf(x0.x, w, acc[0]); acc[1] = fmaf(x0.y, w, acc[1]);
      acc[2] = fmaf(x0.z, w, acc[2]); acc[3] = fmaf(x0.w, w, acc[3]);
      acc[4] = fmaf(x1.x, w, acc[4]); acc[5] = fmaf(x1.y, w, acc[5]);
      acc[6] = fmaf(x1.z, w, acc[6]); acc[7] = fmaf(x1.w, w, acc[7]);
    }
    #pragma unroll
    for (int r = 0; r < TR; ++r) {
      if (EPI == 0) {
        Yb[(size_t)(row0 + r) * FPc + f] = (__bf16)acc[r];
      } else if (EPI == 1) {
        float v = acc[r] + bias[f];
        Y[(size_t)(row0 + r) * FPc + f] = v;                 // raw atom_lin (viz)
        Yb[(size_t)(row0 + r) * KP + f] = (__bf16)leaky(v);  // h0
      } else {
        float v = fmaf(sumw[row0 + r], bias[f], acc[r]);
        Y[(size_t)(row0 + r) * FPc + f] = eluf(v);
      }
    }
  } else if (EPI == 1 && f < KP) {
    #pragma unroll
    for (int r = 0; r < TR; ++r) Yb[(size_t)(row0 + r) * KP + f] = (__bf16)0.f;
  }
}

// -------------------- fused attend + GRU v2 ------------------------------------------
// attend: WN frags in regs, Apk B direct from L2 (2 streams), epilogue -> LDS in gru
// A-frag layout (barrier-free: per-wave disjoint LDS regions).
// gru: xc frags from LDS, h in 14 reg-frags, B via LDS double-buffer + vmcnt(3)
// (v4's proven path — direct-global B with 12 streams serializes at VGPR limit, R8).
__global__ __launch_bounds__(256, 2) void attgru_mfma(
    const __bf16* __restrict__ WNb, const __bf16* __restrict__ Apk,
    const float* __restrict__ attb, const float* __restrict__ SW,
    const __bf16* __restrict__ Hin, __bf16* __restrict__ Hout,
    const __bf16* __restrict__ Wpk,
    const float* __restrict__ bih, const float* __restrict__ bhh,
    float* __restrict__ actOut) {
  __shared__ __align__(16) __bf16 smem[40960];   // 81920 B
  __bf16* xcL = smem;                             // [wv4][kt7][1024] = 57344 B
  __bf16* Bs  = smem + 28672;                     // [buf2][g6][1024] = 24576 B
  const int tid = threadIdx.x, wv = tid >> 6, lane = tid & 63;
  const size_t row0 = (size_t)blockIdx.x * 128;
  const int fl = lane & 31;

  // ---- attend phase: xc = elu(WN @ attW.T + sumw*b) -> LDS (A-frag layout) ----
  {
    bf16x8 af[7][2];
    const __bf16* sw_ = WNb + (row0 + wv * 32 + fl) * KP + (lane >> 5) * 8;
    #pragma unroll
    for (int kt = 0; kt < 7; ++kt)
      #pragma unroll
      for (int h = 0; h < 2; ++h)
        af[kt][h] = *(const bf16x8*)(sw_ + kt * 32 + h * 16);

    // write offset for (row rl, k=f): (k>>5)*1024 + ((k>>3)&3)*256 + rl*8 + (k&7)
    const int xbase = wv * 7168 + ((fl >> 3) & 3) * 256 + (fl & 7);
    #pragma unroll
    for (int ft = 0; ft < 7; ++ft) {
      f32x16 acc = zero16();
      #pragma unroll
      for (int kt = 0; kt < 7; ++kt) {
        const __bf16* bt = Apk + ((size_t)ft * 7 + kt) * 1024 + lane * 8;
        bf16x8 b0 = *(const bf16x8*)(bt);
        bf16x8 b1 = *(const bf16x8*)(bt + 512);
        acc = __builtin_amdgcn_mfma_f32_32x32x16_bf16(af[kt][0], b0, acc, 0, 0, 0);
        acc = __builtin_amdgcn_mfma_f32_32x32x16_bf16(af[kt][1], b1, acc, 0, 0, 0);
      }
      const int f = ft * 32 + fl;
      const bool fok = f < FPc;
      const float bf = fok ? attb[f] : 0.f;
      #pragma unroll
      for (int reg = 0; reg < 16; ++reg) {
        int rl = (reg & 3) + 8 * (reg >> 2) + 4 * (lane >> 5);
        float v = fok ? eluf(acc[reg] + SW[row0 + wv * 32 + rl] * bf) : 0.f;
        xcL[xbase + ft * 1024 + rl * 8] = (__bf16)v;
      }
    }
  }
  // (no barrier: each wave reads back only its own region; lgkmcnt orders LDS)

  // ---- h fragments into registers (after attend, to limit peak VGPR) ----
  bf16x8 hf[7][2];
  {
    const __bf16* sh = Hin + (row0 + wv * 32 + fl) * KP + (lane >> 5) * 8;
    #pragma unroll
    for (int kt = 0; kt < 7; ++kt)
      #pragma unroll
      for (int h = 0; h < 2; ++h)
        hf[kt][h] = *(const bf16x8*)(sh + kt * 32 + h * 16);
  }

  auto stageB = [&](int ft, int kt, int buf) {
    #pragma unroll
    for (int m3 = 0; m3 < 3; ++m3) {
      int m = wv * 3 + m3;               // 0..11
      int g = m >> 1, half = m & 1;
      const __bf16* s = Wpk + ((size_t)(g * 7 + ft) * 7 + kt) * 1024 + half * 512 + lane * 8;
      glds16(s, Bs + buf * 6144 + g * 1024 + half * 512);
    }
  };
  stageB(0, 0, 0);

  f32x16 gacc[6];
  #pragma unroll
  for (int g = 0; g < 6; ++g) gacc[g] = zero16();

  for (int ft = 0; ft < 7; ++ft) {
    #pragma unroll
    for (int kt = 0; kt < 7; ++kt) {
      const int it = ft * 7 + kt;
      const int buf = it & 1;
      const int nft = (kt == 6) ? ft + 1 : ft;
      const int nkt = (kt == 6) ? 0 : kt + 1;
      __builtin_amdgcn_sched_barrier(0);
      if (it < 48) stageB(nft, nkt, buf ^ 1);
      else         stageB(6, 6, buf ^ 1);          // dummy: keep 3 outstanding
      __builtin_amdgcn_sched_barrier(0);
      asm volatile("s_waitcnt vmcnt(3)" ::: "memory");
      __builtin_amdgcn_sched_barrier(0);
      __builtin_amdgcn_s_barrier();
      __builtin_amdgcn_sched_barrier(0);
      #pragma unroll
      for (int h = 0; h < 2; ++h) {
        bf16x8 xch = *(const bf16x8*)(xcL + wv * 7168 + kt * 1024 + h * 512 + lane * 8);
        bf16x8 hh = hf[kt][h];
        const __bf16* bb = Bs + buf * 6144 + h * 512 + lane * 8;
        bf16x8 b0 = *(const bf16x8*)(bb);
        bf16x8 b1 = *(const bf16x8*)(bb + 1024);
        bf16x8 b2 = *(const bf16x8*)(bb + 2048);
        bf16x8 b3 = *(const bf16x8*)(bb + 3072);
        bf16x8 b4 = *(const bf16x8*)(bb + 4096);
        bf16x8 b5 = *(const bf16x8*)(bb + 5120);
        __builtin_amdgcn_s_setprio(1);
        gacc[0] = __builtin_amdgcn_mfma_f32_32x32x16_bf16(xch, b0, gacc[0], 0, 0, 0);
        gacc[1] = __builtin_amdgcn_mfma_f32_32x32x16_bf16(xch, b1, gacc[1], 0, 0, 0);
        gacc[2] = __builtin_amdgcn_mfma_f32_32x32x16_bf16(xch, b2, gacc[2], 0, 0, 0);
        gacc[3] = __builtin_amdgcn_mfma_f32_32x32x16_bf16(hh, b3, gacc[3], 0, 0, 0);
        gacc[4] = __builtin_amdgcn_mfma_f32_32x32x16_bf16(hh, b4, gacc[4], 0, 0, 0);
        gacc[5] = __builtin_amdgcn_mfma_f32_32x32x16_bf16(hh, b5, gacc[5], 0, 0, 0);
        __builtin_amdgcn_s_setprio(0);
      }
      if (kt == 6) {
        const int f = ft * 32 + fl;
        const bool fok = f < FPc;
        float bir = 0, biz = 0, bin_ = 0, bhr = 0, bhz = 0, bhn = 0;
        if (fok) {
          bir = bih[f]; biz = bih[FPc + f]; bin_ = bih[2 * FPc + f];
          bhr = bhh[f]; bhz = bhh[FPc + f]; bhn = bhh[2 * FPc + f];
        }
        #pragma unroll
        for (int reg = 0; reg < 16; ++reg) {
          int rl = (reg & 3) + 8 * (reg >> 2) + 4 * (lane >> 5);
          size_t row = row0 + wv * 32 + rl;
          if (fok) {
            float ho = (float)Hin[row * KP + f];
            float rg_ = sigm(gacc[0][reg] + bir + gacc[3][reg] + bhr);
            float zg  = sigm(gacc[1][reg] + biz + gacc[4][reg] + bhz);
            float ng  = tanhf(gacc[2][reg] + bin_ + rg_ * (gacc[5][reg] + bhn));
            float hp = (1.f - zg) * ng + zg * ho;
            Hout[row * KP + f] = (__bf16)hp;
            actOut[row * FPc + f] = fmaxf(hp, 0.f);
          } else {
            Hout[row * KP + f] = (__bf16)0.f;
          }
        }
        #pragma unroll
        for (int g = 0; g < 6; ++g) gacc[g] = zero16();
      }
      __builtin_amdgcn_sched_barrier(0);
      __builtin_amdgcn_s_barrier();
      __builtin_amdgcn_sched_barrier(0);
    }
  }
}

// -------------------- attn round r>=1: per-molecule block ---------------------------
__global__ __launch_bounds__(256) void attn_molN(
    const __bf16* __restrict__ Hb,       // [BL][KP]
    const int* __restrict__ adl,
    const float* __restrict__ alW,       // +r*2*FP
    const float* __restrict__ albp,      // +r
    float* __restrict__ attnOut, __bf16* __restrict__ WNb, float* __restrict__ SW) {
  __shared__ __align__(16) __bf16 actL[128 * 224];
  __shared__ float saL[128], snL[128];
  const int b = blockIdx.x;
  const int tid = threadIdx.x, wv = tid >> 6, lane = tid & 63;
  const bool l36 = lane < 36;

  {
    const uint4* src = (const uint4*)(Hb + (size_t)b * 128 * KP);
    uint4* dst = (uint4*)actL;
    for (int i = tid; i < 128 * 224 / 8; i += 256) {
      uint4 v = src[i];
      uint32_t c[4] = {v.x, v.y, v.z, v.w};
      #pragma unroll
      for (int j = 0; j < 4; ++j) {
        uint32_t lo = c[j] & 0xffffu, hi = c[j] >> 16;
        if (lo & 0x8000u) lo = 0;
        if (hi & 0x8000u) hi = 0;
        c[j] = lo | (hi << 16);
      }
      dst[i] = make_uint4(c[0], c[1], c[2], c[3]);
    }
  }
  float wa0x = alW[2 * lane], wa0y = alW[2 * lane + 1];
  float wa1x = l36 ? alW[128 + 2 * lane] : 0.f, wa1y = l36 ? alW[129 + 2 * lane] : 0.f;
  float wn0x = alW[FPc + 2 * lane], wn0y = alW[FPc + 2 * lane + 1];
  float wn1x = l36 ? alW[FPc + 128 + 2 * lane] : 0.f, wn1y = l36 ? alW[FPc + 129 + 2 * lane] : 0.f;
  const float ab = albp[0];
  __syncthreads();

  for (int i = 0; i < 32; ++i) {
    int l = wv * 32 + i;
    const uint32_t* rowp = (const uint32_t*)(actL + l * 224);
    uint32_t u0 = rowp[lane];
    uint32_t u1 = l36 ? rowp[64 + lane] : 0u;
    float x0 = bflo(u0), y0 = bfhi(u0), x1 = bflo(u1), y1 = bfhi(u1);
    float psa = x0 * wa0x + y0 * wa0y + x1 * wa1x + y1 * wa1y;
    float psn = x0 * wn0x + y0 * wn0y + x1 * wn1x + y1 * wn1y;
    psa = wave_sum(psa);
    psn = wave_sum(psn);
    if (lane == 0) { saL[l] = psa; snL[l] = psn; }
  }
  __syncthreads();

  for (int i = 0; i < 32; ++i) {
    const int row = wv * 32 + i;
    const size_t grow = (size_t)b * 128 + row;
    int gk = (lane < Kc) ? adl[grow * Kc + lane] : 0;
    int ai[Kc];
    #pragma unroll
    for (int k = 0; k < Kc; ++k) ai[k] = __shfl(gk, k);
    const float sarow = saL[row];
    float s[Kc]; bool pad[Kc]; float mx = -3.0e38f;
    #pragma unroll
    for (int k = 0; k < Kc; ++k) {
      pad[k] = (ai[k] == Lc - 1);
      s[k] = leaky(sarow + snL[ai[k]] + ab) + (pad[k] ? NEGC : 0.f);
      mx = fmaxf(mx, s[k]);
    }
    float e[Kc], sum = 0.f;
    #pragma unroll
    for (int k = 0; k < Kc; ++k) { e[k] = __expf(s[k] - mx); sum += e[k]; }
    float inv = 1.f / sum;
    float w[Kc], sw = 0.f;
    #pragma unroll
    for (int k = 0; k < Kc; ++k) { w[k] = pad[k] ? 0.f : e[k] * inv; sw += w[k]; }
    if (lane < Kc) attnOut[grow * Kc + lane] = w[lane];
    if (lane == 0) SW[grow] = sw;
    float a0 = 0.f, b0 = 0.f, a1 = 0.f, b1 = 0.f;
    #pragma unroll
    for (int k = 0; k < Kc; ++k) {
      const uint32_t* nr = (const uint32_t*)(actL + ai[k] * 224);
      uint32_t u0 = nr[lane];
      uint32_t u1 = l36 ? nr[64 + lane] : 0u;
      a0 = fmaf(w[k], bflo(u0), a0); b0 = fmaf(w[k], bfhi(u0), b0);
      a1 = fmaf(w[k], bflo(u1), a1); b1 = fmaf(w[k], bfhi(u1), b1);
    }
    __bf16* wr = WNb + grow * KP;
    ushort2 o0; o0.x = f2bu(a0); o0.y = f2bu(b0);
    *(ushort2*)(wr + 2 * lane) = o0;
    if (lane < 48) {
      float va = l36 ? a1 : 0.f, vb = l36 ? b1 : 0.f;
      ushort2 o1; o1.x = f2bu(va); o1.y = f2bu(vb);
      *(ushort2*)(wr + 128 + 2 * lane) = o1;
    }
  }
}

// -------------------- attn round r==0: per-molecule block, 8 waves, v-reg cache -----
__global__ __launch_bounds__(512) void attn_mol0(
    const __bf16* __restrict__ Pb, const __bf16* __restrict__ Qb,
    const float* __restrict__ nbb, const __bf16* __restrict__ Hb0,
    const int* __restrict__ adl, const int* __restrict__ bdl,
    const float* __restrict__ alW, const float* __restrict__ albp,
    float* __restrict__ attnOut, __bf16* __restrict__ WNb, float* __restrict__ SW) {
  __shared__ __align__(16) __bf16 Pl[128 * 200];
  __shared__ __align__(16) __bf16 Ql[128 * 200];
  __shared__ float nbbL[200];
  __shared__ float saL[128];
  const int b = blockIdx.x;
  const int tid = threadIdx.x, wv = tid >> 6, lane = tid & 63;
  const bool l36 = lane < 36;

  {
    const uint4* sp = (const uint4*)(Pb + (size_t)b * 128 * FPc);
    const uint4* sq = (const uint4*)(Qb + (size_t)b * 128 * FPc);
    uint4* dp = (uint4*)Pl;
    uint4* dq = (uint4*)Ql;
    for (int i = tid; i < 128 * 200 / 8; i += 512) { dp[i] = sp[i]; dq[i] = sq[i]; }
    for (int i = tid; i < FPc; i += 512) nbbL[i] = nbb[i];
  }
  float wa0x = alW[2 * lane], wa0y = alW[2 * lane + 1];
  float wa1x = l36 ? alW[128 + 2 * lane] : 0.f, wa1y = l36 ? alW[129 + 2 * lane] : 0.f;
  float wn0x = alW[FPc + 2 * lane], wn0y = alW[FPc + 2 * lane + 1];
  float wn1x = l36 ? alW[FPc + 128 + 2 * lane] : 0.f, wn1y = l36 ? alW[FPc + 129 + 2 * lane] : 0.f;
  const float ab = albp[0];

  for (int i = 0; i < 16; ++i) {
    int l = wv * 16 + i;
    const uint32_t* hr = (const uint32_t*)(Hb0 + ((size_t)b * 128 + l) * KP);
    uint32_t u0 = hr[lane];
    uint32_t u1 = l36 ? hr[64 + lane] : 0u;
    float psa = bflo(u0) * wa0x + bfhi(u0) * wa0y + bflo(u1) * wa1x + bfhi(u1) * wa1y;
    psa = wave_sum(psa);
    if (lane == 0) saL[l] = psa;
  }
  __syncthreads();

  const float n0x = nbbL[2 * lane], n0y = nbbL[2 * lane + 1];
  const float n1x = l36 ? nbbL[128 + 2 * lane] : 0.f, n1y = l36 ? nbbL[129 + 2 * lane] : 0.f;

  for (int i = 0; i < 16; ++i) {
    const int row = wv * 16 + i;
    const size_t grow = (size_t)b * 128 + row;
    int gk = (lane < Kc) ? adl[grow * Kc + lane] : 0;
    int hk = (lane < Kc) ? bdl[grow * Kc + lane] : 0;
    int ai[Kc], bi[Kc];
    #pragma unroll
    for (int k = 0; k < Kc; ++k) { ai[k] = __shfl(gk, k); bi[k] = __shfl(hk, k); }
    float v0x[Kc], v0y[Kc], v1x[Kc], v1y[Kc], p[Kc];
    #pragma unroll
    for (int k = 0; k < Kc; ++k) {
      const uint32_t* pr = (const uint32_t*)(Pl + ai[k] * 200);
      const uint32_t* qr = (const uint32_t*)(Ql + bi[k] * 200);
      uint32_t up0 = pr[lane], uq0 = qr[lane];
      uint32_t up1 = l36 ? pr[64 + lane] : 0u, uq1 = l36 ? qr[64 + lane] : 0u;
      v0x[k] = leaky(bflo(up0) + bflo(uq0) + n0x);
      v0y[k] = leaky(bfhi(up0) + bfhi(uq0) + n0y);
      v1x[k] = l36 ? leaky(bflo(up1) + bflo(uq1) + n1x) : 0.f;
      v1y[k] = l36 ? leaky(bfhi(up1) + bfhi(uq1) + n1y) : 0.f;
      p[k] = v0x[k] * wn0x + v0y[k] * wn0y + v1x[k] * wn1x + v1y[k] * wn1y;
    }
    #pragma unroll
    for (int k = 0; k < Kc; ++k) p[k] = wave_sum(p[k]);
    const float sarow = saL[row];
    float s[Kc]; bool pad[Kc]; float mx = -3.0e38f;
    #pragma unroll
    for (int k = 0; k < Kc; ++k) {
      pad[k] = (ai[k] == Lc - 1);
      s[k] = leaky(sarow + p[k] + ab) + (pad[k] ? NEGC : 0.f);
      mx = fmaxf(mx, s[k]);
    }
    float e[Kc], sum = 0.f;
    #pragma unroll
    for (int k = 0; k < Kc; ++k) { e[k] = __expf(s[k] - mx); sum += e[k]; }
    float inv = 1.f / sum;
    float w[Kc], sw = 0.f;
    #pragma unroll
    for (int k = 0; k < Kc; ++k) { w[k] = pad[k] ? 0.f : e[k] * inv; sw += w[k]; }
    if (lane < Kc) attnOut[grow * Kc + lane] = w[lane];
    if (lane == 0) SW[grow] = sw;
    float a0 = 0.f, b0v = 0.f, a1 = 0.f, b1v = 0.f;
    #pragma unroll
    for (int k = 0; k < Kc; ++k) {
      a0  = fmaf(w[k], v0x[k], a0);
      b0v = fmaf(w[k], v0y[k], b0v);
      a1  = fmaf(w[k], v1x[k], a1);
      b1v = fmaf(w[k], v1y[k], b1v);
    }
    __bf16* wr = WNb + grow * KP;
    ushort2 o0; o0.x = f2bu(a0); o0.y = f2bu(b0v);
    *(ushort2*)(wr + 2 * lane) = o0;
    if (lane < 48) {
      float va = l36 ? a1 : 0.f, vb = l36 ? b1v : 0.f;
      ushort2 o1; o1.x = f2bu(va); o1.y = f2bu(vb);
      *(ushort2*)(wr + 128 + 2 * lane) = o1;
    }
  }
}

// -------------------- fused GRU f32 (mol path, 512 rows) -----------------------------
__global__ __launch_bounds__(256) void gru8(
    const float* __restrict__ XC, float* __restrict__ H,
    const float* __restrict__ WihT, const float* __restrict__ WhhT,
    const float* __restrict__ bih, const float* __restrict__ bhh,
    float* __restrict__ actOut, float* __restrict__ unbOut, float* __restrict__ vizOut) {
  constexpr int TR = 8, LDP = 12;
  __shared__ float xc[FPc * LDP];
  __shared__ float xh[FPc * LDP];
  const int row0 = blockIdx.x * TR;
  const int tid = threadIdx.x;
  for (int e = tid; e < TR * FPc; e += 256) {
    int r = e / FPc, g = e - r * FPc;
    xc[g * LDP + r] = XC[(size_t)row0 * FPc + e];
    xh[g * LDP + r] = H[(size_t)row0 * FPc + e];
  }
  __syncthreads();
  const int f = tid;
  if (f < FPc) {
    float air[8], aiz[8], ain[8], ahr[8], ahz[8], ahn[8];
    const float bir = bih[f], biz = bih[f + 200], bin_ = bih[f + 400];
    const float bhr = bhh[f], bhz = bhh[f + 200], bhn = bhh[f + 400];
    #pragma unroll
    for (int r = 0; r < 8; ++r) {
      air[r] = bir; aiz[r] = biz; ain[r] = bin_;
      ahr[r] = bhr; ahz[r] = bhz; ahn[r] = bhn;
    }
    #pragma unroll 2
    for (int g = 0; g < FPc; ++g) {
      const float* wi = &WihT[(size_t)g * 600 + f];
      const float* wh = &WhhT[(size_t)g * 600 + f];
      float wir = wi[0], wiz = wi[200], win = wi[400];
      float whr = wh[0], whz = wh[200], whn = wh[400];
      float4 c0 = *reinterpret_cast<const float4*>(&xc[g * LDP]);
      float4 c1 = *reinterpret_cast<const float4*>(&xc[g * LDP + 4]);
      float4 h0 = *reinterpret_cast<const float4*>(&xh[g * LDP]);
      float4 h1 = *reinterpret_cast<const float4*>(&xh[g * LDP + 4]);
      float cx[8] = {c0.x, c0.y, c0.z, c0.w, c1.x, c1.y, c1.z, c1.w};
      float hx[8] = {h0.x, h0.y, h0.z, h0.w, h1.x, h1.y, h1.z, h1.w};
      #pragma unroll
      for (int r = 0; r < 8; ++r) {
        air[r] = fmaf(cx[r], wir, air[r]);
        aiz[r] = fmaf(cx[r], wiz, aiz[r]);
        ain[r] = fmaf(cx[r], win, ain[r]);
        ahr[r] = fmaf(hx[r], whr, ahr[r]);
        ahz[r] = fmaf(hx[r], whz, ahz[r]);
        ahn[r] = fmaf(hx[r], whn, ahn[r]);
      }
    }
    #pragma unroll
    for (int r = 0; r < 8; ++r) {
      float rg = sigm(air[r] + ahr[r]);
      float zg = sigm(aiz[r] + ahz[r]);
      float ng = tanhf(fmaf(rg, ahn[r], ain[r]));
      float hv = xh[f * LDP + r];
      float hp = (1.f - zg) * ng + zg * hv;
      size_t idx = (size_t)(row0 + r) * FPc + f;
      H[idx] = hp;
      float a = fmaxf(hp, 0.f);
      if (actOut) actOut[idx] = a;
      if (unbOut) unbOut[idx] = hp;
      if (vizOut) vizOut[idx] = a;
    }
  }
}

// -------------------- mol-level sum over atoms ---------------------------------------
__global__ __launch_bounds__(256) void mol_sum_k(
    const __bf16* __restrict__ Hb, const float* __restrict__ ACT, const float* __restrict__ mask,
    float* __restrict__ unb0, float* __restrict__ viz0,
    float* __restrict__ molfeat, float* __restrict__ actmol) {
  const int b = blockIdx.x;
  __shared__ float mk[Lc];
  for (int l = threadIdx.x; l < Lc; l += 256) mk[l] = mask[b * Lc + l];
  __syncthreads();
  const int f = threadIdx.x;
  if (f < FPc) {
    float s1 = 0.f, s2 = 0.f;
    for (int l = 0; l < Lc; ++l) {
      float m = mk[l];
      s1 = fmaf((float)Hb[((size_t)b * Lc + l) * KP + f], m, s1);
      s2 = fmaf(ACT[((size_t)b * Lc + l) * FPc + f], m, s2);
    }
    unb0[b * FPc + f] = s1;
    viz0[b * FPc + f] = s2;
    molfeat[b * FPc + f] = s2;
    actmol[b * FPc + f] = fmaxf(s2, 0.f);
  }
}

// -------------------- mol-level attention over L atoms -------------------------------
__global__ __launch_bounds__(256) void mol_attn_k(
    const float* __restrict__ act, const float* __restrict__ actmol,
    const float* __restrict__ malW, const float* __restrict__ malb,
    const float* __restrict__ mask,
    float* __restrict__ attnOut, float* __restrict__ wact, float* __restrict__ msumw) {
  const int b = blockIdx.x;
  __shared__ float sa_s;
  __shared__ float sn[Lc];
  __shared__ float wl[Lc];
  __shared__ float redmx[2], redsum[2], redsw[2];
  const int wv = threadIdx.x >> 6, lane = threadIdx.x & 63;
  if (wv == 0) {
    float p = 0.f;
    for (int f = lane; f < FPc; f += 64) p = fmaf(actmol[b * FPc + f], malW[f], p);
    float s = wave_sum(p);
    if (lane == 0) sa_s = s;
  }
  for (int l = wv; l < Lc; l += 4) {
    float p = 0.f;
    for (int f = lane; f < FPc; f += 64)
      p = fmaf(act[((size_t)b * Lc + l) * FPc + f], malW[FPc + f], p);
    float s = wave_sum(p);
    if (lane == 0) sn[l] = s;
  }
  __syncthreads();
  const int l = threadIdx.x;
  float sc = -3.0e38f, mval = 0.f;
  if (l < Lc) {
    mval = mask[b * Lc + l];
    sc = leaky(sa_s + sn[l] + malb[0]) + (mval == 0.f ? NEGC : 0.f);
  }
  float m = sc;
  #pragma unroll
  for (int o = 32; o >= 1; o >>= 1) m = fmaxf(m, __shfl_xor(m, o));
  if (lane == 0 && wv < 2) redmx[wv] = m;
  __syncthreads();
  float mx = fmaxf(redmx[0], redmx[1]);
  float e = (l < Lc) ? __expf(sc - mx) : 0.f;
  float s = e;
  #pragma unroll
  for (int o = 32; o >= 1; o >>= 1) s += __shfl_xor(s, o);
  if (lane == 0 && wv < 2) redsum[wv] = s;
  __syncthreads();
  float tot = redsum[0] + redsum[1];
  float w = 0.f;
  if (l < Lc) {
    w = e / tot * mval;
    wl[l] = w;
    attnOut[(size_t)b * Lc + l] = w;
  }
  float swp = w;
  #pragma unroll
  for (int o = 32; o >= 1; o >>= 1) swp += __shfl_xor(swp, o);
  if (lane == 0 && wv < 2) redsw[wv] = swp;
  __syncthreads();
  if (threadIdx.x == 0) msumw[b] = redsw[0] + redsw[1];
  const int f = threadIdx.x;
  if (f < FPc) {
    float a = 0.f;
    for (int l2 = 0; l2 < Lc; ++l2)
      a = fmaf(wl[l2], act[((size_t)b * Lc + l2) * FPc + f], a);
    wact[b * FPc + f] = a;
  }
}

// -------------------- final prediction -----------------------------------------------
__global__ __launch_bounds__(256) void pred_k(
    const float* __restrict__ molfeat, const float* __restrict__ outW,
    const float* __restrict__ outb, float* __restrict__ pred) {
  const int wv = threadIdx.x >> 6, lane = threadIdx.x & 63;
  const int b = blockIdx.x * 4 + wv;
  if (b < Bc) {
    float p = 0.f;
    for (int f = lane; f < FPc; f += 64) p = fmaf(molfeat[b * FPc + f], outW[f], p);
    float s = wave_sum(p);
    if (lane == 0) pred[b] = s + outb[0];
  }
}

extern "C" void kernel_launch(void* const* d_in, const int* in_sizes, int n_in,
                              void* d_out, int out_size, void* d_ws, size_t ws_size,
                              hipStream_t stream) {
  const float* atom_list = (const float*)d_in[0];
  const float* bond_list = (const float*)d_in[1];
  const int*   adl       = (const int*)d_in[2];
  const int*   bdl       = (const int*)d_in[3];
  const float* mask      = (const float*)d_in[4];
  const float* atom_fc_W = (const float*)d_in[5];
  const float* atom_fc_b = (const float*)d_in[6];
  const float* nb_W      = (const float*)d_in[7];
  const float* nb_b      = (const float*)d_in[8];
  const float* align_W   = (const float*)d_in[9];
  const float* align_b   = (const float*)d_in[10];
  const float* attend_W  = (const float*)d_in[11];
  const float* attend_b  = (const float*)d_in[12];
  const float* gru_Wih   = (const float*)d_in[13];
  const float* gru_Whh   = (const float*)d_in[14];
  const float* gru_bih   = (const float*)d_in[15];
  const float* gru_bhh   = (const float*)d_in[16];
  const float* mal_W     = (const float*)d_in[17];
  const float* mal_b     = (const float*)d_in[18];
  const float* matt_W    = (const float*)d_in[19];
  const float* matt_b    = (const float*)d_in[20];
  const float* mWih      = (const float*)d_in[21];
  const float* mWhh      = (const float*)d_in[22];
  const float* mbih      = (const float*)d_in[23];
  const float* mbhh      = (const float*)d_in[24];
  const float* out_W     = (const float*)d_in[25];
  const float* out_b     = (const float*)d_in[26];

  float* out  = (float*)d_out;
  float* AV   = out;                                  // (4,B,L,FP)
  float* ATTN = AV + (size_t)4 * BL * FPc;            // (3,B,L,K)
  float* MV   = ATTN + (size_t)Rc * BL * Kc;          // (3,B,FP)
  float* MU   = MV + (size_t)3 * Bc * FPc;            // (3,B,FP)
  float* MA   = MU + (size_t)3 * Bc * FPc;            // (2,B,L)
  float* PRED = MA + (size_t)Tc * Bc * Lc;            // (B,1)

  char* w = (char*)d_ws;
  __bf16* Hb0  = (__bf16*)w; w += (size_t)BL * KP * 2;
  __bf16* Hb1  = (__bf16*)w; w += (size_t)BL * KP * 2;
  __bf16* WNb  = (__bf16*)w; w += (size_t)BL * KP * 2;
  __bf16* Pb   = (__bf16*)w; w += (size_t)BL * FPc * 2;
  __bf16* Qb   = (__bf16*)w; w += (size_t)BL * FPc * 2;
  __bf16* Wpk  = (__bf16*)w; w += (size_t)Rc * 6 * 49 * 1024 * 2;
  __bf16* Apk  = (__bf16*)w; w += (size_t)Rc * 49 * 1024 * 2;
  float* SW    = (float*)w;  w += (size_t)BL * 4;
  float* MOLF  = (float*)w;  w += (size_t)Bc * FPc * 4;
  float* ACTM  = (float*)w;  w += (size_t)Bc * FPc * 4;
  float* WACT  = (float*)w;  w += (size_t)Bc * FPc * 4;
  float* MCTX  = (float*)w;  w += (size_t)Bc * FPc * 4;
  float* MSW   = (float*)w;  w += (size_t)Bc * 4;
  float* atomfcT = (float*)w; w += (size_t)AFc * FPc * 4;
  float* naT     = (float*)w; w += (size_t)(AFc + BFc) * FPc * 4;
  float* mattT   = (float*)w; w += (size_t)FPc * FPc * 4;
  float* mWihT   = (float*)w; w += (size_t)FPc * 600 * 4;
  float* mWhhT   = (float*)w; w += (size_t)FPc * 600 * 4;

  transpose_k<<<64, 256, 0, stream>>>(atom_fc_W, atomfcT, FPc, AFc);
  transpose_k<<<64, 256, 0, stream>>>(nb_W, naT, FPc, AFc + BFc);
  transpose_k<<<64, 256, 0, stream>>>(matt_W, mattT, FPc, FPc);
  transpose_k<<<64, 256, 0, stream>>>(mWih, mWihT, 600, FPc);
  transpose_k<<<64, 256, 0, stream>>>(mWhh, mWhhT, 600, FPc);
  pack_gru_k<<<(Rc * 6 * 49 * 1024 + 255) / 256, 256, 0, stream>>>(gru_Wih, gru_Whh, Wpk);
  pack_att_k<<<(Rc * 49 * 1024 + 255) / 256, 256, 0, stream>>>(attend_W, Apk);

  gemm8x1<AFc, 1><<<BL / 8, 256, 0, stream>>>(atom_list, atomfcT, atom_fc_b, nullptr, AV, Hb0);
  gemm8x1<AFc, 0><<<BL / 8, 256, 0, stream>>>(atom_list, naT, nullptr, nullptr, nullptr, Pb);
  gemm8x1<BFc, 0><<<BL / 8, 256, 0, stream>>>(bond_list, naT + AFc * FPc, nullptr, nullptr, nullptr, Qb);

  __bf16* Hbuf[2] = {Hb0, Hb1};
  for (int r = 0; r < Rc; ++r) {
    if (r == 0) {
      attn_mol0<<<Bc, 512, 0, stream>>>(Pb, Qb, nb_b, Hb0, adl, bdl,
          align_W, align_b, ATTN, WNb, SW);
    } else {
      attn_molN<<<Bc, 256, 0, stream>>>(Hbuf[r & 1], adl,
          align_W + (size_t)r * 2 * FPc, align_b + r,
          ATTN + (size_t)r * BL * Kc, WNb, SW);
    }
    attgru_mfma<<<BL / 128, 256, 0, stream>>>(WNb, Apk + (size_t)r * 49 * 1024,
        attend_b + (size_t)r * FPc, SW,
        Hbuf[r & 1], Hbuf[(r + 1) & 1],
        Wpk + (size_t)r * 6 * 49 * 1024, gru_bih + (size_t)r * 3 * FPc, gru_bhh + (size_t)r * 3 * FPc,
        AV + (size_t)(r + 1) * BL * FPc);
  }

  mol_sum_k<<<Bc, 256, 0, stream>>>(Hbuf[Rc & 1], AV + (size_t)3 * BL * FPc, mask, MU, MV, MOLF, ACTM);
  for (int t = 0; t < Tc; ++t) {
    mol_attn_k<<<Bc, 256, 0, stream>>>(AV + (size_t)3 * BL * FPc, ACTM, mal_W, mal_b, mask,
        MA + (size_t)t * Bc * Lc, WACT, MSW);
    gemm8x1<FPc, 2><<<Bc / 8, 256, 0, stream>>>(WACT, mattT, matt_b, MSW, MCTX, nullptr);
    gru8<<<Bc / 8, 256, 0, stream>>>(MCTX, MOLF, mWihT, mWhhT, mbih, mbhh,
        ACTM, MU + (size_t)(t + 1) * Bc * FPc, MV + (size_t)(t + 1) * Bc * FPc);
  }
  pred_k<<<Bc / 4, 256, 0, stream>>>(MOLF, out_W, out_b, PRED);
}

// Round 10
// 1010.589 us; speedup vs baseline: 1.2688x; 1.0431x over previous
//
#include <hip/hip_runtime.h>
#include <stdint.h>

#define Bc 512
#define Lc 128
#define Kc 6
#define AFc 39
#define BFc 10
#define FPc 200
#define Rc 3
#define Tc 2
constexpr int BL = Bc * Lc;          // 65536
constexpr int KP = 224;              // padded K / F for MFMA
constexpr float SLOPE = 0.01f;
constexpr float NEGC = -9e8f;

typedef __attribute__((ext_vector_type(8))) __bf16 bf16x8;
typedef __attribute__((ext_vector_type(16))) float f32x16;

__device__ __forceinline__ float leaky(float x) { return x >= 0.f ? x : SLOPE * x; }
__device__ __forceinline__ float sigm(float x) { return 1.f / (1.f + __expf(-x)); }
__device__ __forceinline__ float eluf(float x) { return x > 0.f ? x : expm1f(x); }
__device__ __forceinline__ float wave_sum(float v) {
  #pragma unroll
  for (int m = 32; m >= 1; m >>= 1) v += __shfl_xor(v, m);
  return v;
}
__device__ __forceinline__ float bflo(uint32_t u) { return __uint_as_float(u << 16); }
__device__ __forceinline__ float bfhi(uint32_t u) { return __uint_as_float(u & 0xffff0000u); }
__device__ __forceinline__ unsigned short f2bu(float x) {
  __bf16 b = (__bf16)x;
  return __builtin_bit_cast(unsigned short, b);
}
__device__ __forceinline__ void glds16(const void* g, void* l) {
  __builtin_amdgcn_global_load_lds((const __attribute__((address_space(1))) uint32_t*)g,
      (__attribute__((address_space(3))) uint32_t*)l, 16, 0, 0);
}
__device__ __forceinline__ f32x16 zero16() {
  f32x16 z;
  #pragma unroll
  for (int i = 0; i < 16; ++i) z[i] = 0.f;
  return z;
}

// -------------------- unified prep: 5 transposes + 2 weight packs --------------------
__global__ void prep_k(
    const float* __restrict__ atom_fc_W, const float* __restrict__ nb_W,
    const float* __restrict__ matt_W, const float* __restrict__ mWih,
    const float* __restrict__ mWhh, const float* __restrict__ gru_Wih,
    const float* __restrict__ gru_Whh, const float* __restrict__ attend_W,
    float* __restrict__ atomfcT, float* __restrict__ naT, float* __restrict__ mattT,
    float* __restrict__ mWihT, float* __restrict__ mWhhT,
    __bf16* __restrict__ Wpk, __bf16* __restrict__ Apk) {
  int i = blockIdx.x * 256 + threadIdx.x;
  const int n0 = FPc * AFc, n1 = FPc * (AFc + BFc), n2 = FPc * FPc;
  const int n3 = 600 * FPc, n4 = 600 * FPc;
  const int nW = Rc * 6 * 49 * 1024, nA = Rc * 49 * 1024;
  if (i < n0) { int r = i / AFc, c = i % AFc; atomfcT[c * FPc + r] = atom_fc_W[i]; return; }
  i -= n0;
  if (i < n1) { int r = i / (AFc + BFc), c = i % (AFc + BFc); naT[c * FPc + r] = nb_W[i]; return; }
  i -= n1;
  if (i < n2) { int r = i / FPc, c = i % FPc; mattT[c * FPc + r] = matt_W[i]; return; }
  i -= n2;
  if (i < n3) { int r = i / FPc, c = i % FPc; mWihT[c * 600 + r] = mWih[i]; return; }
  i -= n3;
  if (i < n4) { int r = i / FPc, c = i % FPc; mWhhT[c * 600 + r] = mWhh[i]; return; }
  i -= n4;
  if (i < nW) {
    int j = i & 7, fl = (i >> 3) & 31, c = (i >> 8) & 3;
    int T = i >> 10;
    int kt = T % 7; T /= 7;
    int ft = T % 7; T /= 7;
    int g = T % 6;  int r = T / 6;
    int f = ft * 32 + fl, k = kt * 32 + c * 8 + j;
    float v = 0.f;
    if (f < FPc && k < FPc) {
      if (g < 3) v = gru_Wih[((size_t)r * 3 * FPc + g * FPc + f) * FPc + k];
      else       v = gru_Whh[((size_t)r * 3 * FPc + (g - 3) * FPc + f) * FPc + k];
    }
    Wpk[i] = (__bf16)v;
    return;
  }
  i -= nW;
  if (i < nA) {
    int j = i & 7, fl = (i >> 3) & 31, c = (i >> 8) & 3;
    int T = i >> 10;
    int kt = T % 7; T /= 7;
    int ft = T % 7; int r = T / 7;
    int f = ft * 32 + fl, k = kt * 32 + c * 8 + j;
    float v = (f < FPc && k < FPc) ? attend_W[((size_t)r * FPc + f) * FPc + k] : 0.f;
    Apk[i] = (__bf16)v;
  }
}

// -------------------- generic small GEMM (f32): Y[rows][200] ------------------------
template<int KD, int EPI>
__global__ __launch_bounds__(256) void gemm8x1(
    const float* __restrict__ X, const float* __restrict__ WT,
    const float* __restrict__ bias, const float* __restrict__ sumw,
    float* __restrict__ Y, __bf16* __restrict__ Yb) {
  constexpr int TR = 8, LDP = 12;
  __shared__ float xT[KD * LDP];
  const int row0 = blockIdx.x * TR;
  const int tid = threadIdx.x;
  for (int e = tid; e < TR * KD; e += 256) {
    int r = e / KD, g = e - r * KD;
    xT[g * LDP + r] = X[(size_t)row0 * KD + e];
  }
  __syncthreads();
  const int f = tid;
  if (f < FPc) {
    float acc[TR];
    #pragma unroll
    for (int r = 0; r < TR; ++r) acc[r] = 0.f;
    #pragma unroll 4
    for (int g = 0; g < KD; ++g) {
      float w = WT[(size_t)g * FPc + f];
      float4 x0 = *reinterpret_cast<const float4*>(&xT[g * LDP]);
      float4 x1 = *reinterpret_cast<const float4*>(&xT[g * LDP + 4]);
      acc[0] = fmaf(x0.x, w, acc[0]); acc[1] = fmaf(x0.y, w, acc[1]);
      acc[2] = fmaf(x0.z, w, acc[2]); acc[3] = fmaf(x0.w, w, acc[3]);
      acc[4] = fmaf(x1.x, w, acc[4]); acc[5] = fmaf(x1.y, w, acc[5]);
      acc[6] = fmaf(x1.z, w, acc[6]); acc[7] = fmaf(x1.w, w, acc[7]);
    }
    #pragma unroll
    for (int r = 0; r < TR; ++r) {
      if (EPI == 0) {
        Yb[(size_t)(row0 + r) * FPc + f] = (__bf16)acc[r];
      } else {
        float v = fmaf(sumw[row0 + r], bias[f], acc[r]);
        Y[(size_t)(row0 + r) * FPc + f] = eluf(v);
      }
    }
  }
}

// -------------------- fused atom_list GEMM: atom_fc + neighbor-P ---------------------
__global__ __launch_bounds__(256) void gemm_dual(
    const float* __restrict__ X,       // atom_list [BL][39]
    const float* __restrict__ W1T,     // atomfcT [39][200]
    const float* __restrict__ b1,      // atom_fc_b
    const float* __restrict__ W2T,     // naT (atom part) [39][200]
    float* __restrict__ Yraw,          // AV[0] raw atom_lin
    __bf16* __restrict__ Hb,           // Hb0 (leaky, KP-padded)
    __bf16* __restrict__ Pb) {
  constexpr int KD = AFc, TR = 8, LDP = 12;
  __shared__ float xT[KD * LDP];
  const int row0 = blockIdx.x * TR;
  const int tid = threadIdx.x;
  for (int e = tid; e < TR * KD; e += 256) {
    int r = e / KD, g = e - r * KD;
    xT[g * LDP + r] = X[(size_t)row0 * KD + e];
  }
  __syncthreads();
  const int f = tid;
  if (f < FPc) {
    float a1[TR], a2[TR];
    #pragma unroll
    for (int r = 0; r < TR; ++r) { a1[r] = 0.f; a2[r] = 0.f; }
    #pragma unroll 2
    for (int g = 0; g < KD; ++g) {
      float w1 = W1T[(size_t)g * FPc + f];
      float w2 = W2T[(size_t)g * FPc + f];
      float4 x0 = *reinterpret_cast<const float4*>(&xT[g * LDP]);
      float4 x1 = *reinterpret_cast<const float4*>(&xT[g * LDP + 4]);
      float xs[8] = {x0.x, x0.y, x0.z, x0.w, x1.x, x1.y, x1.z, x1.w};
      #pragma unroll
      for (int r = 0; r < TR; ++r) {
        a1[r] = fmaf(xs[r], w1, a1[r]);
        a2[r] = fmaf(xs[r], w2, a2[r]);
      }
    }
    const float bf = b1[f];
    #pragma unroll
    for (int r = 0; r < TR; ++r) {
      float v = a1[r] + bf;
      Yraw[(size_t)(row0 + r) * FPc + f] = v;
      Hb[(size_t)(row0 + r) * KP + f] = (__bf16)leaky(v);
      Pb[(size_t)(row0 + r) * FPc + f] = (__bf16)a2[r];
    }
  } else if (f < KP) {
    #pragma unroll
    for (int r = 0; r < TR; ++r) Hb[(size_t)(row0 + r) * KP + f] = (__bf16)0.f;
  }
}

// -------------------- fused attend + GRU v2 ------------------------------------------
__global__ __launch_bounds__(256, 2) void attgru_mfma(
    const __bf16* __restrict__ WNb, const __bf16* __restrict__ Apk,
    const float* __restrict__ attb, const float* __restrict__ SW,
    const __bf16* __restrict__ Hin, __bf16* __restrict__ Hout,
    const __bf16* __restrict__ Wpk,
    const float* __restrict__ bih, const float* __restrict__ bhh,
    float* __restrict__ actOut) {
  __shared__ __align__(16) __bf16 smem[40960];   // 81920 B
  __bf16* xcL = smem;                             // [wv4][kt7][1024] = 57344 B
  __bf16* Bs  = smem + 28672;                     // [buf2][g6][1024] = 24576 B
  const int tid = threadIdx.x, wv = tid >> 6, lane = tid & 63;
  const size_t row0 = (size_t)blockIdx.x * 128;
  const int fl = lane & 31;

  // ---- attend phase: xc = elu(WN @ attW.T + sumw*b) -> LDS (A-frag layout) ----
  {
    bf16x8 af[7][2];
    const __bf16* sw_ = WNb + (row0 + wv * 32 + fl) * KP + (lane >> 5) * 8;
    #pragma unroll
    for (int kt = 0; kt < 7; ++kt)
      #pragma unroll
      for (int h = 0; h < 2; ++h)
        af[kt][h] = *(const bf16x8*)(sw_ + kt * 32 + h * 16);

    const int xbase = wv * 7168 + ((fl >> 3) & 3) * 256 + (fl & 7);
    #pragma unroll
    for (int ft = 0; ft < 7; ++ft) {
      f32x16 acc = zero16();
      #pragma unroll
      for (int kt = 0; kt < 7; ++kt) {
        const __bf16* bt = Apk + ((size_t)ft * 7 + kt) * 1024 + lane * 8;
        bf16x8 b0 = *(const bf16x8*)(bt);
        bf16x8 b1 = *(const bf16x8*)(bt + 512);
        acc = __builtin_amdgcn_mfma_f32_32x32x16_bf16(af[kt][0], b0, acc, 0, 0, 0);
        acc = __builtin_amdgcn_mfma_f32_32x32x16_bf16(af[kt][1], b1, acc, 0, 0, 0);
      }
      const int f = ft * 32 + fl;
      const bool fok = f < FPc;
      const float bf = fok ? attb[f] : 0.f;
      #pragma unroll
      for (int reg = 0; reg < 16; ++reg) {
        int rl = (reg & 3) + 8 * (reg >> 2) + 4 * (lane >> 5);
        float v = fok ? eluf(acc[reg] + SW[row0 + wv * 32 + rl] * bf) : 0.f;
        xcL[xbase + ft * 1024 + rl * 8] = (__bf16)v;
      }
    }
  }
  // (no barrier: each wave reads back only its own region; lgkmcnt orders LDS)

  // ---- h fragments into registers ----
  bf16x8 hf[7][2];
  {
    const __bf16* sh = Hin + (row0 + wv * 32 + fl) * KP + (lane >> 5) * 8;
    #pragma unroll
    for (int kt = 0; kt < 7; ++kt)
      #pragma unroll
      for (int h = 0; h < 2; ++h)
        hf[kt][h] = *(const bf16x8*)(sh + kt * 32 + h * 16);
  }

  auto stageB = [&](int ft, int kt, int buf) {
    #pragma unroll
    for (int m3 = 0; m3 < 3; ++m3) {
      int m = wv * 3 + m3;               // 0..11
      int g = m >> 1, half = m & 1;
      const __bf16* s = Wpk + ((size_t)(g * 7 + ft) * 7 + kt) * 1024 + half * 512 + lane * 8;
      glds16(s, Bs + buf * 6144 + g * 1024 + half * 512);
    }
  };
  stageB(0, 0, 0);

  f32x16 gacc[6];
  #pragma unroll
  for (int g = 0; g < 6; ++g) gacc[g] = zero16();

  for (int ft = 0; ft < 7; ++ft) {
    #pragma unroll
    for (int kt = 0; kt < 7; ++kt) {
      const int it = ft * 7 + kt;
      const int buf = it & 1;
      const int nft = (kt == 6) ? ft + 1 : ft;
      const int nkt = (kt == 6) ? 0 : kt + 1;
      __builtin_amdgcn_sched_barrier(0);
      if (it < 48) stageB(nft, nkt, buf ^ 1);
      else         stageB(6, 6, buf ^ 1);          // dummy: keep 3 outstanding
      __builtin_amdgcn_sched_barrier(0);
      asm volatile("s_waitcnt vmcnt(3)" ::: "memory");
      __builtin_amdgcn_sched_barrier(0);
      __builtin_amdgcn_s_barrier();
      __builtin_amdgcn_sched_barrier(0);
      #pragma unroll
      for (int h = 0; h < 2; ++h) {
        bf16x8 xch = *(const bf16x8*)(xcL + wv * 7168 + kt * 1024 + h * 512 + lane * 8);
        bf16x8 hh = hf[kt][h];
        const __bf16* bb = Bs + buf * 6144 + h * 512 + lane * 8;
        bf16x8 b0 = *(const bf16x8*)(bb);
        bf16x8 b1 = *(const bf16x8*)(bb + 1024);
        bf16x8 b2 = *(const bf16x8*)(bb + 2048);
        bf16x8 b3 = *(const bf16x8*)(bb + 3072);
        bf16x8 b4 = *(const bf16x8*)(bb + 4096);
        bf16x8 b5 = *(const bf16x8*)(bb + 5120);
        __builtin_amdgcn_s_setprio(1);
        gacc[0] = __builtin_amdgcn_mfma_f32_32x32x16_bf16(xch, b0, gacc[0], 0, 0, 0);
        gacc[1] = __builtin_amdgcn_mfma_f32_32x32x16_bf16(xch, b1, gacc[1], 0, 0, 0);
        gacc[2] = __builtin_amdgcn_mfma_f32_32x32x16_bf16(xch, b2, gacc[2], 0, 0, 0);
        gacc[3] = __builtin_amdgcn_mfma_f32_32x32x16_bf16(hh, b3, gacc[3], 0, 0, 0);
        gacc[4] = __builtin_amdgcn_mfma_f32_32x32x16_bf16(hh, b4, gacc[4], 0, 0, 0);
        gacc[5] = __builtin_amdgcn_mfma_f32_32x32x16_bf16(hh, b5, gacc[5], 0, 0, 0);
        __builtin_amdgcn_s_setprio(0);
      }
      if (kt == 6) {
        const int f = ft * 32 + fl;
        const bool fok = f < FPc;
        float bir = 0, biz = 0, bin_ = 0, bhr = 0, bhz = 0, bhn = 0;
        if (fok) {
          bir = bih[f]; biz = bih[FPc + f]; bin_ = bih[2 * FPc + f];
          bhr = bhh[f]; bhz = bhh[FPc + f]; bhn = bhh[2 * FPc + f];
        }
        #pragma unroll
        for (int reg = 0; reg < 16; ++reg) {
          int rl = (reg & 3) + 8 * (reg >> 2) + 4 * (lane >> 5);
          size_t row = row0 + wv * 32 + rl;
          if (fok) {
            float ho = (float)Hin[row * KP + f];
            float rg_ = sigm(gacc[0][reg] + bir + gacc[3][reg] + bhr);
            float zg  = sigm(gacc[1][reg] + biz + gacc[4][reg] + bhz);
            float ng  = tanhf(gacc[2][reg] + bin_ + rg_ * (gacc[5][reg] + bhn));
            float hp = (1.f - zg) * ng + zg * ho;
            Hout[row * KP + f] = (__bf16)hp;
            actOut[row * FPc + f] = fmaxf(hp, 0.f);
          } else {
            Hout[row * KP + f] = (__bf16)0.f;
          }
        }
        #pragma unroll
        for (int g = 0; g < 6; ++g) gacc[g] = zero16();
      }
      __builtin_amdgcn_sched_barrier(0);
      __builtin_amdgcn_s_barrier();
      __builtin_amdgcn_sched_barrier(0);
    }
  }
}

// -------------------- attn round r>=1: per-molecule, 8 waves ------------------------
__global__ __launch_bounds__(512) void attn_molN(
    const __bf16* __restrict__ Hb,       // [BL][KP]
    const int* __restrict__ adl,
    const float* __restrict__ alW,       // +r*2*FP
    const float* __restrict__ albp,      // +r
    float* __restrict__ attnOut, __bf16* __restrict__ WNb, float* __restrict__ SW) {
  __shared__ __align__(16) __bf16 actL[128 * 224];
  __shared__ float saL[128], snL[128];
  const int b = blockIdx.x;
  const int tid = threadIdx.x, wv = tid >> 6, lane = tid & 63;
  const bool l36 = lane < 36;

  // ---- stage act = relu(Hb) ----
  {
    const uint4* src = (const uint4*)(Hb + (size_t)b * 128 * KP);
    uint4* dst = (uint4*)actL;
    for (int i = tid; i < 128 * 224 / 8; i += 512) {
      uint4 v = src[i];
      uint32_t c[4] = {v.x, v.y, v.z, v.w};
      #pragma unroll
      for (int j = 0; j < 4; ++j) {
        uint32_t lo = c[j] & 0xffffu, hi = c[j] >> 16;
        if (lo & 0x8000u) lo = 0;
        if (hi & 0x8000u) hi = 0;
        c[j] = lo | (hi << 16);
      }
      dst[i] = make_uint4(c[0], c[1], c[2], c[3]);
    }
  }
  float wa0x = alW[2 * lane], wa0y = alW[2 * lane + 1];
  float wa1x = l36 ? alW[128 + 2 * lane] : 0.f, wa1y = l36 ? alW[129 + 2 * lane] : 0.f;
  float wn0x = alW[FPc + 2 * lane], wn0y = alW[FPc + 2 * lane + 1];
  float wn1x = l36 ? alW[FPc + 128 + 2 * lane] : 0.f, wn1y = l36 ? alW[FPc + 129 + 2 * lane] : 0.f;
  const float ab = albp[0];
  __syncthreads();

  // ---- per-atom dots: 16 atoms per wave ----
  for (int i = 0; i < 16; ++i) {
    int l = wv * 16 + i;
    const uint32_t* rowp = (const uint32_t*)(actL + l * 224);
    uint32_t u0 = rowp[lane];
    uint32_t u1 = l36 ? rowp[64 + lane] : 0u;
    float x0 = bflo(u0), y0 = bfhi(u0), x1 = bflo(u1), y1 = bfhi(u1);
    float psa = x0 * wa0x + y0 * wa0y + x1 * wa1x + y1 * wa1y;
    float psn = x0 * wn0x + y0 * wn0y + x1 * wn1x + y1 * wn1y;
    psa = wave_sum(psa);
    psn = wave_sum(psn);
    if (lane == 0) { saL[l] = psa; snL[l] = psn; }
  }
  __syncthreads();

  // ---- per-row: softmax over 6 neighbors + weighted sum (16 rows per wave) ----
  for (int i = 0; i < 16; ++i) {
    const int row = wv * 16 + i;
    const size_t grow = (size_t)b * 128 + row;
    int gk = (lane < Kc) ? adl[grow * Kc + lane] : 0;
    int ai[Kc];
    #pragma unroll
    for (int k = 0; k < Kc; ++k) ai[k] = __shfl(gk, k);
    const float sarow = saL[row];
    float s[Kc]; bool pad[Kc]; float mx = -3.0e38f;
    #pragma unroll
    for (int k = 0; k < Kc; ++k) {
      pad[k] = (ai[k] == Lc - 1);
      s[k] = leaky(sarow + snL[ai[k]] + ab) + (pad[k] ? NEGC : 0.f);
      mx = fmaxf(mx, s[k]);
    }
    float e[Kc], sum = 0.f;
    #pragma unroll
    for (int k = 0; k < Kc; ++k) { e[k] = __expf(s[k] - mx); sum += e[k]; }
    float inv = 1.f / sum;
    float w[Kc], sw = 0.f;
    #pragma unroll
    for (int k = 0; k < Kc; ++k) { w[k] = pad[k] ? 0.f : e[k] * inv; sw += w[k]; }
    if (lane < Kc) attnOut[grow * Kc + lane] = w[lane];
    if (lane == 0) SW[grow] = sw;
    float a0 = 0.f, b0 = 0.f, a1 = 0.f, b1 = 0.f;
    #pragma unroll
    for (int k = 0; k < Kc; ++k) {
      const uint32_t* nr = (const uint32_t*)(actL + ai[k] * 224);
      uint32_t u0 = nr[lane];
      uint32_t u1 = l36 ? nr[64 + lane] : 0u;
      a0 = fmaf(w[k], bflo(u0), a0); b0 = fmaf(w[k], bfhi(u0), b0);
      a1 = fmaf(w[k], bflo(u1), a1); b1 = fmaf(w[k], bfhi(u1), b1);
    }
    __bf16* wr = WNb + grow * KP;
    ushort2 o0; o0.x = f2bu(a0); o0.y = f2bu(b0);
    *(ushort2*)(wr + 2 * lane) = o0;
    if (lane < 48) {
      float va = l36 ? a1 : 0.f, vb = l36 ? b1 : 0.f;
      ushort2 o1; o1.x = f2bu(va); o1.y = f2bu(vb);
      *(ushort2*)(wr + 128 + 2 * lane) = o1;
    }
  }
}

// -------------------- attn round r==0: per-molecule block, 8 waves, v-reg cache -----
__global__ __launch_bounds__(512) void attn_mol0(
    const __bf16* __restrict__ Pb, const __bf16* __restrict__ Qb,
    const float* __restrict__ nbb, const __bf16* __restrict__ Hb0,
    const int* __restrict__ adl, const int* __restrict__ bdl,
    const float* __restrict__ alW, const float* __restrict__ albp,
    float* __restrict__ attnOut, __bf16* __restrict__ WNb, float* __restrict__ SW) {
  __shared__ __align__(16) __bf16 Pl[128 * 200];
  __shared__ __align__(16) __bf16 Ql[128 * 200];
  __shared__ float nbbL[200];
  __shared__ float saL[128];
  const int b = blockIdx.x;
  const int tid = threadIdx.x, wv = tid >> 6, lane = tid & 63;
  const bool l36 = lane < 36;

  {
    const uint4* sp = (const uint4*)(Pb + (size_t)b * 128 * FPc);
    const uint4* sq = (const uint4*)(Qb + (size_t)b * 128 * FPc);
    uint4* dp = (uint4*)Pl;
    uint4* dq = (uint4*)Ql;
    for (int i = tid; i < 128 * 200 / 8; i += 512) { dp[i] = sp[i]; dq[i] = sq[i]; }
    for (int i = tid; i < FPc; i += 512) nbbL[i] = nbb[i];
  }
  float wa0x = alW[2 * lane], wa0y = alW[2 * lane + 1];
  float wa1x = l36 ? alW[128 + 2 * lane] : 0.f, wa1y = l36 ? alW[129 + 2 * lane] : 0.f;
  float wn0x = alW[FPc + 2 * lane], wn0y = alW[FPc + 2 * lane + 1];
  float wn1x = l36 ? alW[FPc + 128 + 2 * lane] : 0.f, wn1y = l36 ? alW[FPc + 129 + 2 * lane] : 0.f;
  const float ab = albp[0];

  for (int i = 0; i < 16; ++i) {
    int l = wv * 16 + i;
    const uint32_t* hr = (const uint32_t*)(Hb0 + ((size_t)b * 128 + l) * KP);
    uint32_t u0 = hr[lane];
    uint32_t u1 = l36 ? hr[64 + lane] : 0u;
    float psa = bflo(u0) * wa0x + bfhi(u0) * wa0y + bflo(u1) * wa1x + bfhi(u1) * wa1y;
    psa = wave_sum(psa);
    if (lane == 0) saL[l] = psa;
  }
  __syncthreads();

  const float n0x = nbbL[2 * lane], n0y = nbbL[2 * lane + 1];
  const float n1x = l36 ? nbbL[128 + 2 * lane] : 0.f, n1y = l36 ? nbbL[129 + 2 * lane] : 0.f;

  for (int i = 0; i < 16; ++i) {
    const int row = wv * 16 + i;
    const size_t grow = (size_t)b * 128 + row;
    int gk = (lane < Kc) ? adl[grow * Kc + lane] : 0;
    int hk = (lane < Kc) ? bdl[grow * Kc + lane] : 0;
    int ai[Kc], bi[Kc];
    #pragma unroll
    for (int k = 0; k < Kc; ++k) { ai[k] = __shfl(gk, k); bi[k] = __shfl(hk, k); }
    float v0x[Kc], v0y[Kc], v1x[Kc], v1y[Kc], p[Kc];
    #pragma unroll
    for (int k = 0; k < Kc; ++k) {
      const uint32_t* pr = (const uint32_t*)(Pl + ai[k] * 200);
      const uint32_t* qr = (const uint32_t*)(Ql + bi[k] * 200);
      uint32_t up0 = pr[lane], uq0 = qr[lane];
      uint32_t up1 = l36 ? pr[64 + lane] : 0u, uq1 = l36 ? qr[64 + lane] : 0u;
      v0x[k] = leaky(bflo(up0) + bflo(uq0) + n0x);
      v0y[k] = leaky(bfhi(up0) + bfhi(uq0) + n0y);
      v1x[k] = l36 ? leaky(bflo(up1) + bflo(uq1) + n1x) : 0.f;
      v1y[k] = l36 ? leaky(bfhi(up1) + bfhi(uq1) + n1y) : 0.f;
      p[k] = v0x[k] * wn0x + v0y[k] * wn0y + v1x[k] * wn1x + v1y[k] * wn1y;
    }
    #pragma unroll
    for (int k = 0; k < Kc; ++k) p[k] = wave_sum(p[k]);
    const float sarow = saL[row];
    float s[Kc]; bool pad[Kc]; float mx = -3.0e38f;
    #pragma unroll
    for (int k = 0; k < Kc; ++k) {
      pad[k] = (ai[k] == Lc - 1);
      s[k] = leaky(sarow + p[k] + ab) + (pad[k] ? NEGC : 0.f);
      mx = fmaxf(mx, s[k]);
    }
    float e[Kc], sum = 0.f;
    #pragma unroll
    for (int k = 0; k < Kc; ++k) { e[k] = __expf(s[k] - mx); sum += e[k]; }
    float inv = 1.f / sum;
    float w[Kc], sw = 0.f;
    #pragma unroll
    for (int k = 0; k < Kc; ++k) { w[k] = pad[k] ? 0.f : e[k] * inv; sw += w[k]; }
    if (lane < Kc) attnOut[grow * Kc + lane] = w[lane];
    if (lane == 0) SW[grow] = sw;
    float a0 = 0.f, b0v = 0.f, a1 = 0.f, b1v = 0.f;
    #pragma unroll
    for (int k = 0; k < Kc; ++k) {
      a0  = fmaf(w[k], v0x[k], a0);
      b0v = fmaf(w[k], v0y[k], b0v);
      a1  = fmaf(w[k], v1x[k], a1);
      b1v = fmaf(w[k], v1y[k], b1v);
    }
    __bf16* wr = WNb + grow * KP;
    ushort2 o0; o0.x = f2bu(a0); o0.y = f2bu(b0v);
    *(ushort2*)(wr + 2 * lane) = o0;
    if (lane < 48) {
      float va = l36 ? a1 : 0.f, vb = l36 ? b1v : 0.f;
      ushort2 o1; o1.x = f2bu(va); o1.y = f2bu(vb);
      *(ushort2*)(wr + 128 + 2 * lane) = o1;
    }
  }
}

// -------------------- fused GRU f32 (mol path, 512 rows) -----------------------------
__global__ __launch_bounds__(256) void gru8(
    const float* __restrict__ XC, float* __restrict__ H,
    const float* __restrict__ WihT, const float* __restrict__ WhhT,
    const float* __restrict__ bih, const float* __restrict__ bhh,
    float* __restrict__ actOut, float* __restrict__ unbOut, float* __restrict__ vizOut) {
  constexpr int TR = 8, LDP = 12;
  __shared__ float xc[FPc * LDP];
  __shared__ float xh[FPc * LDP];
  const int row0 = blockIdx.x * TR;
  const int tid = threadIdx.x;
  for (int e = tid; e < TR * FPc; e += 256) {
    int r = e / FPc, g = e - r * FPc;
    xc[g * LDP + r] = XC[(size_t)row0 * FPc + e];
    xh[g * LDP + r] = H[(size_t)row0 * FPc + e];
  }
  __syncthreads();
  const int f = tid;
  if (f < FPc) {
    float air[8], aiz[8], ain[8], ahr[8], ahz[8], ahn[8];
    const float bir = bih[f], biz = bih[f + 200], bin_ = bih[f + 400];
    const float bhr = bhh[f], bhz = bhh[f + 200], bhn = bhh[f + 400];
    #pragma unroll
    for (int r = 0; r < 8; ++r) {
      air[r] = bir; aiz[r] = biz; ain[r] = bin_;
      ahr[r] = bhr; ahz[r] = bhz; ahn[r] = bhn;
    }
    #pragma unroll 2
    for (int g = 0; g < FPc; ++g) {
      const float* wi = &WihT[(size_t)g * 600 + f];
      const float* wh = &WhhT[(size_t)g * 600 + f];
      float wir = wi[0], wiz = wi[200], win = wi[400];
      float whr = wh[0], whz = wh[200], whn = wh[400];
      float4 c0 = *reinterpret_cast<const float4*>(&xc[g * LDP]);
      float4 c1 = *reinterpret_cast<const float4*>(&xc[g * LDP + 4]);
      float4 h0 = *reinterpret_cast<const float4*>(&xh[g * LDP]);
      float4 h1 = *reinterpret_cast<const float4*>(&xh[g * LDP + 4]);
      float cx[8] = {c0.x, c0.y, c0.z, c0.w, c1.x, c1.y, c1.z, c1.w};
      float hx[8] = {h0.x, h0.y, h0.z, h0.w, h1.x, h1.y, h1.z, h1.w};
      #pragma unroll
      for (int r = 0; r < 8; ++r) {
        air[r] = fmaf(cx[r], wir, air[r]);
        aiz[r] = fmaf(cx[r], wiz, aiz[r]);
        ain[r] = fmaf(cx[r], win, ain[r]);
        ahr[r] = fmaf(hx[r], whr, ahr[r]);
        ahz[r] = fmaf(hx[r], whz, ahz[r]);
        ahn[r] = fmaf(hx[r], whn, ahn[r]);
      }
    }
    #pragma unroll
    for (int r = 0; r < 8; ++r) {
      float rg = sigm(air[r] + ahr[r]);
      float zg = sigm(aiz[r] + ahz[r]);
      float ng = tanhf(fmaf(rg, ahn[r], ain[r]));
      float hv = xh[f * LDP + r];
      float hp = (1.f - zg) * ng + zg * hv;
      size_t idx = (size_t)(row0 + r) * FPc + f;
      H[idx] = hp;
      float a = fmaxf(hp, 0.f);
      if (actOut) actOut[idx] = a;
      if (unbOut) unbOut[idx] = hp;
      if (vizOut) vizOut[idx] = a;
    }
  }
}

// -------------------- mol-level sum over atoms ---------------------------------------
__global__ __launch_bounds__(256) void mol_sum_k(
    const __bf16* __restrict__ Hb, const float* __restrict__ ACT, const float* __restrict__ mask,
    float* __restrict__ unb0, float* __restrict__ viz0,
    float* __restrict__ molfeat, float* __restrict__ actmol) {
  const int b = blockIdx.x;
  __shared__ float mk[Lc];
  for (int l = threadIdx.x; l < Lc; l += 256) mk[l] = mask[b * Lc + l];
  __syncthreads();
  const int f = threadIdx.x;
  if (f < FPc) {
    float s1 = 0.f, s2 = 0.f;
    for (int l = 0; l < Lc; ++l) {
      float m = mk[l];
      s1 = fmaf((float)Hb[((size_t)b * Lc + l) * KP + f], m, s1);
      s2 = fmaf(ACT[((size_t)b * Lc + l) * FPc + f], m, s2);
    }
    unb0[b * FPc + f] = s1;
    viz0[b * FPc + f] = s2;
    molfeat[b * FPc + f] = s2;
    actmol[b * FPc + f] = fmaxf(s2, 0.f);
  }
}

// -------------------- mol-level attention over L atoms -------------------------------
__global__ __launch_bounds__(256) void mol_attn_k(
    const float* __restrict__ act, const float* __restrict__ actmol,
    const float* __restrict__ malW, const float* __restrict__ malb,
    const float* __restrict__ mask,
    float* __restrict__ attnOut, float* __restrict__ wact, float* __restrict__ msumw) {
  const int b = blockIdx.x;
  __shared__ float sa_s;
  __shared__ float sn[Lc];
  __shared__ float wl[Lc];
  __shared__ float redmx[2], redsum[2], redsw[2];
  const int wv = threadIdx.x >> 6, lane = threadIdx.x & 63;
  if (wv == 0) {
    float p = 0.f;
    for (int f = lane; f < FPc; f += 64) p = fmaf(actmol[b * FPc + f], malW[f], p);
    float s = wave_sum(p);
    if (lane == 0) sa_s = s;
  }
  for (int l = wv; l < Lc; l += 4) {
    float p = 0.f;
    for (int f = lane; f < FPc; f += 64)
      p = fmaf(act[((size_t)b * Lc + l) * FPc + f], malW[FPc + f], p);
    float s = wave_sum(p);
    if (lane == 0) sn[l] = s;
  }
  __syncthreads();
  const int l = threadIdx.x;
  float sc = -3.0e38f, mval = 0.f;
  if (l < Lc) {
    mval = mask[b * Lc + l];
    sc = leaky(sa_s + sn[l] + malb[0]) + (mval == 0.f ? NEGC : 0.f);
  }
  float m = sc;
  #pragma unroll
  for (int o = 32; o >= 1; o >>= 1) m = fmaxf(m, __shfl_xor(m, o));
  if (lane == 0 && wv < 2) redmx[wv] = m;
  __syncthreads();
  float mx = fmaxf(redmx[0], redmx[1]);
  float e = (l < Lc) ? __expf(sc - mx) : 0.f;
  float s = e;
  #pragma unroll
  for (int o = 32; o >= 1; o >>= 1) s += __shfl_xor(s, o);
  if (lane == 0 && wv < 2) redsum[wv] = s;
  __syncthreads();
  float tot = redsum[0] + redsum[1];
  float w = 0.f;
  if (l < Lc) {
    w = e / tot * mval;
    wl[l] = w;
    attnOut[(size_t)b * Lc + l] = w;
  }
  float swp = w;
  #pragma unroll
  for (int o = 32; o >= 1; o >>= 1) swp += __shfl_xor(swp, o);
  if (lane == 0 && wv < 2) redsw[wv] = swp;
  __syncthreads();
  if (threadIdx.x == 0) msumw[b] = redsw[0] + redsw[1];
  const int f = threadIdx.x;
  if (f < FPc) {
    float a = 0.f;
    for (int l2 = 0; l2 < Lc; ++l2)
      a = fmaf(wl[l2], act[((size_t)b * Lc + l2) * FPc + f], a);
    wact[b * FPc + f] = a;
  }
}

// -------------------- final prediction -----------------------------------------------
__global__ __launch_bounds__(256) void pred_k(
    const float* __restrict__ molfeat, const float* __restrict__ outW,
    const float* __restrict__ outb, float* __restrict__ pred) {
  const int wv = threadIdx.x >> 6, lane = threadIdx.x & 63;
  const int b = blockIdx.x * 4 + wv;
  if (b < Bc) {
    float p = 0.f;
    for (int f = lane; f < FPc; f += 64) p = fmaf(molfeat[b * FPc + f], outW[f], p);
    float s = wave_sum(p);
    if (lane == 0) pred[b] = s + outb[0];
  }
}

extern "C" void kernel_launch(void* const* d_in, const int* in_sizes, int n_in,
                              void* d_out, int out_size, void* d_ws, size_t ws_size,
                              hipStream_t stream) {
  const float* atom_list = (const float*)d_in[0];
  const float* bond_list = (const float*)d_in[1];
  const int*   adl       = (const int*)d_in[2];
  const int*   bdl       = (const int*)d_in[3];
  const float* mask      = (const float*)d_in[4];
  const float* atom_fc_W = (const float*)d_in[5];
  const float* atom_fc_b = (const float*)d_in[6];
  const float* nb_W      = (const float*)d_in[7];
  const float* nb_b      = (const float*)d_in[8];
  const float* align_W   = (const float*)d_in[9];
  const float* align_b   = (const float*)d_in[10];
  const float* attend_W  = (const float*)d_in[11];
  const float* attend_b  = (const float*)d_in[12];
  const float* gru_Wih   = (const float*)d_in[13];
  const float* gru_Whh   = (const float*)d_in[14];
  const float* gru_bih   = (const float*)d_in[15];
  const float* gru_bhh   = (const float*)d_in[16];
  const float* mal_W     = (const float*)d_in[17];
  const float* mal_b     = (const float*)d_in[18];
  const float* matt_W    = (const float*)d_in[19];
  const float* matt_b    = (const float*)d_in[20];
  const float* mWih      = (const float*)d_in[21];
  const float* mWhh      = (const float*)d_in[22];
  const float* mbih      = (const float*)d_in[23];
  const float* mbhh      = (const float*)d_in[24];
  const float* out_W     = (const float*)d_in[25];
  const float* out_b     = (const float*)d_in[26];

  float* out  = (float*)d_out;
  float* AV   = out;                                  // (4,B,L,FP)
  float* ATTN = AV + (size_t)4 * BL * FPc;            // (3,B,L,K)
  float* MV   = ATTN + (size_t)Rc * BL * Kc;          // (3,B,FP)
  float* MU   = MV + (size_t)3 * Bc * FPc;            // (3,B,FP)
  float* MA   = MU + (size_t)3 * Bc * FPc;            // (2,B,L)
  float* PRED = MA + (size_t)Tc * Bc * Lc;            // (B,1)

  char* w = (char*)d_ws;
  __bf16* Hb0  = (__bf16*)w; w += (size_t)BL * KP * 2;
  __bf16* Hb1  = (__bf16*)w; w += (size_t)BL * KP * 2;
  __bf16* WNb  = (__bf16*)w; w += (size_t)BL * KP * 2;
  __bf16* Pb   = (__bf16*)w; w += (size_t)BL * FPc * 2;
  __bf16* Qb   = (__bf16*)w; w += (size_t)BL * FPc * 2;
  __bf16* Wpk  = (__bf16*)w; w += (size_t)Rc * 6 * 49 * 1024 * 2;
  __bf16* Apk  = (__bf16*)w; w += (size_t)Rc * 49 * 1024 * 2;
  float* SW    = (float*)w;  w += (size_t)BL * 4;
  float* MOLF  = (float*)w;  w += (size_t)Bc * FPc * 4;
  float* ACTM  = (float*)w;  w += (size_t)Bc * FPc * 4;
  float* WACT  = (float*)w;  w += (size_t)Bc * FPc * 4;
  float* MCTX  = (float*)w;  w += (size_t)Bc * FPc * 4;
  float* MSW   = (float*)w;  w += (size_t)Bc * 4;
  float* atomfcT = (float*)w; w += (size_t)AFc * FPc * 4;
  float* naT     = (float*)w; w += (size_t)(AFc + BFc) * FPc * 4;
  float* mattT   = (float*)w; w += (size_t)FPc * FPc * 4;
  float* mWihT   = (float*)w; w += (size_t)FPc * 600 * 4;
  float* mWhhT   = (float*)w; w += (size_t)FPc * 600 * 4;

  {
    const int nprep = FPc * AFc + FPc * (AFc + BFc) + FPc * FPc + 2 * 600 * FPc
                    + Rc * 6 * 49 * 1024 + Rc * 49 * 1024;
    prep_k<<<(nprep + 255) / 256, 256, 0, stream>>>(
        atom_fc_W, nb_W, matt_W, mWih, mWhh, gru_Wih, gru_Whh, attend_W,
        atomfcT, naT, mattT, mWihT, mWhhT, Wpk, Apk);
  }

  // fused: atom_lin raw -> AV[0], h0 -> Hb0, P -> Pb (one pass over atom_list)
  gemm_dual<<<BL / 8, 256, 0, stream>>>(atom_list, atomfcT, atom_fc_b, naT, AV, Hb0, Pb);
  gemm8x1<BFc, 0><<<BL / 8, 256, 0, stream>>>(bond_list, naT + AFc * FPc, nullptr, nullptr, nullptr, Qb);

  __bf16* Hbuf[2] = {Hb0, Hb1};
  for (int r = 0; r < Rc; ++r) {
    if (r == 0) {
      attn_mol0<<<Bc, 512, 0, stream>>>(Pb, Qb, nb_b, Hb0, adl, bdl,
          align_W, align_b, ATTN, WNb, SW);
    } else {
      attn_molN<<<Bc, 512, 0, stream>>>(Hbuf[r & 1], adl,
          align_W + (size_t)r * 2 * FPc, align_b + r,
          ATTN + (size_t)r * BL * Kc, WNb, SW);
    }
    attgru_mfma<<<BL / 128, 256, 0, stream>>>(WNb, Apk + (size_t)r * 49 * 1024,
        attend_b + (size_t)r * FPc, SW,
        Hbuf[r & 1], Hbuf[(r + 1) & 1],
        Wpk + (size_t)r * 6 * 49 * 1024, gru_bih + (size_t)r * 3 * FPc, gru_bhh + (size_t)r * 3 * FPc,
        AV + (size_t)(r + 1) * BL * FPc);
  }

  mol_sum_k<<<Bc, 256, 0, stream>>>(Hbuf[Rc & 1], AV + (size_t)3 * BL * FPc, mask, MU, MV, MOLF, ACTM);
  for (int t = 0; t < Tc; ++t) {
    mol_attn_k<<<Bc, 256, 0, stream>>>(AV + (size_t)3 * BL * FPc, ACTM, mal_W, mal_b, mask,
        MA + (size_t)t * Bc * Lc, WACT, MSW);
    gemm8x1<FPc, 2><<<Bc / 8, 256, 0, stream>>>(WACT, mattT, matt_b, MSW, MCTX, nullptr);
    gru8<<<Bc / 8, 256, 0, stream>>>(MCTX, MOLF, mWihT, mWhhT, mbih, mbhh,
        ACTM, MU + (size_t)(t + 1) * Bc * FPc, MV + (size_t)(t + 1) * Bc * FPc);
  }
  pred_k<<<Bc / 4, 256, 0, stream>>>(MOLF, out_W, out_b, PRED);
}

// Round 11
// 973.614 us; speedup vs baseline: 1.3170x; 1.0380x over previous
//
#include <hip/hip_runtime.h>
#include <stdint.h>

#define Bc 512
#define Lc 128
#define Kc 6
#define AFc 39
#define BFc 10
#define FPc 200
#define Rc 3
#define Tc 2
constexpr int BL = Bc * Lc;          // 65536
constexpr int KP = 224;              // padded K / F for MFMA
constexpr float SLOPE = 0.01f;
constexpr float NEGC = -9e8f;

typedef __attribute__((ext_vector_type(8))) __bf16 bf16x8;
typedef __attribute__((ext_vector_type(16))) float f32x16;

__device__ __forceinline__ float leaky(float x) { return x >= 0.f ? x : SLOPE * x; }
__device__ __forceinline__ float sigm(float x) { return 1.f / (1.f + __expf(-x)); }
__device__ __forceinline__ float eluf(float x) { return x > 0.f ? x : expm1f(x); }
__device__ __forceinline__ float wave_sum(float v) {
  #pragma unroll
  for (int m = 32; m >= 1; m >>= 1) v += __shfl_xor(v, m);
  return v;
}
__device__ __forceinline__ float bflo(uint32_t u) { return __uint_as_float(u << 16); }
__device__ __forceinline__ float bfhi(uint32_t u) { return __uint_as_float(u & 0xffff0000u); }
__device__ __forceinline__ unsigned short f2bu(float x) {
  __bf16 b = (__bf16)x;
  return __builtin_bit_cast(unsigned short, b);
}
__device__ __forceinline__ void glds16(const void* g, void* l) {
  __builtin_amdgcn_global_load_lds((const __attribute__((address_space(1))) uint32_t*)g,
      (__attribute__((address_space(3))) uint32_t*)l, 16, 0, 0);
}
__device__ __forceinline__ f32x16 zero16() {
  f32x16 z;
  #pragma unroll
  for (int i = 0; i < 16; ++i) z[i] = 0.f;
  return z;
}

// -------------------- unified prep: 5 transposes + 2 weight packs --------------------
__global__ void prep_k(
    const float* __restrict__ atom_fc_W, const float* __restrict__ nb_W,
    const float* __restrict__ matt_W, const float* __restrict__ mWih,
    const float* __restrict__ mWhh, const float* __restrict__ gru_Wih,
    const float* __restrict__ gru_Whh, const float* __restrict__ attend_W,
    float* __restrict__ atomfcT, float* __restrict__ naT, float* __restrict__ mattT,
    float* __restrict__ mWihT, float* __restrict__ mWhhT,
    __bf16* __restrict__ Wpk, __bf16* __restrict__ Apk) {
  int i = blockIdx.x * 256 + threadIdx.x;
  const int n0 = FPc * AFc, n1 = FPc * (AFc + BFc), n2 = FPc * FPc;
  const int n3 = 600 * FPc, n4 = 600 * FPc;
  const int nW = Rc * 6 * 49 * 1024, nA = Rc * 49 * 1024;
  if (i < n0) { int r = i / AFc, c = i % AFc; atomfcT[c * FPc + r] = atom_fc_W[i]; return; }
  i -= n0;
  if (i < n1) { int r = i / (AFc + BFc), c = i % (AFc + BFc); naT[c * FPc + r] = nb_W[i]; return; }
  i -= n1;
  if (i < n2) { int r = i / FPc, c = i % FPc; mattT[c * FPc + r] = matt_W[i]; return; }
  i -= n2;
  if (i < n3) { int r = i / FPc, c = i % FPc; mWihT[c * 600 + r] = mWih[i]; return; }
  i -= n3;
  if (i < n4) { int r = i / FPc, c = i % FPc; mWhhT[c * 600 + r] = mWhh[i]; return; }
  i -= n4;
  if (i < nW) {
    int j = i & 7, fl = (i >> 3) & 31, c = (i >> 8) & 3;
    int T = i >> 10;
    int kt = T % 7; T /= 7;
    int ft = T % 7; T /= 7;
    int g = T % 6;  int r = T / 6;
    int f = ft * 32 + fl, k = kt * 32 + c * 8 + j;
    float v = 0.f;
    if (f < FPc && k < FPc) {
      if (g < 3) v = gru_Wih[((size_t)r * 3 * FPc + g * FPc + f) * FPc + k];
      else       v = gru_Whh[((size_t)r * 3 * FPc + (g - 3) * FPc + f) * FPc + k];
    }
    Wpk[i] = (__bf16)v;
    return;
  }
  i -= nW;
  if (i < nA) {
    int j = i & 7, fl = (i >> 3) & 31, c = (i >> 8) & 3;
    int T = i >> 10;
    int kt = T % 7; T /= 7;
    int ft = T % 7; int r = T / 7;
    int f = ft * 32 + fl, k = kt * 32 + c * 8 + j;
    float v = (f < FPc && k < FPc) ? attend_W[((size_t)r * FPc + f) * FPc + k] : 0.f;
    Apk[i] = (__bf16)v;
  }
}

// -------------------- generic small GEMM (f32): Yb[rows][200] bf16 -------------------
template<int KD>
__global__ __launch_bounds__(256) void gemm8x1(
    const float* __restrict__ X, const float* __restrict__ WT,
    __bf16* __restrict__ Yb) {
  constexpr int TR = 8, LDP = 12;
  __shared__ float xT[KD * LDP];
  const int row0 = blockIdx.x * TR;
  const int tid = threadIdx.x;
  for (int e = tid; e < TR * KD; e += 256) {
    int r = e / KD, g = e - r * KD;
    xT[g * LDP + r] = X[(size_t)row0 * KD + e];
  }
  __syncthreads();
  const int f = tid;
  if (f < FPc) {
    float acc[TR];
    #pragma unroll
    for (int r = 0; r < TR; ++r) acc[r] = 0.f;
    #pragma unroll 4
    for (int g = 0; g < KD; ++g) {
      float w = WT[(size_t)g * FPc + f];
      float4 x0 = *reinterpret_cast<const float4*>(&xT[g * LDP]);
      float4 x1 = *reinterpret_cast<const float4*>(&xT[g * LDP + 4]);
      acc[0] = fmaf(x0.x, w, acc[0]); acc[1] = fmaf(x0.y, w, acc[1]);
      acc[2] = fmaf(x0.z, w, acc[2]); acc[3] = fmaf(x0.w, w, acc[3]);
      acc[4] = fmaf(x1.x, w, acc[4]); acc[5] = fmaf(x1.y, w, acc[5]);
      acc[6] = fmaf(x1.z, w, acc[6]); acc[7] = fmaf(x1.w, w, acc[7]);
    }
    #pragma unroll
    for (int r = 0; r < TR; ++r)
      Yb[(size_t)(row0 + r) * FPc + f] = (__bf16)acc[r];
  }
}

// -------------------- fused atom_list GEMM: atom_fc + neighbor-P ---------------------
__global__ __launch_bounds__(256) void gemm_dual(
    const float* __restrict__ X, const float* __restrict__ W1T,
    const float* __restrict__ b1, const float* __restrict__ W2T,
    float* __restrict__ Yraw, __bf16* __restrict__ Hb, __bf16* __restrict__ Pb) {
  constexpr int KD = AFc, TR = 8, LDP = 12;
  __shared__ float xT[KD * LDP];
  const int row0 = blockIdx.x * TR;
  const int tid = threadIdx.x;
  for (int e = tid; e < TR * KD; e += 256) {
    int r = e / KD, g = e - r * KD;
    xT[g * LDP + r] = X[(size_t)row0 * KD + e];
  }
  __syncthreads();
  const int f = tid;
  if (f < FPc) {
    float a1[TR], a2[TR];
    #pragma unroll
    for (int r = 0; r < TR; ++r) { a1[r] = 0.f; a2[r] = 0.f; }
    #pragma unroll 2
    for (int g = 0; g < KD; ++g) {
      float w1 = W1T[(size_t)g * FPc + f];
      float w2 = W2T[(size_t)g * FPc + f];
      float4 x0 = *reinterpret_cast<const float4*>(&xT[g * LDP]);
      float4 x1 = *reinterpret_cast<const float4*>(&xT[g * LDP + 4]);
      float xs[8] = {x0.x, x0.y, x0.z, x0.w, x1.x, x1.y, x1.z, x1.w};
      #pragma unroll
      for (int r = 0; r < TR; ++r) {
        a1[r] = fmaf(xs[r], w1, a1[r]);
        a2[r] = fmaf(xs[r], w2, a2[r]);
      }
    }
    const float bf = b1[f];
    #pragma unroll
    for (int r = 0; r < TR; ++r) {
      float v = a1[r] + bf;
      Yraw[(size_t)(row0 + r) * FPc + f] = v;
      Hb[(size_t)(row0 + r) * KP + f] = (__bf16)leaky(v);
      Pb[(size_t)(row0 + r) * FPc + f] = (__bf16)a2[r];
    }
  } else if (f < KP) {
    #pragma unroll
    for (int r = 0; r < TR; ++r) Hb[(size_t)(row0 + r) * KP + f] = (__bf16)0.f;
  }
}

// -------------------- fused attend + GRU v3 ------------------------------------------
// xc in regs via per-tile LDS bounce (2KB/wave scratch); Bs 4-deep, vmcnt(9) 3-ahead.
__global__ __launch_bounds__(256, 2) void attgru_mfma(
    const __bf16* __restrict__ WNb, const __bf16* __restrict__ Apk,
    const float* __restrict__ attb, const float* __restrict__ SW,
    const __bf16* __restrict__ Hin, __bf16* __restrict__ Hout,
    const __bf16* __restrict__ Wpk,
    const float* __restrict__ bih, const float* __restrict__ bhh,
    float* __restrict__ actOut) {
  __shared__ __align__(16) __bf16 smem[28672];   // 57344 B
  __bf16* scr = smem;                             // [wv4][1024] = 8192 B
  __bf16* Bs  = smem + 4096;                      // [buf4][g6][1024] = 49152 B
  const int tid = threadIdx.x, wv = tid >> 6, lane = tid & 63;
  const size_t row0 = (size_t)blockIdx.x * 128;
  const int fl = lane & 31;

  // ---- h fragments (issued first; latency hides under attend) ----
  bf16x8 hf[7][2];
  {
    const __bf16* sh = Hin + (row0 + wv * 32 + fl) * KP + (lane >> 5) * 8;
    #pragma unroll
    for (int kt = 0; kt < 7; ++kt)
      #pragma unroll
      for (int h = 0; h < 2; ++h)
        hf[kt][h] = *(const bf16x8*)(sh + kt * 32 + h * 16);
  }

  // ---- attend phase: per-tile compute + LDS bounce -> xcf regs ----
  bf16x8 xcf[7][2];
  {
    bf16x8 af[7][2];
    const __bf16* sw_ = WNb + (row0 + wv * 32 + fl) * KP + (lane >> 5) * 8;
    #pragma unroll
    for (int kt = 0; kt < 7; ++kt)
      #pragma unroll
      for (int h = 0; h < 2; ++h)
        af[kt][h] = *(const bf16x8*)(sw_ + kt * 32 + h * 16);

    const int xbase = wv * 1024 + ((fl >> 3) & 3) * 256 + (fl & 7);
    #pragma unroll 1
    for (int ft = 0; ft < 7; ++ft) {
      f32x16 acc = zero16();
      #pragma unroll
      for (int kt = 0; kt < 7; ++kt) {
        const __bf16* bt = Apk + ((size_t)ft * 7 + kt) * 1024 + lane * 8;
        bf16x8 b0 = *(const bf16x8*)(bt);
        bf16x8 b1 = *(const bf16x8*)(bt + 512);
        acc = __builtin_amdgcn_mfma_f32_32x32x16_bf16(af[kt][0], b0, acc, 0, 0, 0);
        acc = __builtin_amdgcn_mfma_f32_32x32x16_bf16(af[kt][1], b1, acc, 0, 0, 0);
      }
      const int f = ft * 32 + fl;
      const bool fok = f < FPc;
      const float bf = fok ? attb[f] : 0.f;
      #pragma unroll
      for (int reg = 0; reg < 16; ++reg) {
        int rl = (reg & 3) + 8 * (reg >> 2) + 4 * (lane >> 5);
        float v = fok ? eluf(acc[reg] + SW[row0 + wv * 32 + rl] * bf) : 0.f;
        scr[xbase + rl * 8] = (__bf16)v;
      }
      // intra-wave transpose readback (lgkmcnt-ordered by compiler)
      xcf[ft][0] = *(const bf16x8*)(scr + wv * 1024 + lane * 8);
      xcf[ft][1] = *(const bf16x8*)(scr + wv * 1024 + 512 + lane * 8);
    }
  }

  auto stageB = [&](int ft, int kt, int buf) {
    #pragma unroll
    for (int m3 = 0; m3 < 3; ++m3) {
      int m = wv * 3 + m3;               // 0..11
      int g = m >> 1, half = m & 1;
      const __bf16* s = Wpk + ((size_t)(g * 7 + ft) * 7 + kt) * 1024 + half * 512 + lane * 8;
      glds16(s, Bs + buf * 6144 + g * 1024 + half * 512);
    }
  };
  asm volatile("s_waitcnt vmcnt(0)" ::: "memory");
  stageB(0, 0, 0);
  stageB(0, 1, 1);
  stageB(0, 2, 2);

  f32x16 gacc[6];
  #pragma unroll
  for (int g = 0; g < 6; ++g) gacc[g] = zero16();

  for (int ft = 0; ft < 7; ++ft) {
    #pragma unroll
    for (int kt = 0; kt < 7; ++kt) {
      const int it = ft * 7 + kt;
      const int buf = it & 3;
      const int nt = it + 3;
      const int sft = (nt < 49) ? nt / 7 : 6;
      const int skt = (nt < 49) ? nt % 7 : 6;
      __builtin_amdgcn_sched_barrier(0);
      stageB(sft, skt, nt & 3);
      __builtin_amdgcn_sched_barrier(0);
      asm volatile("s_waitcnt vmcnt(9)" ::: "memory");
      __builtin_amdgcn_sched_barrier(0);
      __builtin_amdgcn_s_barrier();
      __builtin_amdgcn_sched_barrier(0);
      #pragma unroll
      for (int h = 0; h < 2; ++h) {
        bf16x8 xch = xcf[kt][h];
        bf16x8 hh = hf[kt][h];
        const __bf16* bb = Bs + buf * 6144 + h * 512 + lane * 8;
        bf16x8 b0 = *(const bf16x8*)(bb);
        bf16x8 b1 = *(const bf16x8*)(bb + 1024);
        bf16x8 b2 = *(const bf16x8*)(bb + 2048);
        bf16x8 b3 = *(const bf16x8*)(bb + 3072);
        bf16x8 b4 = *(const bf16x8*)(bb + 4096);
        bf16x8 b5 = *(const bf16x8*)(bb + 5120);
        __builtin_amdgcn_s_setprio(1);
        gacc[0] = __builtin_amdgcn_mfma_f32_32x32x16_bf16(xch, b0, gacc[0], 0, 0, 0);
        gacc[1] = __builtin_amdgcn_mfma_f32_32x32x16_bf16(xch, b1, gacc[1], 0, 0, 0);
        gacc[2] = __builtin_amdgcn_mfma_f32_32x32x16_bf16(xch, b2, gacc[2], 0, 0, 0);
        gacc[3] = __builtin_amdgcn_mfma_f32_32x32x16_bf16(hh, b3, gacc[3], 0, 0, 0);
        gacc[4] = __builtin_amdgcn_mfma_f32_32x32x16_bf16(hh, b4, gacc[4], 0, 0, 0);
        gacc[5] = __builtin_amdgcn_mfma_f32_32x32x16_bf16(hh, b5, gacc[5], 0, 0, 0);
        __builtin_amdgcn_s_setprio(0);
      }
      if (kt == 6) {
        const int f = ft * 32 + fl;
        const bool fok = f < FPc;
        float bir = 0, biz = 0, bin_ = 0, bhr = 0, bhz = 0, bhn = 0;
        if (fok) {
          bir = bih[f]; biz = bih[FPc + f]; bin_ = bih[2 * FPc + f];
          bhr = bhh[f]; bhz = bhh[FPc + f]; bhn = bhh[2 * FPc + f];
        }
        #pragma unroll
        for (int reg = 0; reg < 16; ++reg) {
          int rl = (reg & 3) + 8 * (reg >> 2) + 4 * (lane >> 5);
          size_t row = row0 + wv * 32 + rl;
          if (fok) {
            float ho = (float)Hin[row * KP + f];
            float rg_ = sigm(gacc[0][reg] + bir + gacc[3][reg] + bhr);
            float zg  = sigm(gacc[1][reg] + biz + gacc[4][reg] + bhz);
            float ng  = tanhf(gacc[2][reg] + bin_ + rg_ * (gacc[5][reg] + bhn));
            float hp = (1.f - zg) * ng + zg * ho;
            Hout[row * KP + f] = (__bf16)hp;
            actOut[row * FPc + f] = fmaxf(hp, 0.f);
          } else {
            Hout[row * KP + f] = (__bf16)0.f;
          }
        }
        #pragma unroll
        for (int g = 0; g < 6; ++g) gacc[g] = zero16();
      }
      __builtin_amdgcn_sched_barrier(0);
      __builtin_amdgcn_s_barrier();
      __builtin_amdgcn_sched_barrier(0);
    }
  }
}

// -------------------- attn round r>=1: per-molecule, 8 waves ------------------------
__global__ __launch_bounds__(512) void attn_molN(
    const __bf16* __restrict__ Hb, const int* __restrict__ adl,
    const float* __restrict__ alW, const float* __restrict__ albp,
    float* __restrict__ attnOut, __bf16* __restrict__ WNb, float* __restrict__ SW) {
  __shared__ __align__(16) __bf16 actL[128 * 224];
  __shared__ float saL[128], snL[128];
  const int b = blockIdx.x;
  const int tid = threadIdx.x, wv = tid >> 6, lane = tid & 63;
  const bool l36 = lane < 36;

  {
    const uint4* src = (const uint4*)(Hb + (size_t)b * 128 * KP);
    uint4* dst = (uint4*)actL;
    for (int i = tid; i < 128 * 224 / 8; i += 512) {
      uint4 v = src[i];
      uint32_t c[4] = {v.x, v.y, v.z, v.w};
      #pragma unroll
      for (int j = 0; j < 4; ++j) {
        uint32_t lo = c[j] & 0xffffu, hi = c[j] >> 16;
        if (lo & 0x8000u) lo = 0;
        if (hi & 0x8000u) hi = 0;
        c[j] = lo | (hi << 16);
      }
      dst[i] = make_uint4(c[0], c[1], c[2], c[3]);
    }
  }
  float wa0x = alW[2 * lane], wa0y = alW[2 * lane + 1];
  float wa1x = l36 ? alW[128 + 2 * lane] : 0.f, wa1y = l36 ? alW[129 + 2 * lane] : 0.f;
  float wn0x = alW[FPc + 2 * lane], wn0y = alW[FPc + 2 * lane + 1];
  float wn1x = l36 ? alW[FPc + 128 + 2 * lane] : 0.f, wn1y = l36 ? alW[FPc + 129 + 2 * lane] : 0.f;
  const float ab = albp[0];
  __syncthreads();

  for (int i = 0; i < 16; ++i) {
    int l = wv * 16 + i;
    const uint32_t* rowp = (const uint32_t*)(actL + l * 224);
    uint32_t u0 = rowp[lane];
    uint32_t u1 = l36 ? rowp[64 + lane] : 0u;
    float x0 = bflo(u0), y0 = bfhi(u0), x1 = bflo(u1), y1 = bfhi(u1);
    float psa = x0 * wa0x + y0 * wa0y + x1 * wa1x + y1 * wa1y;
    float psn = x0 * wn0x + y0 * wn0y + x1 * wn1x + y1 * wn1y;
    psa = wave_sum(psa);
    psn = wave_sum(psn);
    if (lane == 0) { saL[l] = psa; snL[l] = psn; }
  }
  __syncthreads();

  for (int i = 0; i < 16; ++i) {
    const int row = wv * 16 + i;
    const size_t grow = (size_t)b * 128 + row;
    int gk = (lane < Kc) ? adl[grow * Kc + lane] : 0;
    int ai[Kc];
    #pragma unroll
    for (int k = 0; k < Kc; ++k) ai[k] = __shfl(gk, k);
    const float sarow = saL[row];
    float s[Kc]; bool pad[Kc]; float mx = -3.0e38f;
    #pragma unroll
    for (int k = 0; k < Kc; ++k) {
      pad[k] = (ai[k] == Lc - 1);
      s[k] = leaky(sarow + snL[ai[k]] + ab) + (pad[k] ? NEGC : 0.f);
      mx = fmaxf(mx, s[k]);
    }
    float e[Kc], sum = 0.f;
    #pragma unroll
    for (int k = 0; k < Kc; ++k) { e[k] = __expf(s[k] - mx); sum += e[k]; }
    float inv = 1.f / sum;
    float w[Kc], sw = 0.f;
    #pragma unroll
    for (int k = 0; k < Kc; ++k) { w[k] = pad[k] ? 0.f : e[k] * inv; sw += w[k]; }
    if (lane < Kc) attnOut[grow * Kc + lane] = w[lane];
    if (lane == 0) SW[grow] = sw;
    float a0 = 0.f, b0 = 0.f, a1 = 0.f, b1 = 0.f;
    #pragma unroll
    for (int k = 0; k < Kc; ++k) {
      const uint32_t* nr = (const uint32_t*)(actL + ai[k] * 224);
      uint32_t u0 = nr[lane];
      uint32_t u1 = l36 ? nr[64 + lane] : 0u;
      a0 = fmaf(w[k], bflo(u0), a0); b0 = fmaf(w[k], bfhi(u0), b0);
      a1 = fmaf(w[k], bflo(u1), a1); b1 = fmaf(w[k], bfhi(u1), b1);
    }
    __bf16* wr = WNb + grow * KP;
    ushort2 o0; o0.x = f2bu(a0); o0.y = f2bu(b0);
    *(ushort2*)(wr + 2 * lane) = o0;
    if (lane < 48) {
      float va = l36 ? a1 : 0.f, vb = l36 ? b1 : 0.f;
      ushort2 o1; o1.x = f2bu(va); o1.y = f2bu(vb);
      *(ushort2*)(wr + 128 + 2 * lane) = o1;
    }
  }
}

// -------------------- attn round r==0: per-molecule block, 8 waves, v-reg cache -----
__global__ __launch_bounds__(512) void attn_mol0(
    const __bf16* __restrict__ Pb, const __bf16* __restrict__ Qb,
    const float* __restrict__ nbb, const __bf16* __restrict__ Hb0,
    const int* __restrict__ adl, const int* __restrict__ bdl,
    const float* __restrict__ alW, const float* __restrict__ albp,
    float* __restrict__ attnOut, __bf16* __restrict__ WNb, float* __restrict__ SW) {
  __shared__ __align__(16) __bf16 Pl[128 * 200];
  __shared__ __align__(16) __bf16 Ql[128 * 200];
  __shared__ float nbbL[200];
  __shared__ float saL[128];
  const int b = blockIdx.x;
  const int tid = threadIdx.x, wv = tid >> 6, lane = tid & 63;
  const bool l36 = lane < 36;

  {
    const uint4* sp = (const uint4*)(Pb + (size_t)b * 128 * FPc);
    const uint4* sq = (const uint4*)(Qb + (size_t)b * 128 * FPc);
    uint4* dp = (uint4*)Pl;
    uint4* dq = (uint4*)Ql;
    for (int i = tid; i < 128 * 200 / 8; i += 512) { dp[i] = sp[i]; dq[i] = sq[i]; }
    for (int i = tid; i < FPc; i += 512) nbbL[i] = nbb[i];
  }
  float wa0x = alW[2 * lane], wa0y = alW[2 * lane + 1];
  float wa1x = l36 ? alW[128 + 2 * lane] : 0.f, wa1y = l36 ? alW[129 + 2 * lane] : 0.f;
  float wn0x = alW[FPc + 2 * lane], wn0y = alW[FPc + 2 * lane + 1];
  float wn1x = l36 ? alW[FPc + 128 + 2 * lane] : 0.f, wn1y = l36 ? alW[FPc + 129 + 2 * lane] : 0.f;
  const float ab = albp[0];

  for (int i = 0; i < 16; ++i) {
    int l = wv * 16 + i;
    const uint32_t* hr = (const uint32_t*)(Hb0 + ((size_t)b * 128 + l) * KP);
    uint32_t u0 = hr[lane];
    uint32_t u1 = l36 ? hr[64 + lane] : 0u;
    float psa = bflo(u0) * wa0x + bfhi(u0) * wa0y + bflo(u1) * wa1x + bfhi(u1) * wa1y;
    psa = wave_sum(psa);
    if (lane == 0) saL[l] = psa;
  }
  __syncthreads();

  const float n0x = nbbL[2 * lane], n0y = nbbL[2 * lane + 1];
  const float n1x = l36 ? nbbL[128 + 2 * lane] : 0.f, n1y = l36 ? nbbL[129 + 2 * lane] : 0.f;

  for (int i = 0; i < 16; ++i) {
    const int row = wv * 16 + i;
    const size_t grow = (size_t)b * 128 + row;
    int gk = (lane < Kc) ? adl[grow * Kc + lane] : 0;
    int hk = (lane < Kc) ? bdl[grow * Kc + lane] : 0;
    int ai[Kc], bi[Kc];
    #pragma unroll
    for (int k = 0; k < Kc; ++k) { ai[k] = __shfl(gk, k); bi[k] = __shfl(hk, k); }
    float v0x[Kc], v0y[Kc], v1x[Kc], v1y[Kc], p[Kc];
    #pragma unroll
    for (int k = 0; k < Kc; ++k) {
      const uint32_t* pr = (const uint32_t*)(Pl + ai[k] * 200);
      const uint32_t* qr = (const uint32_t*)(Ql + bi[k] * 200);
      uint32_t up0 = pr[lane], uq0 = qr[lane];
      uint32_t up1 = l36 ? pr[64 + lane] : 0u, uq1 = l36 ? qr[64 + lane] : 0u;
      v0x[k] = leaky(bflo(up0) + bflo(uq0) + n0x);
      v0y[k] = leaky(bfhi(up0) + bfhi(uq0) + n0y);
      v1x[k] = l36 ? leaky(bflo(up1) + bflo(uq1) + n1x) : 0.f;
      v1y[k] = l36 ? leaky(bfhi(up1) + bfhi(uq1) + n1y) : 0.f;
      p[k] = v0x[k] * wn0x + v0y[k] * wn0y + v1x[k] * wn1x + v1y[k] * wn1y;
    }
    #pragma unroll
    for (int k = 0; k < Kc; ++k) p[k] = wave_sum(p[k]);
    const float sarow = saL[row];
    float s[Kc]; bool pad[Kc]; float mx = -3.0e38f;
    #pragma unroll
    for (int k = 0; k < Kc; ++k) {
      pad[k] = (ai[k] == Lc - 1);
      s[k] = leaky(sarow + p[k] + ab) + (pad[k] ? NEGC : 0.f);
      mx = fmaxf(mx, s[k]);
    }
    float e[Kc], sum = 0.f;
    #pragma unroll
    for (int k = 0; k < Kc; ++k) { e[k] = __expf(s[k] - mx); sum += e[k]; }
    float inv = 1.f / sum;
    float w[Kc], sw = 0.f;
    #pragma unroll
    for (int k = 0; k < Kc; ++k) { w[k] = pad[k] ? 0.f : e[k] * inv; sw += w[k]; }
    if (lane < Kc) attnOut[grow * Kc + lane] = w[lane];
    if (lane == 0) SW[grow] = sw;
    float a0 = 0.f, b0v = 0.f, a1 = 0.f, b1v = 0.f;
    #pragma unroll
    for (int k = 0; k < Kc; ++k) {
      a0  = fmaf(w[k], v0x[k], a0);
      b0v = fmaf(w[k], v0y[k], b0v);
      a1  = fmaf(w[k], v1x[k], a1);
      b1v = fmaf(w[k], v1y[k], b1v);
    }
    __bf16* wr = WNb + grow * KP;
    ushort2 o0; o0.x = f2bu(a0); o0.y = f2bu(b0v);
    *(ushort2*)(wr + 2 * lane) = o0;
    if (lane < 48) {
      float va = l36 ? a1 : 0.f, vb = l36 ? b1v : 0.f;
      ushort2 o1; o1.x = f2bu(va); o1.y = f2bu(vb);
      *(ushort2*)(wr + 128 + 2 * lane) = o1;
    }
  }
}

// -------------------- fused mol phase: sum + T x (attn, attend, gru) + pred ----------
// one block per molecule; intermediates in LDS/regs.
__global__ __launch_bounds__(256) void mol_fused(
    const __bf16* __restrict__ Hb, const float* __restrict__ ACT,
    const float* __restrict__ mask,
    const float* __restrict__ malW, const float* __restrict__ malb,
    const float* __restrict__ mattT, const float* __restrict__ matt_b,
    const float* __restrict__ mWihT, const float* __restrict__ mWhhT,
    const float* __restrict__ mbih, const float* __restrict__ mbhh,
    const float* __restrict__ outW, const float* __restrict__ outb,
    float* __restrict__ MV, float* __restrict__ MU, float* __restrict__ MA,
    float* __restrict__ PRED) {
  const int b = blockIdx.x;
  __shared__ float mk[Lc];
  __shared__ float molf[FPc], actm[FPc], wact[FPc], ctx[FPc];
  __shared__ float snL[Lc], wl[Lc];
  __shared__ float red[4], red2[4];
  const int tid = threadIdx.x, wv = tid >> 6, lane = tid & 63;
  const float* actB = ACT + (size_t)b * Lc * FPc;

  for (int l = tid; l < Lc; l += 256) mk[l] = mask[b * Lc + l];
  __syncthreads();
  const int f = tid;
  if (f < FPc) {
    float s1 = 0.f, s2 = 0.f;
    for (int l = 0; l < Lc; ++l) {
      float m = mk[l];
      s1 = fmaf((float)Hb[((size_t)b * Lc + l) * KP + f], m, s1);
      s2 = fmaf(actB[l * FPc + f], m, s2);
    }
    MU[b * FPc + f] = s1;
    MV[b * FPc + f] = s2;
    molf[f] = s2;
    actm[f] = fmaxf(s2, 0.f);
  }
  __syncthreads();

  for (int t = 0; t < Tc; ++t) {
    // sa = dot(actm, malW[:200])
    {
      float p = 0.f;
      for (int i = tid; i < FPc; i += 256) p = fmaf(actm[i], malW[i], p);
      p = wave_sum(p);
      if (lane == 0) red[wv] = p;
    }
    // sn[l]
    for (int l = wv; l < Lc; l += 4) {
      float p = 0.f;
      for (int fi = lane; fi < FPc; fi += 64) p = fmaf(actB[l * FPc + fi], malW[FPc + fi], p);
      p = wave_sum(p);
      if (lane == 0) snL[l] = p;
    }
    __syncthreads();
    const float sa = red[0] + red[1] + red[2] + red[3];
    // softmax over l
    const int l = tid;
    float sc = -3.0e38f, mval = 0.f;
    if (l < Lc) {
      mval = mk[l];
      sc = leaky(sa + snL[l] + malb[0]) + (mval == 0.f ? NEGC : 0.f);
    }
    float m = sc;
    #pragma unroll
    for (int o = 32; o >= 1; o >>= 1) m = fmaxf(m, __shfl_xor(m, o));
    if (lane == 0) red[wv] = m;
    __syncthreads();
    float mx = fmaxf(red[0], red[1]);
    float e = (l < Lc) ? __expf(sc - mx) : 0.f;
    float s = e;
    #pragma unroll
    for (int o = 32; o >= 1; o >>= 1) s += __shfl_xor(s, o);
    if (lane == 0) red2[wv] = s;
    __syncthreads();
    float tot = red2[0] + red2[1];
    float w = 0.f;
    if (l < Lc) {
      w = e / tot * mval;
      wl[l] = w;
      MA[(size_t)t * Bc * Lc + b * Lc + l] = w;
    }
    float swp = w;
    #pragma unroll
    for (int o = 32; o >= 1; o >>= 1) swp += __shfl_xor(swp, o);
    if (lane == 0) red[wv] = swp;
    __syncthreads();
    const float sumw = red[0] + red[1];
    // wact[f] = sum_l wl[l]*act[l][f]
    if (f < FPc) {
      float a = 0.f;
      for (int l2 = 0; l2 < Lc; ++l2) a = fmaf(wl[l2], actB[l2 * FPc + f], a);
      wact[f] = a;
    }
    __syncthreads();
    // ctx[f] = elu(sum_g wact[g]*mattT[g*200+f] + sumw*matt_b[f])
    if (f < FPc) {
      float a = 0.f;
      #pragma unroll 4
      for (int g = 0; g < FPc; ++g) a = fmaf(wact[g], mattT[(size_t)g * FPc + f], a);
      ctx[f] = eluf(fmaf(sumw, matt_b[f], a));
    }
    __syncthreads();
    // GRU (thread f owns feature f)
    float hp = 0.f;
    if (f < FPc) {
      float air = mbih[f], aiz = mbih[FPc + f], ain = mbih[2 * FPc + f];
      float ahr = mbhh[f], ahz = mbhh[FPc + f], ahn = mbhh[2 * FPc + f];
      #pragma unroll 2
      for (int g = 0; g < FPc; ++g) {
        float xc = ctx[g], hx = molf[g];
        const float* wi = &mWihT[(size_t)g * 600 + f];
        const float* wh = &mWhhT[(size_t)g * 600 + f];
        air = fmaf(xc, wi[0], air);
        aiz = fmaf(xc, wi[200], aiz);
        ain = fmaf(xc, wi[400], ain);
        ahr = fmaf(hx, wh[0], ahr);
        ahz = fmaf(hx, wh[200], ahz);
        ahn = fmaf(hx, wh[400], ahn);
      }
      float rg = sigm(air + ahr);
      float zg = sigm(aiz + ahz);
      float ng = tanhf(fmaf(rg, ahn, ain));
      hp = (1.f - zg) * ng + zg * molf[f];
      MU[(size_t)(t + 1) * Bc * FPc + b * FPc + f] = hp;
      MV[(size_t)(t + 1) * Bc * FPc + b * FPc + f] = fmaxf(hp, 0.f);
    }
    __syncthreads();
    if (f < FPc) {
      molf[f] = hp;
      actm[f] = fmaxf(hp, 0.f);
    }
    __syncthreads();
  }
  // pred
  {
    float p = 0.f;
    for (int i = tid; i < FPc; i += 256) p = fmaf(molf[i], outW[i], p);
    p = wave_sum(p);
    if (lane == 0) red[wv] = p;
    __syncthreads();
    if (tid == 0) PRED[b] = red[0] + red[1] + red[2] + red[3] + outb[0];
  }
}

extern "C" void kernel_launch(void* const* d_in, const int* in_sizes, int n_in,
                              void* d_out, int out_size, void* d_ws, size_t ws_size,
                              hipStream_t stream) {
  const float* atom_list = (const float*)d_in[0];
  const float* bond_list = (const float*)d_in[1];
  const int*   adl       = (const int*)d_in[2];
  const int*   bdl       = (const int*)d_in[3];
  const float* mask      = (const float*)d_in[4];
  const float* atom_fc_W = (const float*)d_in[5];
  const float* atom_fc_b = (const float*)d_in[6];
  const float* nb_W      = (const float*)d_in[7];
  const float* nb_b      = (const float*)d_in[8];
  const float* align_W   = (const float*)d_in[9];
  const float* align_b   = (const float*)d_in[10];
  const float* attend_W  = (const float*)d_in[11];
  const float* attend_b  = (const float*)d_in[12];
  const float* gru_Wih   = (const float*)d_in[13];
  const float* gru_Whh   = (const float*)d_in[14];
  const float* gru_bih   = (const float*)d_in[15];
  const float* gru_bhh   = (const float*)d_in[16];
  const float* mal_W     = (const float*)d_in[17];
  const float* mal_b     = (const float*)d_in[18];
  const float* matt_W    = (const float*)d_in[19];
  const float* matt_b    = (const float*)d_in[20];
  const float* mWih      = (const float*)d_in[21];
  const float* mWhh      = (const float*)d_in[22];
  const float* mbih      = (const float*)d_in[23];
  const float* mbhh      = (const float*)d_in[24];
  const float* out_W     = (const float*)d_in[25];
  const float* out_b     = (const float*)d_in[26];

  float* out  = (float*)d_out;
  float* AV   = out;                                  // (4,B,L,FP)
  float* ATTN = AV + (size_t)4 * BL * FPc;            // (3,B,L,K)
  float* MV   = ATTN + (size_t)Rc * BL * Kc;          // (3,B,FP)
  float* MU   = MV + (size_t)3 * Bc * FPc;            // (3,B,FP)
  float* MA   = MU + (size_t)3 * Bc * FPc;            // (2,B,L)
  float* PRED = MA + (size_t)Tc * Bc * Lc;            // (B,1)

  char* w = (char*)d_ws;
  __bf16* Hb0  = (__bf16*)w; w += (size_t)BL * KP * 2;
  __bf16* Hb1  = (__bf16*)w; w += (size_t)BL * KP * 2;
  __bf16* WNb  = (__bf16*)w; w += (size_t)BL * KP * 2;
  __bf16* Pb   = (__bf16*)w; w += (size_t)BL * FPc * 2;
  __bf16* Qb   = (__bf16*)w; w += (size_t)BL * FPc * 2;
  __bf16* Wpk  = (__bf16*)w; w += (size_t)Rc * 6 * 49 * 1024 * 2;
  __bf16* Apk  = (__bf16*)w; w += (size_t)Rc * 49 * 1024 * 2;
  float* SW    = (float*)w;  w += (size_t)BL * 4;
  float* atomfcT = (float*)w; w += (size_t)AFc * FPc * 4;
  float* naT     = (float*)w; w += (size_t)(AFc + BFc) * FPc * 4;
  float* mattT   = (float*)w; w += (size_t)FPc * FPc * 4;
  float* mWihT   = (float*)w; w += (size_t)FPc * 600 * 4;
  float* mWhhT   = (float*)w; w += (size_t)FPc * 600 * 4;

  {
    const int nprep = FPc * AFc + FPc * (AFc + BFc) + FPc * FPc + 2 * 600 * FPc
                    + Rc * 6 * 49 * 1024 + Rc * 49 * 1024;
    prep_k<<<(nprep + 255) / 256, 256, 0, stream>>>(
        atom_fc_W, nb_W, matt_W, mWih, mWhh, gru_Wih, gru_Whh, attend_W,
        atomfcT, naT, mattT, mWihT, mWhhT, Wpk, Apk);
  }

  gemm_dual<<<BL / 8, 256, 0, stream>>>(atom_list, atomfcT, atom_fc_b, naT, AV, Hb0, Pb);
  gemm8x1<BFc><<<BL / 8, 256, 0, stream>>>(bond_list, naT + AFc * FPc, Qb);

  __bf16* Hbuf[2] = {Hb0, Hb1};
  for (int r = 0; r < Rc; ++r) {
    if (r == 0) {
      attn_mol0<<<Bc, 512, 0, stream>>>(Pb, Qb, nb_b, Hb0, adl, bdl,
          align_W, align_b, ATTN, WNb, SW);
    } else {
      attn_molN<<<Bc, 512, 0, stream>>>(Hbuf[r & 1], adl,
          align_W + (size_t)r * 2 * FPc, align_b + r,
          ATTN + (size_t)r * BL * Kc, WNb, SW);
    }
    attgru_mfma<<<BL / 128, 256, 0, stream>>>(WNb, Apk + (size_t)r * 49 * 1024,
        attend_b + (size_t)r * FPc, SW,
        Hbuf[r & 1], Hbuf[(r + 1) & 1],
        Wpk + (size_t)r * 6 * 49 * 1024, gru_bih + (size_t)r * 3 * FPc, gru_bhh + (size_t)r * 3 * FPc,
        AV + (size_t)(r + 1) * BL * FPc);
  }

  mol_fused<<<Bc, 256, 0, stream>>>(Hbuf[Rc & 1], AV + (size_t)3 * BL * FPc, mask,
      mal_W, mal_b, mattT, matt_b, mWihT, mWhhT, mbih, mbhh, out_W, out_b,
      MV, MU, MA, PRED);
}

// Round 12
// 907.089 us; speedup vs baseline: 1.4136x; 1.0733x over previous
//
#include <hip/hip_runtime.h>
#include <stdint.h>

#define Bc 512
#define Lc 128
#define Kc 6
#define AFc 39
#define BFc 10
#define FPc 200
#define Rc 3
#define Tc 2
constexpr int BL = Bc * Lc;          // 65536
constexpr int KP = 224;              // padded K / F for MFMA
constexpr float SLOPE = 0.01f;
constexpr float NEGC = -9e8f;

typedef __attribute__((ext_vector_type(8))) __bf16 bf16x8;
typedef __attribute__((ext_vector_type(16))) float f32x16;

__device__ __forceinline__ float leaky(float x) { return x >= 0.f ? x : SLOPE * x; }
__device__ __forceinline__ float sigm(float x) { return 1.f / (1.f + __expf(-x)); }
__device__ __forceinline__ float eluf(float x) { return x > 0.f ? x : expm1f(x); }
__device__ __forceinline__ float wave_sum(float v) {
  #pragma unroll
  for (int m = 32; m >= 1; m >>= 1) v += __shfl_xor(v, m);
  return v;
}
__device__ __forceinline__ float bflo(uint32_t u) { return __uint_as_float(u << 16); }
__device__ __forceinline__ float bfhi(uint32_t u) { return __uint_as_float(u & 0xffff0000u); }
__device__ __forceinline__ unsigned short f2bu(float x) {
  __bf16 b = (__bf16)x;
  return __builtin_bit_cast(unsigned short, b);
}
__device__ __forceinline__ void glds16(const void* g, void* l) {
  __builtin_amdgcn_global_load_lds((const __attribute__((address_space(1))) uint32_t*)g,
      (__attribute__((address_space(3))) uint32_t*)l, 16, 0, 0);
}
__device__ __forceinline__ f32x16 zero16() {
  f32x16 z;
  #pragma unroll
  for (int i = 0; i < 16; ++i) z[i] = 0.f;
  return z;
}

// -------------------- unified prep: 5 transposes + 2 weight packs --------------------
__global__ void prep_k(
    const float* __restrict__ atom_fc_W, const float* __restrict__ nb_W,
    const float* __restrict__ matt_W, const float* __restrict__ mWih,
    const float* __restrict__ mWhh, const float* __restrict__ gru_Wih,
    const float* __restrict__ gru_Whh, const float* __restrict__ attend_W,
    float* __restrict__ atomfcT, float* __restrict__ naT, float* __restrict__ mattT,
    float* __restrict__ mWihT, float* __restrict__ mWhhT,
    __bf16* __restrict__ Wpk, __bf16* __restrict__ Apk) {
  int i = blockIdx.x * 256 + threadIdx.x;
  const int n0 = FPc * AFc, n1 = FPc * (AFc + BFc), n2 = FPc * FPc;
  const int n3 = 600 * FPc, n4 = 600 * FPc;
  const int nW = Rc * 6 * 49 * 1024, nA = Rc * 49 * 1024;
  if (i < n0) { int r = i / AFc, c = i % AFc; atomfcT[c * FPc + r] = atom_fc_W[i]; return; }
  i -= n0;
  if (i < n1) { int r = i / (AFc + BFc), c = i % (AFc + BFc); naT[c * FPc + r] = nb_W[i]; return; }
  i -= n1;
  if (i < n2) { int r = i / FPc, c = i % FPc; mattT[c * FPc + r] = matt_W[i]; return; }
  i -= n2;
  if (i < n3) { int r = i / FPc, c = i % FPc; mWihT[c * 600 + r] = mWih[i]; return; }
  i -= n3;
  if (i < n4) { int r = i / FPc, c = i % FPc; mWhhT[c * 600 + r] = mWhh[i]; return; }
  i -= n4;
  if (i < nW) {
    int j = i & 7, fl = (i >> 3) & 31, c = (i >> 8) & 3;
    int T = i >> 10;
    int kt = T % 7; T /= 7;
    int ft = T % 7; T /= 7;
    int g = T % 6;  int r = T / 6;
    int f = ft * 32 + fl, k = kt * 32 + c * 8 + j;
    float v = 0.f;
    if (f < FPc && k < FPc) {
      if (g < 3) v = gru_Wih[((size_t)r * 3 * FPc + g * FPc + f) * FPc + k];
      else       v = gru_Whh[((size_t)r * 3 * FPc + (g - 3) * FPc + f) * FPc + k];
    }
    Wpk[i] = (__bf16)v;
    return;
  }
  i -= nW;
  if (i < nA) {
    int j = i & 7, fl = (i >> 3) & 31, c = (i >> 8) & 3;
    int T = i >> 10;
    int kt = T % 7; T /= 7;
    int ft = T % 7; int r = T / 7;
    int f = ft * 32 + fl, k = kt * 32 + c * 8 + j;
    float v = (f < FPc && k < FPc) ? attend_W[((size_t)r * FPc + f) * FPc + k] : 0.f;
    Apk[i] = (__bf16)v;
  }
}

// -------------------- generic small GEMM (f32): Yb[rows][200] bf16 -------------------
template<int KD>
__global__ __launch_bounds__(256) void gemm8x1(
    const float* __restrict__ X, const float* __restrict__ WT,
    __bf16* __restrict__ Yb) {
  constexpr int TR = 8, LDP = 12;
  __shared__ float xT[KD * LDP];
  const int row0 = blockIdx.x * TR;
  const int tid = threadIdx.x;
  for (int e = tid; e < TR * KD; e += 256) {
    int r = e / KD, g = e - r * KD;
    xT[g * LDP + r] = X[(size_t)row0 * KD + e];
  }
  __syncthreads();
  const int f = tid;
  if (f < FPc) {
    float acc[TR];
    #pragma unroll
    for (int r = 0; r < TR; ++r) acc[r] = 0.f;
    #pragma unroll 4
    for (int g = 0; g < KD; ++g) {
      float w = WT[(size_t)g * FPc + f];
      float4 x0 = *reinterpret_cast<const float4*>(&xT[g * LDP]);
      float4 x1 = *reinterpret_cast<const float4*>(&xT[g * LDP + 4]);
      acc[0] = fmaf(x0.x, w, acc[0]); acc[1] = fmaf(x0.y, w, acc[1]);
      acc[2] = fmaf(x0.z, w, acc[2]); acc[3] = fmaf(x0.w, w, acc[3]);
      acc[4] = fmaf(x1.x, w, acc[4]); acc[5] = fmaf(x1.y, w, acc[5]);
      acc[6] = fmaf(x1.z, w, acc[6]); acc[7] = fmaf(x1.w, w, acc[7]);
    }
    #pragma unroll
    for (int r = 0; r < TR; ++r)
      Yb[(size_t)(row0 + r) * FPc + f] = (__bf16)acc[r];
  }
}

// -------------------- fused atom_list GEMM: atom_fc + neighbor-P ---------------------
__global__ __launch_bounds__(256) void gemm_dual(
    const float* __restrict__ X, const float* __restrict__ W1T,
    const float* __restrict__ b1, const float* __restrict__ W2T,
    float* __restrict__ Yraw, __bf16* __restrict__ Hb, __bf16* __restrict__ Pb) {
  constexpr int KD = AFc, TR = 8, LDP = 12;
  __shared__ float xT[KD * LDP];
  const int row0 = blockIdx.x * TR;
  const int tid = threadIdx.x;
  for (int e = tid; e < TR * KD; e += 256) {
    int r = e / KD, g = e - r * KD;
    xT[g * LDP + r] = X[(size_t)row0 * KD + e];
  }
  __syncthreads();
  const int f = tid;
  if (f < FPc) {
    float a1[TR], a2[TR];
    #pragma unroll
    for (int r = 0; r < TR; ++r) { a1[r] = 0.f; a2[r] = 0.f; }
    #pragma unroll 2
    for (int g = 0; g < KD; ++g) {
      float w1 = W1T[(size_t)g * FPc + f];
      float w2 = W2T[(size_t)g * FPc + f];
      float4 x0 = *reinterpret_cast<const float4*>(&xT[g * LDP]);
      float4 x1 = *reinterpret_cast<const float4*>(&xT[g * LDP + 4]);
      float xs[8] = {x0.x, x0.y, x0.z, x0.w, x1.x, x1.y, x1.z, x1.w};
      #pragma unroll
      for (int r = 0; r < TR; ++r) {
        a1[r] = fmaf(xs[r], w1, a1[r]);
        a2[r] = fmaf(xs[r], w2, a2[r]);
      }
    }
    const float bf = b1[f];
    #pragma unroll
    for (int r = 0; r < TR; ++r) {
      float v = a1[r] + bf;
      Yraw[(size_t)(row0 + r) * FPc + f] = v;
      Hb[(size_t)(row0 + r) * KP + f] = (__bf16)leaky(v);
      Pb[(size_t)(row0 + r) * FPc + f] = (__bf16)a2[r];
    }
  } else if (f < KP) {
    #pragma unroll
    for (int r = 0; r < TR; ++r) Hb[(size_t)(row0 + r) * KP + f] = (__bf16)0.f;
  }
}

// -------------------- fused attend + GRU v3 ------------------------------------------
__global__ __launch_bounds__(256, 2) void attgru_mfma(
    const __bf16* __restrict__ WNb, const __bf16* __restrict__ Apk,
    const float* __restrict__ attb, const float* __restrict__ SW,
    const __bf16* __restrict__ Hin, __bf16* __restrict__ Hout,
    const __bf16* __restrict__ Wpk,
    const float* __restrict__ bih, const float* __restrict__ bhh,
    float* __restrict__ actOut) {
  __shared__ __align__(16) __bf16 smem[28672];   // 57344 B
  __bf16* scr = smem;                             // [wv4][1024] = 8192 B
  __bf16* Bs  = smem + 4096;                      // [buf4][g6][1024] = 49152 B
  const int tid = threadIdx.x, wv = tid >> 6, lane = tid & 63;
  const size_t row0 = (size_t)blockIdx.x * 128;
  const int fl = lane & 31;

  // ---- h fragments (issued first; latency hides under attend) ----
  bf16x8 hf[7][2];
  {
    const __bf16* sh = Hin + (row0 + wv * 32 + fl) * KP + (lane >> 5) * 8;
    #pragma unroll
    for (int kt = 0; kt < 7; ++kt)
      #pragma unroll
      for (int h = 0; h < 2; ++h)
        hf[kt][h] = *(const bf16x8*)(sh + kt * 32 + h * 16);
  }

  // ---- attend phase: per-tile compute + LDS bounce -> xcf regs ----
  bf16x8 xcf[7][2];
  {
    bf16x8 af[7][2];
    const __bf16* sw_ = WNb + (row0 + wv * 32 + fl) * KP + (lane >> 5) * 8;
    #pragma unroll
    for (int kt = 0; kt < 7; ++kt)
      #pragma unroll
      for (int h = 0; h < 2; ++h)
        af[kt][h] = *(const bf16x8*)(sw_ + kt * 32 + h * 16);

    const int xbase = wv * 1024 + ((fl >> 3) & 3) * 256 + (fl & 7);
    #pragma unroll 1
    for (int ft = 0; ft < 7; ++ft) {
      f32x16 acc = zero16();
      #pragma unroll
      for (int kt = 0; kt < 7; ++kt) {
        const __bf16* bt = Apk + ((size_t)ft * 7 + kt) * 1024 + lane * 8;
        bf16x8 b0 = *(const bf16x8*)(bt);
        bf16x8 b1 = *(const bf16x8*)(bt + 512);
        acc = __builtin_amdgcn_mfma_f32_32x32x16_bf16(af[kt][0], b0, acc, 0, 0, 0);
        acc = __builtin_amdgcn_mfma_f32_32x32x16_bf16(af[kt][1], b1, acc, 0, 0, 0);
      }
      const int f = ft * 32 + fl;
      const bool fok = f < FPc;
      const float bf = fok ? attb[f] : 0.f;
      #pragma unroll
      for (int reg = 0; reg < 16; ++reg) {
        int rl = (reg & 3) + 8 * (reg >> 2) + 4 * (lane >> 5);
        float v = fok ? eluf(acc[reg] + SW[row0 + wv * 32 + rl] * bf) : 0.f;
        scr[xbase + rl * 8] = (__bf16)v;
      }
      xcf[ft][0] = *(const bf16x8*)(scr + wv * 1024 + lane * 8);
      xcf[ft][1] = *(const bf16x8*)(scr + wv * 1024 + 512 + lane * 8);
    }
  }

  auto stageB = [&](int ft, int kt, int buf) {
    #pragma unroll
    for (int m3 = 0; m3 < 3; ++m3) {
      int m = wv * 3 + m3;               // 0..11
      int g = m >> 1, half = m & 1;
      const __bf16* s = Wpk + ((size_t)(g * 7 + ft) * 7 + kt) * 1024 + half * 512 + lane * 8;
      glds16(s, Bs + buf * 6144 + g * 1024 + half * 512);
    }
  };
  asm volatile("s_waitcnt vmcnt(0)" ::: "memory");
  stageB(0, 0, 0);
  stageB(0, 1, 1);
  stageB(0, 2, 2);

  f32x16 gacc[6];
  #pragma unroll
  for (int g = 0; g < 6; ++g) gacc[g] = zero16();

  for (int ft = 0; ft < 7; ++ft) {
    #pragma unroll
    for (int kt = 0; kt < 7; ++kt) {
      const int it = ft * 7 + kt;
      const int buf = it & 3;
      const int nt = it + 3;
      const int sft = (nt < 49) ? nt / 7 : 6;
      const int skt = (nt < 49) ? nt % 7 : 6;
      __builtin_amdgcn_sched_barrier(0);
      stageB(sft, skt, nt & 3);
      __builtin_amdgcn_sched_barrier(0);
      asm volatile("s_waitcnt vmcnt(9)" ::: "memory");
      __builtin_amdgcn_sched_barrier(0);
      __builtin_amdgcn_s_barrier();
      __builtin_amdgcn_sched_barrier(0);
      #pragma unroll
      for (int h = 0; h < 2; ++h) {
        bf16x8 xch = xcf[kt][h];
        bf16x8 hh = hf[kt][h];
        const __bf16* bb = Bs + buf * 6144 + h * 512 + lane * 8;
        bf16x8 b0 = *(const bf16x8*)(bb);
        bf16x8 b1 = *(const bf16x8*)(bb + 1024);
        bf16x8 b2 = *(const bf16x8*)(bb + 2048);
        bf16x8 b3 = *(const bf16x8*)(bb + 3072);
        bf16x8 b4 = *(const bf16x8*)(bb + 4096);
        bf16x8 b5 = *(const bf16x8*)(bb + 5120);
        __builtin_amdgcn_s_setprio(1);
        gacc[0] = __builtin_amdgcn_mfma_f32_32x32x16_bf16(xch, b0, gacc[0], 0, 0, 0);
        gacc[1] = __builtin_amdgcn_mfma_f32_32x32x16_bf16(xch, b1, gacc[1], 0, 0, 0);
        gacc[2] = __builtin_amdgcn_mfma_f32_32x32x16_bf16(xch, b2, gacc[2], 0, 0, 0);
        gacc[3] = __builtin_amdgcn_mfma_f32_32x32x16_bf16(hh, b3, gacc[3], 0, 0, 0);
        gacc[4] = __builtin_amdgcn_mfma_f32_32x32x16_bf16(hh, b4, gacc[4], 0, 0, 0);
        gacc[5] = __builtin_amdgcn_mfma_f32_32x32x16_bf16(hh, b5, gacc[5], 0, 0, 0);
        __builtin_amdgcn_s_setprio(0);
      }
      if (kt == 6) {
        const int f = ft * 32 + fl;
        const bool fok = f < FPc;
        float bir = 0, biz = 0, bin_ = 0, bhr = 0, bhz = 0, bhn = 0;
        if (fok) {
          bir = bih[f]; biz = bih[FPc + f]; bin_ = bih[2 * FPc + f];
          bhr = bhh[f]; bhz = bhh[FPc + f]; bhn = bhh[2 * FPc + f];
        }
        #pragma unroll
        for (int reg = 0; reg < 16; ++reg) {
          int rl = (reg & 3) + 8 * (reg >> 2) + 4 * (lane >> 5);
          size_t row = row0 + wv * 32 + rl;
          if (fok) {
            float ho = (float)Hin[row * KP + f];
            float rg_ = sigm(gacc[0][reg] + bir + gacc[3][reg] + bhr);
            float zg  = sigm(gacc[1][reg] + biz + gacc[4][reg] + bhz);
            float ng  = tanhf(gacc[2][reg] + bin_ + rg_ * (gacc[5][reg] + bhn));
            float hp = (1.f - zg) * ng + zg * ho;
            Hout[row * KP + f] = (__bf16)hp;
            actOut[row * FPc + f] = fmaxf(hp, 0.f);
          } else {
            Hout[row * KP + f] = (__bf16)0.f;
          }
        }
        #pragma unroll
        for (int g = 0; g < 6; ++g) gacc[g] = zero16();
      }
      __builtin_amdgcn_sched_barrier(0);
      __builtin_amdgcn_s_barrier();
      __builtin_amdgcn_sched_barrier(0);
    }
  }
}

// -------------------- attn round r>=1: per-molecule, 8 waves ------------------------
__global__ __launch_bounds__(512) void attn_molN(
    const __bf16* __restrict__ Hb, const int* __restrict__ adl,
    const float* __restrict__ alW, const float* __restrict__ albp,
    float* __restrict__ attnOut, __bf16* __restrict__ WNb, float* __restrict__ SW) {
  __shared__ __align__(16) __bf16 actL[128 * 224];
  __shared__ float saL[128], snL[128];
  const int b = blockIdx.x;
  const int tid = threadIdx.x, wv = tid >> 6, lane = tid & 63;
  const bool l36 = lane < 36;

  {
    const uint4* src = (const uint4*)(Hb + (size_t)b * 128 * KP);
    uint4* dst = (uint4*)actL;
    for (int i = tid; i < 128 * 224 / 8; i += 512) {
      uint4 v = src[i];
      uint32_t c[4] = {v.x, v.y, v.z, v.w};
      #pragma unroll
      for (int j = 0; j < 4; ++j) {
        uint32_t lo = c[j] & 0xffffu, hi = c[j] >> 16;
        if (lo & 0x8000u) lo = 0;
        if (hi & 0x8000u) hi = 0;
        c[j] = lo | (hi << 16);
      }
      dst[i] = make_uint4(c[0], c[1], c[2], c[3]);
    }
  }
  float wa0x = alW[2 * lane], wa0y = alW[2 * lane + 1];
  float wa1x = l36 ? alW[128 + 2 * lane] : 0.f, wa1y = l36 ? alW[129 + 2 * lane] : 0.f;
  float wn0x = alW[FPc + 2 * lane], wn0y = alW[FPc + 2 * lane + 1];
  float wn1x = l36 ? alW[FPc + 128 + 2 * lane] : 0.f, wn1y = l36 ? alW[FPc + 129 + 2 * lane] : 0.f;
  const float ab = albp[0];
  __syncthreads();

  for (int i = 0; i < 16; ++i) {
    int l = wv * 16 + i;
    const uint32_t* rowp = (const uint32_t*)(actL + l * 224);
    uint32_t u0 = rowp[lane];
    uint32_t u1 = l36 ? rowp[64 + lane] : 0u;
    float x0 = bflo(u0), y0 = bfhi(u0), x1 = bflo(u1), y1 = bfhi(u1);
    float psa = x0 * wa0x + y0 * wa0y + x1 * wa1x + y1 * wa1y;
    float psn = x0 * wn0x + y0 * wn0y + x1 * wn1x + y1 * wn1y;
    psa = wave_sum(psa);
    psn = wave_sum(psn);
    if (lane == 0) { saL[l] = psa; snL[l] = psn; }
  }
  __syncthreads();

  for (int i = 0; i < 16; ++i) {
    const int row = wv * 16 + i;
    const size_t grow = (size_t)b * 128 + row;
    int gk = (lane < Kc) ? adl[grow * Kc + lane] : 0;
    int ai[Kc];
    #pragma unroll
    for (int k = 0; k < Kc; ++k) ai[k] = __shfl(gk, k);
    const float sarow = saL[row];
    float s[Kc]; bool pad[Kc]; float mx = -3.0e38f;
    #pragma unroll
    for (int k = 0; k < Kc; ++k) {
      pad[k] = (ai[k] == Lc - 1);
      s[k] = leaky(sarow + snL[ai[k]] + ab) + (pad[k] ? NEGC : 0.f);
      mx = fmaxf(mx, s[k]);
    }
    float e[Kc], sum = 0.f;
    #pragma unroll
    for (int k = 0; k < Kc; ++k) { e[k] = __expf(s[k] - mx); sum += e[k]; }
    float inv = 1.f / sum;
    float w[Kc], sw = 0.f;
    #pragma unroll
    for (int k = 0; k < Kc; ++k) { w[k] = pad[k] ? 0.f : e[k] * inv; sw += w[k]; }
    if (lane < Kc) attnOut[grow * Kc + lane] = w[lane];
    if (lane == 0) SW[grow] = sw;
    float a0 = 0.f, b0 = 0.f, a1 = 0.f, b1 = 0.f;
    #pragma unroll
    for (int k = 0; k < Kc; ++k) {
      const uint32_t* nr = (const uint32_t*)(actL + ai[k] * 224);
      uint32_t u0 = nr[lane];
      uint32_t u1 = l36 ? nr[64 + lane] : 0u;
      a0 = fmaf(w[k], bflo(u0), a0); b0 = fmaf(w[k], bfhi(u0), b0);
      a1 = fmaf(w[k], bflo(u1), a1); b1 = fmaf(w[k], bfhi(u1), b1);
    }
    __bf16* wr = WNb + grow * KP;
    ushort2 o0; o0.x = f2bu(a0); o0.y = f2bu(b0);
    *(ushort2*)(wr + 2 * lane) = o0;
    if (lane < 48) {
      float va = l36 ? a1 : 0.f, vb = l36 ? b1 : 0.f;
      ushort2 o1; o1.x = f2bu(va); o1.y = f2bu(vb);
      *(ushort2*)(wr + 128 + 2 * lane) = o1;
    }
  }
}

// -------------------- attn round r==0: per-molecule block, 8 waves, v-reg cache -----
__global__ __launch_bounds__(512) void attn_mol0(
    const __bf16* __restrict__ Pb, const __bf16* __restrict__ Qb,
    const float* __restrict__ nbb, const __bf16* __restrict__ Hb0,
    const int* __restrict__ adl, const int* __restrict__ bdl,
    const float* __restrict__ alW, const float* __restrict__ albp,
    float* __restrict__ attnOut, __bf16* __restrict__ WNb, float* __restrict__ SW) {
  __shared__ __align__(16) __bf16 Pl[128 * 200];
  __shared__ __align__(16) __bf16 Ql[128 * 200];
  __shared__ float nbbL[200];
  __shared__ float saL[128];
  const int b = blockIdx.x;
  const int tid = threadIdx.x, wv = tid >> 6, lane = tid & 63;
  const bool l36 = lane < 36;

  {
    const uint4* sp = (const uint4*)(Pb + (size_t)b * 128 * FPc);
    const uint4* sq = (const uint4*)(Qb + (size_t)b * 128 * FPc);
    uint4* dp = (uint4*)Pl;
    uint4* dq = (uint4*)Ql;
    for (int i = tid; i < 128 * 200 / 8; i += 512) { dp[i] = sp[i]; dq[i] = sq[i]; }
    for (int i = tid; i < FPc; i += 512) nbbL[i] = nbb[i];
  }
  float wa0x = alW[2 * lane], wa0y = alW[2 * lane + 1];
  float wa1x = l36 ? alW[128 + 2 * lane] : 0.f, wa1y = l36 ? alW[129 + 2 * lane] : 0.f;
  float wn0x = alW[FPc + 2 * lane], wn0y = alW[FPc + 2 * lane + 1];
  float wn1x = l36 ? alW[FPc + 128 + 2 * lane] : 0.f, wn1y = l36 ? alW[FPc + 129 + 2 * lane] : 0.f;
  const float ab = albp[0];

  for (int i = 0; i < 16; ++i) {
    int l = wv * 16 + i;
    const uint32_t* hr = (const uint32_t*)(Hb0 + ((size_t)b * 128 + l) * KP);
    uint32_t u0 = hr[lane];
    uint32_t u1 = l36 ? hr[64 + lane] : 0u;
    float psa = bflo(u0) * wa0x + bfhi(u0) * wa0y + bflo(u1) * wa1x + bfhi(u1) * wa1y;
    psa = wave_sum(psa);
    if (lane == 0) saL[l] = psa;
  }
  __syncthreads();

  const float n0x = nbbL[2 * lane], n0y = nbbL[2 * lane + 1];
  const float n1x = l36 ? nbbL[128 + 2 * lane] : 0.f, n1y = l36 ? nbbL[129 + 2 * lane] : 0.f;

  for (int i = 0; i < 16; ++i) {
    const int row = wv * 16 + i;
    const size_t grow = (size_t)b * 128 + row;
    int gk = (lane < Kc) ? adl[grow * Kc + lane] : 0;
    int hk = (lane < Kc) ? bdl[grow * Kc + lane] : 0;
    int ai[Kc], bi[Kc];
    #pragma unroll
    for (int k = 0; k < Kc; ++k) { ai[k] = __shfl(gk, k); bi[k] = __shfl(hk, k); }
    float v0x[Kc], v0y[Kc], v1x[Kc], v1y[Kc], p[Kc];
    #pragma unroll
    for (int k = 0; k < Kc; ++k) {
      const uint32_t* pr = (const uint32_t*)(Pl + ai[k] * 200);
      const uint32_t* qr = (const uint32_t*)(Ql + bi[k] * 200);
      uint32_t up0 = pr[lane], uq0 = qr[lane];
      uint32_t up1 = l36 ? pr[64 + lane] : 0u, uq1 = l36 ? qr[64 + lane] : 0u;
      v0x[k] = leaky(bflo(up0) + bflo(uq0) + n0x);
      v0y[k] = leaky(bfhi(up0) + bfhi(uq0) + n0y);
      v1x[k] = l36 ? leaky(bflo(up1) + bflo(uq1) + n1x) : 0.f;
      v1y[k] = l36 ? leaky(bfhi(up1) + bfhi(uq1) + n1y) : 0.f;
      p[k] = v0x[k] * wn0x + v0y[k] * wn0y + v1x[k] * wn1x + v1y[k] * wn1y;
    }
    #pragma unroll
    for (int k = 0; k < Kc; ++k) p[k] = wave_sum(p[k]);
    const float sarow = saL[row];
    float s[Kc]; bool pad[Kc]; float mx = -3.0e38f;
    #pragma unroll
    for (int k = 0; k < Kc; ++k) {
      pad[k] = (ai[k] == Lc - 1);
      s[k] = leaky(sarow + p[k] + ab) + (pad[k] ? NEGC : 0.f);
      mx = fmaxf(mx, s[k]);
    }
    float e[Kc], sum = 0.f;
    #pragma unroll
    for (int k = 0; k < Kc; ++k) { e[k] = __expf(s[k] - mx); sum += e[k]; }
    float inv = 1.f / sum;
    float w[Kc], sw = 0.f;
    #pragma unroll
    for (int k = 0; k < Kc; ++k) { w[k] = pad[k] ? 0.f : e[k] * inv; sw += w[k]; }
    if (lane < Kc) attnOut[grow * Kc + lane] = w[lane];
    if (lane == 0) SW[grow] = sw;
    float a0 = 0.f, b0v = 0.f, a1 = 0.f, b1v = 0.f;
    #pragma unroll
    for (int k = 0; k < Kc; ++k) {
      a0  = fmaf(w[k], v0x[k], a0);
      b0v = fmaf(w[k], v0y[k], b0v);
      a1  = fmaf(w[k], v1x[k], a1);
      b1v = fmaf(w[k], v1y[k], b1v);
    }
    __bf16* wr = WNb + grow * KP;
    ushort2 o0; o0.x = f2bu(a0); o0.y = f2bu(b0v);
    *(ushort2*)(wr + 2 * lane) = o0;
    if (lane < 48) {
      float va = l36 ? a1 : 0.f, vb = l36 ? b1v : 0.f;
      ushort2 o1; o1.x = f2bu(va); o1.y = f2bu(vb);
      *(ushort2*)(wr + 128 + 2 * lane) = o1;
    }
  }
}

// -------------------- fused mol phase v2: act staged in LDS (bf16) -------------------
__global__ __launch_bounds__(256) void mol_fused(
    const __bf16* __restrict__ Hb, const float* __restrict__ mask,
    const float* __restrict__ malW, const float* __restrict__ malb,
    const float* __restrict__ mattT, const float* __restrict__ matt_b,
    const float* __restrict__ mWihT, const float* __restrict__ mWhhT,
    const float* __restrict__ mbih, const float* __restrict__ mbhh,
    const float* __restrict__ outW, const float* __restrict__ outb,
    float* __restrict__ MV, float* __restrict__ MU, float* __restrict__ MA,
    float* __restrict__ PRED) {
  const int b = blockIdx.x;
  __shared__ __align__(16) __bf16 actL[Lc * FPc];   // 51200 B
  __shared__ float mk[Lc];
  __shared__ float molf[FPc], actm[FPc], wact[FPc], ctx[FPc];
  __shared__ float snL[Lc], wl[Lc];
  __shared__ float red[4], red2[4];
  const int tid = threadIdx.x, wv = tid >> 6, lane = tid & 63;
  const bool l36 = lane < 36;

  for (int l = tid; l < Lc; l += 256) mk[l] = mask[b * Lc + l];
  __syncthreads();
  const int f = tid;
  // single global pass: stage act=relu(Hb) into LDS + both masked sums
  if (f < FPc) {
    float s1 = 0.f, s2 = 0.f;
    for (int l = 0; l < Lc; ++l) {
      float m = mk[l];
      float h = (float)Hb[((size_t)b * Lc + l) * KP + f];
      float a = fmaxf(h, 0.f);
      actL[l * FPc + f] = (__bf16)a;
      s1 = fmaf(h, m, s1);
      s2 = fmaf(a, m, s2);
    }
    MU[b * FPc + f] = s1;
    MV[b * FPc + f] = s2;
    molf[f] = s2;
    actm[f] = fmaxf(s2, 0.f);
  }
  // packed weight pairs for the sn dot (malW[200:400])
  float wn0x = malW[FPc + 2 * lane], wn0y = malW[FPc + 2 * lane + 1];
  float wn1x = l36 ? malW[FPc + 128 + 2 * lane] : 0.f;
  float wn1y = l36 ? malW[FPc + 129 + 2 * lane] : 0.f;
  __syncthreads();

  for (int t = 0; t < Tc; ++t) {
    // sa = dot(actm, malW[:200])
    {
      float p = 0.f;
      for (int i = tid; i < FPc; i += 256) p = fmaf(actm[i], malW[i], p);
      p = wave_sum(p);
      if (lane == 0) red[wv] = p;
    }
    // sn[l] from LDS act (packed bf16 reads)
    for (int l = wv; l < Lc; l += 4) {
      const uint32_t* rowp = (const uint32_t*)(actL + l * FPc);
      uint32_t u0 = rowp[lane];
      uint32_t u1 = l36 ? rowp[64 + lane] : 0u;
      float p = bflo(u0) * wn0x + bfhi(u0) * wn0y + bflo(u1) * wn1x + bfhi(u1) * wn1y;
      p = wave_sum(p);
      if (lane == 0) snL[l] = p;
    }
    __syncthreads();
    const float sa = red[0] + red[1] + red[2] + red[3];
    // softmax over l
    const int l = tid;
    float sc = -3.0e38f, mval = 0.f;
    if (l < Lc) {
      mval = mk[l];
      sc = leaky(sa + snL[l] + malb[0]) + (mval == 0.f ? NEGC : 0.f);
    }
    float m = sc;
    #pragma unroll
    for (int o = 32; o >= 1; o >>= 1) m = fmaxf(m, __shfl_xor(m, o));
    if (lane == 0) red[wv] = m;
    __syncthreads();
    float mx = fmaxf(red[0], red[1]);
    float e = (l < Lc) ? __expf(sc - mx) : 0.f;
    float s = e;
    #pragma unroll
    for (int o = 32; o >= 1; o >>= 1) s += __shfl_xor(s, o);
    if (lane == 0) red2[wv] = s;
    __syncthreads();
    float tot = red2[0] + red2[1];
    float w = 0.f;
    if (l < Lc) {
      w = e / tot * mval;
      wl[l] = w;
      MA[(size_t)t * Bc * Lc + b * Lc + l] = w;
    }
    float swp = w;
    #pragma unroll
    for (int o = 32; o >= 1; o >>= 1) swp += __shfl_xor(swp, o);
    if (lane == 0) red[wv] = swp;
    __syncthreads();
    const float sumw = red[0] + red[1];
    // wact[f] = sum_l wl[l]*act[l][f] (from LDS)
    if (f < FPc) {
      float a = 0.f;
      for (int l2 = 0; l2 < Lc; ++l2)
        a = fmaf(wl[l2], (float)actL[l2 * FPc + f], a);
      wact[f] = a;
    }
    __syncthreads();
    // ctx[f] = elu(sum_g wact[g]*mattT[g*200+f] + sumw*matt_b[f])
    if (f < FPc) {
      float a = 0.f;
      #pragma unroll 4
      for (int g = 0; g < FPc; ++g) a = fmaf(wact[g], mattT[(size_t)g * FPc + f], a);
      ctx[f] = eluf(fmaf(sumw, matt_b[f], a));
    }
    __syncthreads();
    // GRU (thread f owns feature f)
    float hp = 0.f;
    if (f < FPc) {
      float air = mbih[f], aiz = mbih[FPc + f], ain = mbih[2 * FPc + f];
      float ahr = mbhh[f], ahz = mbhh[FPc + f], ahn = mbhh[2 * FPc + f];
      #pragma unroll 2
      for (int g = 0; g < FPc; ++g) {
        float xc = ctx[g], hx = molf[g];
        const float* wi = &mWihT[(size_t)g * 600 + f];
        const float* wh = &mWhhT[(size_t)g * 600 + f];
        air = fmaf(xc, wi[0], air);
        aiz = fmaf(xc, wi[200], aiz);
        ain = fmaf(xc, wi[400], ain);
        ahr = fmaf(hx, wh[0], ahr);
        ahz = fmaf(hx, wh[200], ahz);
        ahn = fmaf(hx, wh[400], ahn);
      }
      float rg = sigm(air + ahr);
      float zg = sigm(aiz + ahz);
      float ng = tanhf(fmaf(rg, ahn, ain));
      hp = (1.f - zg) * ng + zg * molf[f];
      MU[(size_t)(t + 1) * Bc * FPc + b * FPc + f] = hp;
      MV[(size_t)(t + 1) * Bc * FPc + b * FPc + f] = fmaxf(hp, 0.f);
    }
    __syncthreads();
    if (f < FPc) {
      molf[f] = hp;
      actm[f] = fmaxf(hp, 0.f);
    }
    __syncthreads();
  }
  // pred
  {
    float p = 0.f;
    for (int i = tid; i < FPc; i += 256) p = fmaf(molf[i], outW[i], p);
    p = wave_sum(p);
    if (lane == 0) red[wv] = p;
    __syncthreads();
    if (tid == 0) PRED[b] = red[0] + red[1] + red[2] + red[3] + outb[0];
  }
}

extern "C" void kernel_launch(void* const* d_in, const int* in_sizes, int n_in,
                              void* d_out, int out_size, void* d_ws, size_t ws_size,
                              hipStream_t stream) {
  const float* atom_list = (const float*)d_in[0];
  const float* bond_list = (const float*)d_in[1];
  const int*   adl       = (const int*)d_in[2];
  const int*   bdl       = (const int*)d_in[3];
  const float* mask      = (const float*)d_in[4];
  const float* atom_fc_W = (const float*)d_in[5];
  const float* atom_fc_b = (const float*)d_in[6];
  const float* nb_W      = (const float*)d_in[7];
  const float* nb_b      = (const float*)d_in[8];
  const float* align_W   = (const float*)d_in[9];
  const float* align_b   = (const float*)d_in[10];
  const float* attend_W  = (const float*)d_in[11];
  const float* attend_b  = (const float*)d_in[12];
  const float* gru_Wih   = (const float*)d_in[13];
  const float* gru_Whh   = (const float*)d_in[14];
  const float* gru_bih   = (const float*)d_in[15];
  const float* gru_bhh   = (const float*)d_in[16];
  const float* mal_W     = (const float*)d_in[17];
  const float* mal_b     = (const float*)d_in[18];
  const float* matt_W    = (const float*)d_in[19];
  const float* matt_b    = (const float*)d_in[20];
  const float* mWih      = (const float*)d_in[21];
  const float* mWhh      = (const float*)d_in[22];
  const float* mbih      = (const float*)d_in[23];
  const float* mbhh      = (const float*)d_in[24];
  const float* out_W     = (const float*)d_in[25];
  const float* out_b     = (const float*)d_in[26];

  float* out  = (float*)d_out;
  float* AV   = out;                                  // (4,B,L,FP)
  float* ATTN = AV + (size_t)4 * BL * FPc;            // (3,B,L,K)
  float* MV   = ATTN + (size_t)Rc * BL * Kc;          // (3,B,FP)
  float* MU   = MV + (size_t)3 * Bc * FPc;            // (3,B,FP)
  float* MA   = MU + (size_t)3 * Bc * FPc;            // (2,B,L)
  float* PRED = MA + (size_t)Tc * Bc * Lc;            // (B,1)

  char* w = (char*)d_ws;
  __bf16* Hb0  = (__bf16*)w; w += (size_t)BL * KP * 2;
  __bf16* Hb1  = (__bf16*)w; w += (size_t)BL * KP * 2;
  __bf16* WNb  = (__bf16*)w; w += (size_t)BL * KP * 2;
  __bf16* Pb   = (__bf16*)w; w += (size_t)BL * FPc * 2;
  __bf16* Qb   = (__bf16*)w; w += (size_t)BL * FPc * 2;
  __bf16* Wpk  = (__bf16*)w; w += (size_t)Rc * 6 * 49 * 1024 * 2;
  __bf16* Apk  = (__bf16*)w; w += (size_t)Rc * 49 * 1024 * 2;
  float* SW    = (float*)w;  w += (size_t)BL * 4;
  float* atomfcT = (float*)w; w += (size_t)AFc * FPc * 4;
  float* naT     = (float*)w; w += (size_t)(AFc + BFc) * FPc * 4;
  float* mattT   = (float*)w; w += (size_t)FPc * FPc * 4;
  float* mWihT   = (float*)w; w += (size_t)FPc * 600 * 4;
  float* mWhhT   = (float*)w; w += (size_t)FPc * 600 * 4;

  {
    const int nprep = FPc * AFc + FPc * (AFc + BFc) + FPc * FPc + 2 * 600 * FPc
                    + Rc * 6 * 49 * 1024 + Rc * 49 * 1024;
    prep_k<<<(nprep + 255) / 256, 256, 0, stream>>>(
        atom_fc_W, nb_W, matt_W, mWih, mWhh, gru_Wih, gru_Whh, attend_W,
        atomfcT, naT, mattT, mWihT, mWhhT, Wpk, Apk);
  }

  gemm_dual<<<BL / 8, 256, 0, stream>>>(atom_list, atomfcT, atom_fc_b, naT, AV, Hb0, Pb);
  gemm8x1<BFc><<<BL / 8, 256, 0, stream>>>(bond_list, naT + AFc * FPc, Qb);

  __bf16* Hbuf[2] = {Hb0, Hb1};
  for (int r = 0; r < Rc; ++r) {
    if (r == 0) {
      attn_mol0<<<Bc, 512, 0, stream>>>(Pb, Qb, nb_b, Hb0, adl, bdl,
          align_W, align_b, ATTN, WNb, SW);
    } else {
      attn_molN<<<Bc, 512, 0, stream>>>(Hbuf[r & 1], adl,
          align_W + (size_t)r * 2 * FPc, align_b + r,
          ATTN + (size_t)r * BL * Kc, WNb, SW);
    }
    attgru_mfma<<<BL / 128, 256, 0, stream>>>(WNb, Apk + (size_t)r * 49 * 1024,
        attend_b + (size_t)r * FPc, SW,
        Hbuf[r & 1], Hbuf[(r + 1) & 1],
        Wpk + (size_t)r * 6 * 49 * 1024, gru_bih + (size_t)r * 3 * FPc, gru_bhh + (size_t)r * 3 * FPc,
        AV + (size_t)(r + 1) * BL * FPc);
  }

  mol_fused<<<Bc, 256, 0, stream>>>(Hbuf[Rc & 1], mask,
      mal_W, mal_b, mattT, matt_b, mWihT, mWhhT, mbih, mbhh, out_W, out_b,
      MV, MU, MA, PRED);
}

// Round 13
// 760.617 us; speedup vs baseline: 1.6858x; 1.1926x over previous
//
#include <hip/hip_runtime.h>
#include <stdint.h>

#define Bc 512
#define Lc 128
#define Kc 6
#define AFc 39
#define BFc 10
#define FPc 200
#define Rc 3
#define Tc 2
constexpr int BL = Bc * Lc;          // 65536
constexpr int KP = 224;              // padded K / F for MFMA
constexpr float SLOPE = 0.01f;
constexpr float NEGC = -9e8f;

typedef __attribute__((ext_vector_type(8))) __bf16 bf16x8;
typedef __attribute__((ext_vector_type(16))) float f32x16;

__device__ __forceinline__ float leaky(float x) { return x >= 0.f ? x : SLOPE * x; }
__device__ __forceinline__ float sigm(float x) { return 1.f / (1.f + __expf(-x)); }
__device__ __forceinline__ float eluf(float x) { return x > 0.f ? x : expm1f(x); }
__device__ __forceinline__ float wave_sum(float v) {
  #pragma unroll
  for (int m = 32; m >= 1; m >>= 1) v += __shfl_xor(v, m);
  return v;
}
__device__ __forceinline__ float bflo(uint32_t u) { return __uint_as_float(u << 16); }
__device__ __forceinline__ float bfhi(uint32_t u) { return __uint_as_float(u & 0xffff0000u); }
__device__ __forceinline__ unsigned short f2bu(float x) {
  __bf16 b = (__bf16)x;
  return __builtin_bit_cast(unsigned short, b);
}
__device__ __forceinline__ void glds16(const void* g, void* l) {
  __builtin_amdgcn_global_load_lds((const __attribute__((address_space(1))) uint32_t*)g,
      (__attribute__((address_space(3))) uint32_t*)l, 16, 0, 0);
}
__device__ __forceinline__ f32x16 zero16() {
  f32x16 z;
  #pragma unroll
  for (int i = 0; i < 16; ++i) z[i] = 0.f;
  return z;
}

// -------------------- unified prep: 5 transposes + 2 weight packs --------------------
__global__ void prep_k(
    const float* __restrict__ atom_fc_W, const float* __restrict__ nb_W,
    const float* __restrict__ matt_W, const float* __restrict__ mWih,
    const float* __restrict__ mWhh, const float* __restrict__ gru_Wih,
    const float* __restrict__ gru_Whh, const float* __restrict__ attend_W,
    float* __restrict__ atomfcT, float* __restrict__ naT, float* __restrict__ mattT,
    float* __restrict__ mWihT, float* __restrict__ mWhhT,
    __bf16* __restrict__ Wpk, __bf16* __restrict__ Apk) {
  int i = blockIdx.x * 256 + threadIdx.x;
  const int n0 = FPc * AFc, n1 = FPc * (AFc + BFc), n2 = FPc * FPc;
  const int n3 = 600 * FPc, n4 = 600 * FPc;
  const int nW = Rc * 6 * 49 * 1024, nA = Rc * 49 * 1024;
  if (i < n0) { int r = i / AFc, c = i % AFc; atomfcT[c * FPc + r] = atom_fc_W[i]; return; }
  i -= n0;
  if (i < n1) { int r = i / (AFc + BFc), c = i % (AFc + BFc); naT[c * FPc + r] = nb_W[i]; return; }
  i -= n1;
  if (i < n2) { int r = i / FPc, c = i % FPc; mattT[c * FPc + r] = matt_W[i]; return; }
  i -= n2;
  if (i < n3) { int r = i / FPc, c = i % FPc; mWihT[c * 600 + r] = mWih[i]; return; }
  i -= n3;
  if (i < n4) { int r = i / FPc, c = i % FPc; mWhhT[c * 600 + r] = mWhh[i]; return; }
  i -= n4;
  if (i < nW) {
    int j = i & 7, fl = (i >> 3) & 31, c = (i >> 8) & 3;
    int T = i >> 10;
    int kt = T % 7; T /= 7;
    int ft = T % 7; T /= 7;
    int g = T % 6;  int r = T / 6;
    int f = ft * 32 + fl, k = kt * 32 + c * 8 + j;
    float v = 0.f;
    if (f < FPc && k < FPc) {
      if (g < 3) v = gru_Wih[((size_t)r * 3 * FPc + g * FPc + f) * FPc + k];
      else       v = gru_Whh[((size_t)r * 3 * FPc + (g - 3) * FPc + f) * FPc + k];
    }
    Wpk[i] = (__bf16)v;
    return;
  }
  i -= nW;
  if (i < nA) {
    int j = i & 7, fl = (i >> 3) & 31, c = (i >> 8) & 3;
    int T = i >> 10;
    int kt = T % 7; T /= 7;
    int ft = T % 7; int r = T / 7;
    int f = ft * 32 + fl, k = kt * 32 + c * 8 + j;
    float v = (f < FPc && k < FPc) ? attend_W[((size_t)r * FPc + f) * FPc + k] : 0.f;
    Apk[i] = (__bf16)v;
  }
}

// -------------------- generic small GEMM (f32): Yb[rows][200] bf16 -------------------
template<int KD>
__global__ __launch_bounds__(256) void gemm8x1(
    const float* __restrict__ X, const float* __restrict__ WT,
    __bf16* __restrict__ Yb) {
  constexpr int TR = 8, LDP = 12;
  __shared__ float xT[KD * LDP];
  const int row0 = blockIdx.x * TR;
  const int tid = threadIdx.x;
  for (int e = tid; e < TR * KD; e += 256) {
    int r = e / KD, g = e - r * KD;
    xT[g * LDP + r] = X[(size_t)row0 * KD + e];
  }
  __syncthreads();
  const int f = tid;
  if (f < FPc) {
    float acc[TR];
    #pragma unroll
    for (int r = 0; r < TR; ++r) acc[r] = 0.f;
    #pragma unroll 4
    for (int g = 0; g < KD; ++g) {
      float w = WT[(size_t)g * FPc + f];
      float4 x0 = *reinterpret_cast<const float4*>(&xT[g * LDP]);
      float4 x1 = *reinterpret_cast<const float4*>(&xT[g * LDP + 4]);
      acc[0] = fmaf(x0.x, w, acc[0]); acc[1] = fmaf(x0.y, w, acc[1]);
      acc[2] = fmaf(x0.z, w, acc[2]); acc[3] = fmaf(x0.w, w, acc[3]);
      acc[4] = fmaf(x1.x, w, acc[4]); acc[5] = fmaf(x1.y, w, acc[5]);
      acc[6] = fmaf(x1.z, w, acc[6]); acc[7] = fmaf(x1.w, w, acc[7]);
    }
    #pragma unroll
    for (int r = 0; r < TR; ++r)
      Yb[(size_t)(row0 + r) * FPc + f] = (__bf16)acc[r];
  }
}

// -------------------- fused atom_list GEMM: atom_fc + neighbor-P ---------------------
__global__ __launch_bounds__(256) void gemm_dual(
    const float* __restrict__ X, const float* __restrict__ W1T,
    const float* __restrict__ b1, const float* __restrict__ W2T,
    float* __restrict__ Yraw, __bf16* __restrict__ Hb, __bf16* __restrict__ Pb) {
  constexpr int KD = AFc, TR = 8, LDP = 12;
  __shared__ float xT[KD * LDP];
  const int row0 = blockIdx.x * TR;
  const int tid = threadIdx.x;
  for (int e = tid; e < TR * KD; e += 256) {
    int r = e / KD, g = e - r * KD;
    xT[g * LDP + r] = X[(size_t)row0 * KD + e];
  }
  __syncthreads();
  const int f = tid;
  if (f < FPc) {
    float a1[TR], a2[TR];
    #pragma unroll
    for (int r = 0; r < TR; ++r) { a1[r] = 0.f; a2[r] = 0.f; }
    #pragma unroll 2
    for (int g = 0; g < KD; ++g) {
      float w1 = W1T[(size_t)g * FPc + f];
      float w2 = W2T[(size_t)g * FPc + f];
      float4 x0 = *reinterpret_cast<const float4*>(&xT[g * LDP]);
      float4 x1 = *reinterpret_cast<const float4*>(&xT[g * LDP + 4]);
      float xs[8] = {x0.x, x0.y, x0.z, x0.w, x1.x, x1.y, x1.z, x1.w};
      #pragma unroll
      for (int r = 0; r < TR; ++r) {
        a1[r] = fmaf(xs[r], w1, a1[r]);
        a2[r] = fmaf(xs[r], w2, a2[r]);
      }
    }
    const float bf = b1[f];
    #pragma unroll
    for (int r = 0; r < TR; ++r) {
      float v = a1[r] + bf;
      Yraw[(size_t)(row0 + r) * FPc + f] = v;
      Hb[(size_t)(row0 + r) * KP + f] = (__bf16)leaky(v);
      Pb[(size_t)(row0 + r) * FPc + f] = (__bf16)a2[r];
    }
  } else if (f < KP) {
    #pragma unroll
    for (int r = 0; r < TR; ++r) Hb[(size_t)(row0 + r) * KP + f] = (__bf16)0.f;
  }
}

// -------------------- fused attend + GRU v2 (measured 137-140 us) --------------------
// attend: WN frags in regs, Apk B direct from L2, epilogue -> xcL LDS (A-frag layout).
// gru: xc from LDS, h in 14 reg-frags, Bs LDS 2-deep + vmcnt(3) (3 loads/tile/wave).
__global__ __launch_bounds__(256, 2) void attgru_mfma(
    const __bf16* __restrict__ WNb, const __bf16* __restrict__ Apk,
    const float* __restrict__ attb, const float* __restrict__ SW,
    const __bf16* __restrict__ Hin, __bf16* __restrict__ Hout,
    const __bf16* __restrict__ Wpk,
    const float* __restrict__ bih, const float* __restrict__ bhh,
    float* __restrict__ actOut) {
  __shared__ __align__(16) __bf16 smem[40960];   // 81920 B
  __bf16* xcL = smem;                             // [wv4][kt7][1024] = 57344 B
  __bf16* Bs  = smem + 28672;                     // [buf2][g6][1024] = 24576 B
  const int tid = threadIdx.x, wv = tid >> 6, lane = tid & 63;
  const size_t row0 = (size_t)blockIdx.x * 128;
  const int fl = lane & 31;

  // ---- attend phase: xc = elu(WN @ attW.T + sumw*b) -> LDS (A-frag layout) ----
  {
    bf16x8 af[7][2];
    const __bf16* sw_ = WNb + (row0 + wv * 32 + fl) * KP + (lane >> 5) * 8;
    #pragma unroll
    for (int kt = 0; kt < 7; ++kt)
      #pragma unroll
      for (int h = 0; h < 2; ++h)
        af[kt][h] = *(const bf16x8*)(sw_ + kt * 32 + h * 16);

    const int xbase = wv * 7168 + ((fl >> 3) & 3) * 256 + (fl & 7);
    #pragma unroll
    for (int ft = 0; ft < 7; ++ft) {
      f32x16 acc = zero16();
      #pragma unroll
      for (int kt = 0; kt < 7; ++kt) {
        const __bf16* bt = Apk + ((size_t)ft * 7 + kt) * 1024 + lane * 8;
        bf16x8 b0 = *(const bf16x8*)(bt);
        bf16x8 b1 = *(const bf16x8*)(bt + 512);
        acc = __builtin_amdgcn_mfma_f32_32x32x16_bf16(af[kt][0], b0, acc, 0, 0, 0);
        acc = __builtin_amdgcn_mfma_f32_32x32x16_bf16(af[kt][1], b1, acc, 0, 0, 0);
      }
      const int f = ft * 32 + fl;
      const bool fok = f < FPc;
      const float bf = fok ? attb[f] : 0.f;
      #pragma unroll
      for (int reg = 0; reg < 16; ++reg) {
        int rl = (reg & 3) + 8 * (reg >> 2) + 4 * (lane >> 5);
        float v = fok ? eluf(acc[reg] + SW[row0 + wv * 32 + rl] * bf) : 0.f;
        xcL[xbase + ft * 1024 + rl * 8] = (__bf16)v;
      }
    }
  }
  // (no barrier: each wave reads back only its own region; lgkmcnt orders LDS)

  // ---- h fragments into registers ----
  bf16x8 hf[7][2];
  {
    const __bf16* sh = Hin + (row0 + wv * 32 + fl) * KP + (lane >> 5) * 8;
    #pragma unroll
    for (int kt = 0; kt < 7; ++kt)
      #pragma unroll
      for (int h = 0; h < 2; ++h)
        hf[kt][h] = *(const bf16x8*)(sh + kt * 32 + h * 16);
  }

  auto stageB = [&](int ft, int kt, int buf) {
    #pragma unroll
    for (int m3 = 0; m3 < 3; ++m3) {
      int m = wv * 3 + m3;               // 0..11
      int g = m >> 1, half = m & 1;
      const __bf16* s = Wpk + ((size_t)(g * 7 + ft) * 7 + kt) * 1024 + half * 512 + lane * 8;
      glds16(s, Bs + buf * 6144 + g * 1024 + half * 512);
    }
  };
  stageB(0, 0, 0);

  f32x16 gacc[6];
  #pragma unroll
  for (int g = 0; g < 6; ++g) gacc[g] = zero16();

  for (int ft = 0; ft < 7; ++ft) {
    #pragma unroll
    for (int kt = 0; kt < 7; ++kt) {
      const int it = ft * 7 + kt;
      const int buf = it & 1;
      const int nft = (kt == 6) ? ft + 1 : ft;
      const int nkt = (kt == 6) ? 0 : kt + 1;
      __builtin_amdgcn_sched_barrier(0);
      if (it < 48) stageB(nft, nkt, buf ^ 1);
      else         stageB(6, 6, buf ^ 1);          // dummy: keep 3 outstanding
      __builtin_amdgcn_sched_barrier(0);
      asm volatile("s_waitcnt vmcnt(3)" ::: "memory");
      __builtin_amdgcn_sched_barrier(0);
      __builtin_amdgcn_s_barrier();
      __builtin_amdgcn_sched_barrier(0);
      #pragma unroll
      for (int h = 0; h < 2; ++h) {
        bf16x8 xch = *(const bf16x8*)(xcL + wv * 7168 + kt * 1024 + h * 512 + lane * 8);
        bf16x8 hh = hf[kt][h];
        const __bf16* bb = Bs + buf * 6144 + h * 512 + lane * 8;
        bf16x8 b0 = *(const bf16x8*)(bb);
        bf16x8 b1 = *(const bf16x8*)(bb + 1024);
        bf16x8 b2 = *(const bf16x8*)(bb + 2048);
        bf16x8 b3 = *(const bf16x8*)(bb + 3072);
        bf16x8 b4 = *(const bf16x8*)(bb + 4096);
        bf16x8 b5 = *(const bf16x8*)(bb + 5120);
        __builtin_amdgcn_s_setprio(1);
        gacc[0] = __builtin_amdgcn_mfma_f32_32x32x16_bf16(xch, b0, gacc[0], 0, 0, 0);
        gacc[1] = __builtin_amdgcn_mfma_f32_32x32x16_bf16(xch, b1, gacc[1], 0, 0, 0);
        gacc[2] = __builtin_amdgcn_mfma_f32_32x32x16_bf16(xch, b2, gacc[2], 0, 0, 0);
        gacc[3] = __builtin_amdgcn_mfma_f32_32x32x16_bf16(hh, b3, gacc[3], 0, 0, 0);
        gacc[4] = __builtin_amdgcn_mfma_f32_32x32x16_bf16(hh, b4, gacc[4], 0, 0, 0);
        gacc[5] = __builtin_amdgcn_mfma_f32_32x32x16_bf16(hh, b5, gacc[5], 0, 0, 0);
        __builtin_amdgcn_s_setprio(0);
      }
      if (kt == 6) {
        const int f = ft * 32 + fl;
        const bool fok = f < FPc;
        float bir = 0, biz = 0, bin_ = 0, bhr = 0, bhz = 0, bhn = 0;
        if (fok) {
          bir = bih[f]; biz = bih[FPc + f]; bin_ = bih[2 * FPc + f];
          bhr = bhh[f]; bhz = bhh[FPc + f]; bhn = bhh[2 * FPc + f];
        }
        #pragma unroll
        for (int reg = 0; reg < 16; ++reg) {
          int rl = (reg & 3) + 8 * (reg >> 2) + 4 * (lane >> 5);
          size_t row = row0 + wv * 32 + rl;
          if (fok) {
            float ho = (float)Hin[row * KP + f];
            float rg_ = sigm(gacc[0][reg] + bir + gacc[3][reg] + bhr);
            float zg  = sigm(gacc[1][reg] + biz + gacc[4][reg] + bhz);
            float ng  = tanhf(gacc[2][reg] + bin_ + rg_ * (gacc[5][reg] + bhn));
            float hp = (1.f - zg) * ng + zg * ho;
            Hout[row * KP + f] = (__bf16)hp;
            actOut[row * FPc + f] = fmaxf(hp, 0.f);
          } else {
            Hout[row * KP + f] = (__bf16)0.f;
          }
        }
        #pragma unroll
        for (int g = 0; g < 6; ++g) gacc[g] = zero16();
      }
      __builtin_amdgcn_sched_barrier(0);
      __builtin_amdgcn_s_barrier();
      __builtin_amdgcn_sched_barrier(0);
    }
  }
}

// -------------------- attn round r>=1: per-molecule, 8 waves ------------------------
__global__ __launch_bounds__(512) void attn_molN(
    const __bf16* __restrict__ Hb, const int* __restrict__ adl,
    const float* __restrict__ alW, const float* __restrict__ albp,
    float* __restrict__ attnOut, __bf16* __restrict__ WNb, float* __restrict__ SW) {
  __shared__ __align__(16) __bf16 actL[128 * 224];
  __shared__ float saL[128], snL[128];
  const int b = blockIdx.x;
  const int tid = threadIdx.x, wv = tid >> 6, lane = tid & 63;
  const bool l36 = lane < 36;

  {
    const uint4* src = (const uint4*)(Hb + (size_t)b * 128 * KP);
    uint4* dst = (uint4*)actL;
    for (int i = tid; i < 128 * 224 / 8; i += 512) {
      uint4 v = src[i];
      uint32_t c[4] = {v.x, v.y, v.z, v.w};
      #pragma unroll
      for (int j = 0; j < 4; ++j) {
        uint32_t lo = c[j] & 0xffffu, hi = c[j] >> 16;
        if (lo & 0x8000u) lo = 0;
        if (hi & 0x8000u) hi = 0;
        c[j] = lo | (hi << 16);
      }
      dst[i] = make_uint4(c[0], c[1], c[2], c[3]);
    }
  }
  float wa0x = alW[2 * lane], wa0y = alW[2 * lane + 1];
  float wa1x = l36 ? alW[128 + 2 * lane] : 0.f, wa1y = l36 ? alW[129 + 2 * lane] : 0.f;
  float wn0x = alW[FPc + 2 * lane], wn0y = alW[FPc + 2 * lane + 1];
  float wn1x = l36 ? alW[FPc + 128 + 2 * lane] : 0.f, wn1y = l36 ? alW[FPc + 129 + 2 * lane] : 0.f;
  const float ab = albp[0];
  __syncthreads();

  for (int i = 0; i < 16; ++i) {
    int l = wv * 16 + i;
    const uint32_t* rowp = (const uint32_t*)(actL + l * 224);
    uint32_t u0 = rowp[lane];
    uint32_t u1 = l36 ? rowp[64 + lane] : 0u;
    float x0 = bflo(u0), y0 = bfhi(u0), x1 = bflo(u1), y1 = bfhi(u1);
    float psa = x0 * wa0x + y0 * wa0y + x1 * wa1x + y1 * wa1y;
    float psn = x0 * wn0x + y0 * wn0y + x1 * wn1x + y1 * wn1y;
    psa = wave_sum(psa);
    psn = wave_sum(psn);
    if (lane == 0) { saL[l] = psa; snL[l] = psn; }
  }
  __syncthreads();

  for (int i = 0; i < 16; ++i) {
    const int row = wv * 16 + i;
    const size_t grow = (size_t)b * 128 + row;
    int gk = (lane < Kc) ? adl[grow * Kc + lane] : 0;
    int ai[Kc];
    #pragma unroll
    for (int k = 0; k < Kc; ++k) ai[k] = __shfl(gk, k);
    const float sarow = saL[row];
    float s[Kc]; bool pad[Kc]; float mx = -3.0e38f;
    #pragma unroll
    for (int k = 0; k < Kc; ++k) {
      pad[k] = (ai[k] == Lc - 1);
      s[k] = leaky(sarow + snL[ai[k]] + ab) + (pad[k] ? NEGC : 0.f);
      mx = fmaxf(mx, s[k]);
    }
    float e[Kc], sum = 0.f;
    #pragma unroll
    for (int k = 0; k < Kc; ++k) { e[k] = __expf(s[k] - mx); sum += e[k]; }
    float inv = 1.f / sum;
    float w[Kc], sw = 0.f;
    #pragma unroll
    for (int k = 0; k < Kc; ++k) { w[k] = pad[k] ? 0.f : e[k] * inv; sw += w[k]; }
    if (lane < Kc) attnOut[grow * Kc + lane] = w[lane];
    if (lane == 0) SW[grow] = sw;
    float a0 = 0.f, b0 = 0.f, a1 = 0.f, b1 = 0.f;
    #pragma unroll
    for (int k = 0; k < Kc; ++k) {
      const uint32_t* nr = (const uint32_t*)(actL + ai[k] * 224);
      uint32_t u0 = nr[lane];
      uint32_t u1 = l36 ? nr[64 + lane] : 0u;
      a0 = fmaf(w[k], bflo(u0), a0); b0 = fmaf(w[k], bfhi(u0), b0);
      a1 = fmaf(w[k], bflo(u1), a1); b1 = fmaf(w[k], bfhi(u1), b1);
    }
    __bf16* wr = WNb + grow * KP;
    ushort2 o0; o0.x = f2bu(a0); o0.y = f2bu(b0);
    *(ushort2*)(wr + 2 * lane) = o0;
    if (lane < 48) {
      float va = l36 ? a1 : 0.f, vb = l36 ? b1 : 0.f;
      ushort2 o1; o1.x = f2bu(va); o1.y = f2bu(vb);
      *(ushort2*)(wr + 128 + 2 * lane) = o1;
    }
  }
}

// -------------------- attn round r==0: per-molecule block, 8 waves, v-reg cache -----
__global__ __launch_bounds__(512) void attn_mol0(
    const __bf16* __restrict__ Pb, const __bf16* __restrict__ Qb,
    const float* __restrict__ nbb, const __bf16* __restrict__ Hb0,
    const int* __restrict__ adl, const int* __restrict__ bdl,
    const float* __restrict__ alW, const float* __restrict__ albp,
    float* __restrict__ attnOut, __bf16* __restrict__ WNb, float* __restrict__ SW) {
  __shared__ __align__(16) __bf16 Pl[128 * 200];
  __shared__ __align__(16) __bf16 Ql[128 * 200];
  __shared__ float nbbL[200];
  __shared__ float saL[128];
  const int b = blockIdx.x;
  const int tid = threadIdx.x, wv = tid >> 6, lane = tid & 63;
  const bool l36 = lane < 36;

  {
    const uint4* sp = (const uint4*)(Pb + (size_t)b * 128 * FPc);
    const uint4* sq = (const uint4*)(Qb + (size_t)b * 128 * FPc);
    uint4* dp = (uint4*)Pl;
    uint4* dq = (uint4*)Ql;
    for (int i = tid; i < 128 * 200 / 8; i += 512) { dp[i] = sp[i]; dq[i] = sq[i]; }
    for (int i = tid; i < FPc; i += 512) nbbL[i] = nbb[i];
  }
  float wa0x = alW[2 * lane], wa0y = alW[2 * lane + 1];
  float wa1x = l36 ? alW[128 + 2 * lane] : 0.f, wa1y = l36 ? alW[129 + 2 * lane] : 0.f;
  float wn0x = alW[FPc + 2 * lane], wn0y = alW[FPc + 2 * lane + 1];
  float wn1x = l36 ? alW[FPc + 128 + 2 * lane] : 0.f, wn1y = l36 ? alW[FPc + 129 + 2 * lane] : 0.f;
  const float ab = albp[0];

  for (int i = 0; i < 16; ++i) {
    int l = wv * 16 + i;
    const uint32_t* hr = (const uint32_t*)(Hb0 + ((size_t)b * 128 + l) * KP);
    uint32_t u0 = hr[lane];
    uint32_t u1 = l36 ? hr[64 + lane] : 0u;
    float psa = bflo(u0) * wa0x + bfhi(u0) * wa0y + bflo(u1) * wa1x + bfhi(u1) * wa1y;
    psa = wave_sum(psa);
    if (lane == 0) saL[l] = psa;
  }
  __syncthreads();

  const float n0x = nbbL[2 * lane], n0y = nbbL[2 * lane + 1];
  const float n1x = l36 ? nbbL[128 + 2 * lane] : 0.f, n1y = l36 ? nbbL[129 + 2 * lane] : 0.f;

  for (int i = 0; i < 16; ++i) {
    const int row = wv * 16 + i;
    const size_t grow = (size_t)b * 128 + row;
    int gk = (lane < Kc) ? adl[grow * Kc + lane] : 0;
    int hk = (lane < Kc) ? bdl[grow * Kc + lane] : 0;
    int ai[Kc], bi[Kc];
    #pragma unroll
    for (int k = 0; k < Kc; ++k) { ai[k] = __shfl(gk, k); bi[k] = __shfl(hk, k); }
    float v0x[Kc], v0y[Kc], v1x[Kc], v1y[Kc], p[Kc];
    #pragma unroll
    for (int k = 0; k < Kc; ++k) {
      const uint32_t* pr = (const uint32_t*)(Pl + ai[k] * 200);
      const uint32_t* qr = (const uint32_t*)(Ql + bi[k] * 200);
      uint32_t up0 = pr[lane], uq0 = qr[lane];
      uint32_t up1 = l36 ? pr[64 + lane] : 0u, uq1 = l36 ? qr[64 + lane] : 0u;
      v0x[k] = leaky(bflo(up0) + bflo(uq0) + n0x);
      v0y[k] = leaky(bfhi(up0) + bfhi(uq0) + n0y);
      v1x[k] = l36 ? leaky(bflo(up1) + bflo(uq1) + n1x) : 0.f;
      v1y[k] = l36 ? leaky(bfhi(up1) + bfhi(uq1) + n1y) : 0.f;
      p[k] = v0x[k] * wn0x + v0y[k] * wn0y + v1x[k] * wn1x + v1y[k] * wn1y;
    }
    #pragma unroll
    for (int k = 0; k < Kc; ++k) p[k] = wave_sum(p[k]);
    const float sarow = saL[row];
    float s[Kc]; bool pad[Kc]; float mx = -3.0e38f;
    #pragma unroll
    for (int k = 0; k < Kc; ++k) {
      pad[k] = (ai[k] == Lc - 1);
      s[k] = leaky(sarow + p[k] + ab) + (pad[k] ? NEGC : 0.f);
      mx = fmaxf(mx, s[k]);
    }
    float e[Kc], sum = 0.f;
    #pragma unroll
    for (int k = 0; k < Kc; ++k) { e[k] = __expf(s[k] - mx); sum += e[k]; }
    float inv = 1.f / sum;
    float w[Kc], sw = 0.f;
    #pragma unroll
    for (int k = 0; k < Kc; ++k) { w[k] = pad[k] ? 0.f : e[k] * inv; sw += w[k]; }
    if (lane < Kc) attnOut[grow * Kc + lane] = w[lane];
    if (lane == 0) SW[grow] = sw;
    float a0 = 0.f, b0v = 0.f, a1 = 0.f, b1v = 0.f;
    #pragma unroll
    for (int k = 0; k < Kc; ++k) {
      a0  = fmaf(w[k], v0x[k], a0);
      b0v = fmaf(w[k], v0y[k], b0v);
      a1  = fmaf(w[k], v1x[k], a1);
      b1v = fmaf(w[k], v1y[k], b1v);
    }
    __bf16* wr = WNb + grow * KP;
    ushort2 o0; o0.x = f2bu(a0); o0.y = f2bu(b0v);
    *(ushort2*)(wr + 2 * lane) = o0;
    if (lane < 48) {
      float va = l36 ? a1 : 0.f, vb = l36 ? b1v : 0.f;
      ushort2 o1; o1.x = f2bu(va); o1.y = f2bu(vb);
      *(ushort2*)(wr + 128 + 2 * lane) = o1;
    }
  }
}

// -------------------- fused mol phase v2: act staged in LDS (bf16) -------------------
__global__ __launch_bounds__(256) void mol_fused(
    const __bf16* __restrict__ Hb, const float* __restrict__ mask,
    const float* __restrict__ malW, const float* __restrict__ malb,
    const float* __restrict__ mattT, const float* __restrict__ matt_b,
    const float* __restrict__ mWihT, const float* __restrict__ mWhhT,
    const float* __restrict__ mbih, const float* __restrict__ mbhh,
    const float* __restrict__ outW, const float* __restrict__ outb,
    float* __restrict__ MV, float* __restrict__ MU, float* __restrict__ MA,
    float* __restrict__ PRED) {
  const int b = blockIdx.x;
  __shared__ __align__(16) __bf16 actL[Lc * FPc];   // 51200 B
  __shared__ float mk[Lc];
  __shared__ float molf[FPc], actm[FPc], wact[FPc], ctx[FPc];
  __shared__ float snL[Lc], wl[Lc];
  __shared__ float red[4], red2[4];
  const int tid = threadIdx.x, wv = tid >> 6, lane = tid & 63;
  const bool l36 = lane < 36;

  for (int l = tid; l < Lc; l += 256) mk[l] = mask[b * Lc + l];
  __syncthreads();
  const int f = tid;
  if (f < FPc) {
    float s1 = 0.f, s2 = 0.f;
    for (int l = 0; l < Lc; ++l) {
      float m = mk[l];
      float h = (float)Hb[((size_t)b * Lc + l) * KP + f];
      float a = fmaxf(h, 0.f);
      actL[l * FPc + f] = (__bf16)a;
      s1 = fmaf(h, m, s1);
      s2 = fmaf(a, m, s2);
    }
    MU[b * FPc + f] = s1;
    MV[b * FPc + f] = s2;
    molf[f] = s2;
    actm[f] = fmaxf(s2, 0.f);
  }
  float wn0x = malW[FPc + 2 * lane], wn0y = malW[FPc + 2 * lane + 1];
  float wn1x = l36 ? malW[FPc + 128 + 2 * lane] : 0.f;
  float wn1y = l36 ? malW[FPc + 129 + 2 * lane] : 0.f;
  __syncthreads();

  for (int t = 0; t < Tc; ++t) {
    {
      float p = 0.f;
      for (int i = tid; i < FPc; i += 256) p = fmaf(actm[i], malW[i], p);
      p = wave_sum(p);
      if (lane == 0) red[wv] = p;
    }
    for (int l = wv; l < Lc; l += 4) {
      const uint32_t* rowp = (const uint32_t*)(actL + l * FPc);
      uint32_t u0 = rowp[lane];
      uint32_t u1 = l36 ? rowp[64 + lane] : 0u;
      float p = bflo(u0) * wn0x + bfhi(u0) * wn0y + bflo(u1) * wn1x + bfhi(u1) * wn1y;
      p = wave_sum(p);
      if (lane == 0) snL[l] = p;
    }
    __syncthreads();
    const float sa = red[0] + red[1] + red[2] + red[3];
    const int l = tid;
    float sc = -3.0e38f, mval = 0.f;
    if (l < Lc) {
      mval = mk[l];
      sc = leaky(sa + snL[l] + malb[0]) + (mval == 0.f ? NEGC : 0.f);
    }
    float m = sc;
    #pragma unroll
    for (int o = 32; o >= 1; o >>= 1) m = fmaxf(m, __shfl_xor(m, o));
    if (lane == 0) red[wv] = m;
    __syncthreads();
    float mx = fmaxf(red[0], red[1]);
    float e = (l < Lc) ? __expf(sc - mx) : 0.f;
    float s = e;
    #pragma unroll
    for (int o = 32; o >= 1; o >>= 1) s += __shfl_xor(s, o);
    if (lane == 0) red2[wv] = s;
    __syncthreads();
    float tot = red2[0] + red2[1];
    float w = 0.f;
    if (l < Lc) {
      w = e / tot * mval;
      wl[l] = w;
      MA[(size_t)t * Bc * Lc + b * Lc + l] = w;
    }
    float swp = w;
    #pragma unroll
    for (int o = 32; o >= 1; o >>= 1) swp += __shfl_xor(swp, o);
    if (lane == 0) red[wv] = swp;
    __syncthreads();
    const float sumw = red[0] + red[1];
    if (f < FPc) {
      float a = 0.f;
      for (int l2 = 0; l2 < Lc; ++l2)
        a = fmaf(wl[l2], (float)actL[l2 * FPc + f], a);
      wact[f] = a;
    }
    __syncthreads();
    if (f < FPc) {
      float a = 0.f;
      #pragma unroll 4
      for (int g = 0; g < FPc; ++g) a = fmaf(wact[g], mattT[(size_t)g * FPc + f], a);
      ctx[f] = eluf(fmaf(sumw, matt_b[f], a));
    }
    __syncthreads();
    float hp = 0.f;
    if (f < FPc) {
      float air = mbih[f], aiz = mbih[FPc + f], ain = mbih[2 * FPc + f];
      float ahr = mbhh[f], ahz = mbhh[FPc + f], ahn = mbhh[2 * FPc + f];
      #pragma unroll 2
      for (int g = 0; g < FPc; ++g) {
        float xc = ctx[g], hx = molf[g];
        const float* wi = &mWihT[(size_t)g * 600 + f];
        const float* wh = &mWhhT[(size_t)g * 600 + f];
        air = fmaf(xc, wi[0], air);
        aiz = fmaf(xc, wi[200], aiz);
        ain = fmaf(xc, wi[400], ain);
        ahr = fmaf(hx, wh[0], ahr);
        ahz = fmaf(hx, wh[200], ahz);
        ahn = fmaf(hx, wh[400], ahn);
      }
      float rg = sigm(air + ahr);
      float zg = sigm(aiz + ahz);
      float ng = tanhf(fmaf(rg, ahn, ain));
      hp = (1.f - zg) * ng + zg * molf[f];
      MU[(size_t)(t + 1) * Bc * FPc + b * FPc + f] = hp;
      MV[(size_t)(t + 1) * Bc * FPc + b * FPc + f] = fmaxf(hp, 0.f);
    }
    __syncthreads();
    if (f < FPc) {
      molf[f] = hp;
      actm[f] = fmaxf(hp, 0.f);
    }
    __syncthreads();
  }
  {
    float p = 0.f;
    for (int i = tid; i < FPc; i += 256) p = fmaf(molf[i], outW[i], p);
    p = wave_sum(p);
    if (lane == 0) red[wv] = p;
    __syncthreads();
    if (tid == 0) PRED[b] = red[0] + red[1] + red[2] + red[3] + outb[0];
  }
}

extern "C" void kernel_launch(void* const* d_in, const int* in_sizes, int n_in,
                              void* d_out, int out_size, void* d_ws, size_t ws_size,
                              hipStream_t stream) {
  const float* atom_list = (const float*)d_in[0];
  const float* bond_list = (const float*)d_in[1];
  const int*   adl       = (const int*)d_in[2];
  const int*   bdl       = (const int*)d_in[3];
  const float* mask      = (const float*)d_in[4];
  const float* atom_fc_W = (const float*)d_in[5];
  const float* atom_fc_b = (const float*)d_in[6];
  const float* nb_W      = (const float*)d_in[7];
  const float* nb_b      = (const float*)d_in[8];
  const float* align_W   = (const float*)d_in[9];
  const float* align_b   = (const float*)d_in[10];
  const float* attend_W  = (const float*)d_in[11];
  const float* attend_b  = (const float*)d_in[12];
  const float* gru_Wih   = (const float*)d_in[13];
  const float* gru_Whh   = (const float*)d_in[14];
  const float* gru_bih   = (const float*)d_in[15];
  const float* gru_bhh   = (const float*)d_in[16];
  const float* mal_W     = (const float*)d_in[17];
  const float* mal_b     = (const float*)d_in[18];
  const float* matt_W    = (const float*)d_in[19];
  const float* matt_b    = (const float*)d_in[20];
  const float* mWih      = (const float*)d_in[21];
  const float* mWhh      = (const float*)d_in[22];
  const float* mbih      = (const float*)d_in[23];
  const float* mbhh      = (const float*)d_in[24];
  const float* out_W     = (const float*)d_in[25];
  const float* out_b     = (const float*)d_in[26];

  float* out  = (float*)d_out;
  float* AV   = out;                                  // (4,B,L,FP)
  float* ATTN = AV + (size_t)4 * BL * FPc;            // (3,B,L,K)
  float* MV   = ATTN + (size_t)Rc * BL * Kc;          // (3,B,FP)
  float* MU   = MV + (size_t)3 * Bc * FPc;            // (3,B,FP)
  float* MA   = MU + (size_t)3 * Bc * FPc;            // (2,B,L)
  float* PRED = MA + (size_t)Tc * Bc * Lc;            // (B,1)

  char* w = (char*)d_ws;
  __bf16* Hb0  = (__bf16*)w; w += (size_t)BL * KP * 2;
  __bf16* Hb1  = (__bf16*)w; w += (size_t)BL * KP * 2;
  __bf16* WNb  = (__bf16*)w; w += (size_t)BL * KP * 2;
  __bf16* Pb   = (__bf16*)w; w += (size_t)BL * FPc * 2;
  __bf16* Qb   = (__bf16*)w; w += (size_t)BL * FPc * 2;
  __bf16* Wpk  = (__bf16*)w; w += (size_t)Rc * 6 * 49 * 1024 * 2;
  __bf16* Apk  = (__bf16*)w; w += (size_t)Rc * 49 * 1024 * 2;
  float* SW    = (float*)w;  w += (size_t)BL * 4;
  float* atomfcT = (float*)w; w += (size_t)AFc * FPc * 4;
  float* naT     = (float*)w; w += (size_t)(AFc + BFc) * FPc * 4;
  float* mattT   = (float*)w; w += (size_t)FPc * FPc * 4;
  float* mWihT   = (float*)w; w += (size_t)FPc * 600 * 4;
  float* mWhhT   = (float*)w; w += (size_t)FPc * 600 * 4;

  {
    const int nprep = FPc * AFc + FPc * (AFc + BFc) + FPc * FPc + 2 * 600 * FPc
                    + Rc * 6 * 49 * 1024 + Rc * 49 * 1024;
    prep_k<<<(nprep + 255) / 256, 256, 0, stream>>>(
        atom_fc_W, nb_W, matt_W, mWih, mWhh, gru_Wih, gru_Whh, attend_W,
        atomfcT, naT, mattT, mWihT, mWhhT, Wpk, Apk);
  }

  gemm_dual<<<BL / 8, 256, 0, stream>>>(atom_list, atomfcT, atom_fc_b, naT, AV, Hb0, Pb);
  gemm8x1<BFc><<<BL / 8, 256, 0, stream>>>(bond_list, naT + AFc * FPc, Qb);

  __bf16* Hbuf[2] = {Hb0, Hb1};
  for (int r = 0; r < Rc; ++r) {
    if (r == 0) {
      attn_mol0<<<Bc, 512, 0, stream>>>(Pb, Qb, nb_b, Hb0, adl, bdl,
          align_W, align_b, ATTN, WNb, SW);
    } else {
      attn_molN<<<Bc, 512, 0, stream>>>(Hbuf[r & 1], adl,
          align_W + (size_t)r * 2 * FPc, align_b + r,
          ATTN + (size_t)r * BL * Kc, WNb, SW);
    }
    attgru_mfma<<<BL / 128, 256, 0, stream>>>(WNb, Apk + (size_t)r * 49 * 1024,
        attend_b + (size_t)r * FPc, SW,
        Hbuf[r & 1], Hbuf[(r + 1) & 1],
        Wpk + (size_t)r * 6 * 49 * 1024, gru_bih + (size_t)r * 3 * FPc, gru_bhh + (size_t)r * 3 * FPc,
        AV + (size_t)(r + 1) * BL * FPc);
  }

  mol_fused<<<Bc, 256, 0, stream>>>(Hbuf[Rc & 1], mask,
      mal_W, mal_b, mattT, matt_b, mWihT, mWhhT, mbih, mbhh, out_W, out_b,
      MV, MU, MA, PRED);
}

// Round 14
// 707.168 us; speedup vs baseline: 1.8132x; 1.0756x over previous
//
#include <hip/hip_runtime.h>
#include <stdint.h>

#define Bc 512
#define Lc 128
#define Kc 6
#define AFc 39
#define BFc 10
#define FPc 200
#define Rc 3
#define Tc 2
constexpr int BL = Bc * Lc;          // 65536
constexpr int KP = 224;              // padded K / F for MFMA
constexpr float SLOPE = 0.01f;
constexpr float NEGC = -9e8f;

typedef __attribute__((ext_vector_type(8))) __bf16 bf16x8;
typedef __attribute__((ext_vector_type(16))) float f32x16;

__device__ __forceinline__ float leaky(float x) { return x >= 0.f ? x : SLOPE * x; }
__device__ __forceinline__ float sigm(float x) { return 1.f / (1.f + __expf(-x)); }
__device__ __forceinline__ float eluf(float x) { return x > 0.f ? x : expm1f(x); }
__device__ __forceinline__ float wave_sum(float v) {
  #pragma unroll
  for (int m = 32; m >= 1; m >>= 1) v += __shfl_xor(v, m);
  return v;
}
__device__ __forceinline__ float bflo(uint32_t u) { return __uint_as_float(u << 16); }
__device__ __forceinline__ float bfhi(uint32_t u) { return __uint_as_float(u & 0xffff0000u); }
__device__ __forceinline__ unsigned short f2bu(float x) {
  __bf16 b = (__bf16)x;
  return __builtin_bit_cast(unsigned short, b);
}
__device__ __forceinline__ uint32_t packbf(float a, float b) {
  return (uint32_t)f2bu(a) | ((uint32_t)f2bu(b) << 16);
}
__device__ __forceinline__ void glds16(const void* g, void* l) {
  __builtin_amdgcn_global_load_lds((const __attribute__((address_space(1))) uint32_t*)g,
      (__attribute__((address_space(3))) uint32_t*)l, 16, 0, 0);
}
__device__ __forceinline__ f32x16 zero16() {
  f32x16 z;
  #pragma unroll
  for (int i = 0; i < 16; ++i) z[i] = 0.f;
  return z;
}

// -------------------- unified prep: transposes + weight packs ------------------------
__global__ void prep_k(
    const float* __restrict__ atom_fc_W, const float* __restrict__ nb_W,
    const float* __restrict__ matt_W, const float* __restrict__ mWih,
    const float* __restrict__ mWhh, const float* __restrict__ gru_Wih,
    const float* __restrict__ gru_Whh, const float* __restrict__ attend_W,
    float* __restrict__ atomfcT, float* __restrict__ naT,
    uint32_t* __restrict__ mgpk, uint32_t* __restrict__ mattp,
    __bf16* __restrict__ Wpk, __bf16* __restrict__ Apk) {
  int i = blockIdx.x * 256 + threadIdx.x;
  const int n0 = FPc * AFc, n1 = FPc * (AFc + BFc);
  const int nG = 3 * FPc * FPc, nM = (FPc / 2) * FPc;
  const int nW = Rc * 6 * 49 * 1024, nA = Rc * 49 * 1024;
  if (i < n0) { int r = i / AFc, c = i % AFc; atomfcT[c * FPc + r] = atom_fc_W[i]; return; }
  i -= n0;
  if (i < n1) { int r = i / (AFc + BFc), c = i % (AFc + BFc); naT[c * FPc + r] = nb_W[i]; return; }
  i -= n1;
  if (i < nG) {
    int p = i / (FPc * FPc); int rem = i % (FPc * FPc);
    int g = rem / FPc, f = rem % FPc;
    float a, b;
    if (p == 0) {        // {wi_r, wi_z}
      a = mWih[(size_t)(0 * FPc + f) * FPc + g];
      b = mWih[(size_t)(1 * FPc + f) * FPc + g];
    } else if (p == 1) { // {wi_n, wh_r}
      a = mWih[(size_t)(2 * FPc + f) * FPc + g];
      b = mWhh[(size_t)(0 * FPc + f) * FPc + g];
    } else {             // {wh_z, wh_n}
      a = mWhh[(size_t)(1 * FPc + f) * FPc + g];
      b = mWhh[(size_t)(2 * FPc + f) * FPc + g];
    }
    mgpk[(size_t)p * FPc * FPc + g * FPc + f] = packbf(a, b);
    return;
  }
  i -= nG;
  if (i < nM) {
    int g2 = i / FPc, f = i % FPc;
    float a = matt_W[(size_t)f * FPc + 2 * g2];
    float b = matt_W[(size_t)f * FPc + 2 * g2 + 1];
    mattp[(size_t)g2 * FPc + f] = packbf(a, b);
    return;
  }
  i -= nM;
  if (i < nW) {
    int j = i & 7, fl = (i >> 3) & 31, c = (i >> 8) & 3;
    int T = i >> 10;
    int kt = T % 7; T /= 7;
    int ft = T % 7; T /= 7;
    int g = T % 6;  int r = T / 6;
    int f = ft * 32 + fl, k = kt * 32 + c * 8 + j;
    float v = 0.f;
    if (f < FPc && k < FPc) {
      if (g < 3) v = gru_Wih[((size_t)r * 3 * FPc + g * FPc + f) * FPc + k];
      else       v = gru_Whh[((size_t)r * 3 * FPc + (g - 3) * FPc + f) * FPc + k];
    }
    Wpk[i] = (__bf16)v;
    return;
  }
  i -= nW;
  if (i < nA) {
    int j = i & 7, fl = (i >> 3) & 31, c = (i >> 8) & 3;
    int T = i >> 10;
    int kt = T % 7; T /= 7;
    int ft = T % 7; int r = T / 7;
    int f = ft * 32 + fl, k = kt * 32 + c * 8 + j;
    float v = (f < FPc && k < FPc) ? attend_W[((size_t)r * FPc + f) * FPc + k] : 0.f;
    Apk[i] = (__bf16)v;
  }
}

// -------------------- generic small GEMM (f32): Yb[rows][200] bf16 -------------------
template<int KD>
__global__ __launch_bounds__(256) void gemm8x1(
    const float* __restrict__ X, const float* __restrict__ WT,
    __bf16* __restrict__ Yb) {
  constexpr int TR = 8, LDP = 12;
  __shared__ float xT[KD * LDP];
  const int row0 = blockIdx.x * TR;
  const int tid = threadIdx.x;
  for (int e = tid; e < TR * KD; e += 256) {
    int r = e / KD, g = e - r * KD;
    xT[g * LDP + r] = X[(size_t)row0 * KD + e];
  }
  __syncthreads();
  const int f = tid;
  if (f < FPc) {
    float acc[TR];
    #pragma unroll
    for (int r = 0; r < TR; ++r) acc[r] = 0.f;
    #pragma unroll 4
    for (int g = 0; g < KD; ++g) {
      float w = WT[(size_t)g * FPc + f];
      float4 x0 = *reinterpret_cast<const float4*>(&xT[g * LDP]);
      float4 x1 = *reinterpret_cast<const float4*>(&xT[g * LDP + 4]);
      acc[0] = fmaf(x0.x, w, acc[0]); acc[1] = fmaf(x0.y, w, acc[1]);
      acc[2] = fmaf(x0.z, w, acc[2]); acc[3] = fmaf(x0.w, w, acc[3]);
      acc[4] = fmaf(x1.x, w, acc[4]); acc[5] = fmaf(x1.y, w, acc[5]);
      acc[6] = fmaf(x1.z, w, acc[6]); acc[7] = fmaf(x1.w, w, acc[7]);
    }
    #pragma unroll
    for (int r = 0; r < TR; ++r)
      Yb[(size_t)(row0 + r) * FPc + f] = (__bf16)acc[r];
  }
}

// -------------------- fused atom_list GEMM: atom_fc + neighbor-P ---------------------
__global__ __launch_bounds__(256) void gemm_dual(
    const float* __restrict__ X, const float* __restrict__ W1T,
    const float* __restrict__ b1, const float* __restrict__ W2T,
    float* __restrict__ Yraw, __bf16* __restrict__ Hb, __bf16* __restrict__ Pb) {
  constexpr int KD = AFc, TR = 8, LDP = 12;
  __shared__ float xT[KD * LDP];
  const int row0 = blockIdx.x * TR;
  const int tid = threadIdx.x;
  for (int e = tid; e < TR * KD; e += 256) {
    int r = e / KD, g = e - r * KD;
    xT[g * LDP + r] = X[(size_t)row0 * KD + e];
  }
  __syncthreads();
  const int f = tid;
  if (f < FPc) {
    float a1[TR], a2[TR];
    #pragma unroll
    for (int r = 0; r < TR; ++r) { a1[r] = 0.f; a2[r] = 0.f; }
    #pragma unroll 2
    for (int g = 0; g < KD; ++g) {
      float w1 = W1T[(size_t)g * FPc + f];
      float w2 = W2T[(size_t)g * FPc + f];
      float4 x0 = *reinterpret_cast<const float4*>(&xT[g * LDP]);
      float4 x1 = *reinterpret_cast<const float4*>(&xT[g * LDP + 4]);
      float xs[8] = {x0.x, x0.y, x0.z, x0.w, x1.x, x1.y, x1.z, x1.w};
      #pragma unroll
      for (int r = 0; r < TR; ++r) {
        a1[r] = fmaf(xs[r], w1, a1[r]);
        a2[r] = fmaf(xs[r], w2, a2[r]);
      }
    }
    const float bf = b1[f];
    #pragma unroll
    for (int r = 0; r < TR; ++r) {
      float v = a1[r] + bf;
      Yraw[(size_t)(row0 + r) * FPc + f] = v;
      Hb[(size_t)(row0 + r) * KP + f] = (__bf16)leaky(v);
      Pb[(size_t)(row0 + r) * FPc + f] = (__bf16)a2[r];
    }
  } else if (f < KP) {
    #pragma unroll
    for (int r = 0; r < TR; ++r) Hb[(size_t)(row0 + r) * KP + f] = (__bf16)0.f;
  }
}

// -------------------- fused attend + GRU v2 (measured 137-140 us) --------------------
__global__ __launch_bounds__(256, 2) void attgru_mfma(
    const __bf16* __restrict__ WNb, const __bf16* __restrict__ Apk,
    const float* __restrict__ attb, const float* __restrict__ SW,
    const __bf16* __restrict__ Hin, __bf16* __restrict__ Hout,
    const __bf16* __restrict__ Wpk,
    const float* __restrict__ bih, const float* __restrict__ bhh,
    float* __restrict__ actOut) {
  __shared__ __align__(16) __bf16 smem[40960];   // 81920 B
  __bf16* xcL = smem;                             // [wv4][kt7][1024] = 57344 B
  __bf16* Bs  = smem + 28672;                     // [buf2][g6][1024] = 24576 B
  const int tid = threadIdx.x, wv = tid >> 6, lane = tid & 63;
  const size_t row0 = (size_t)blockIdx.x * 128;
  const int fl = lane & 31;

  // ---- attend phase: xc = elu(WN @ attW.T + sumw*b) -> LDS (A-frag layout) ----
  {
    bf16x8 af[7][2];
    const __bf16* sw_ = WNb + (row0 + wv * 32 + fl) * KP + (lane >> 5) * 8;
    #pragma unroll
    for (int kt = 0; kt < 7; ++kt)
      #pragma unroll
      for (int h = 0; h < 2; ++h)
        af[kt][h] = *(const bf16x8*)(sw_ + kt * 32 + h * 16);

    const int xbase = wv * 7168 + ((fl >> 3) & 3) * 256 + (fl & 7);
    #pragma unroll
    for (int ft = 0; ft < 7; ++ft) {
      f32x16 acc = zero16();
      #pragma unroll
      for (int kt = 0; kt < 7; ++kt) {
        const __bf16* bt = Apk + ((size_t)ft * 7 + kt) * 1024 + lane * 8;
        bf16x8 b0 = *(const bf16x8*)(bt);
        bf16x8 b1 = *(const bf16x8*)(bt + 512);
        acc = __builtin_amdgcn_mfma_f32_32x32x16_bf16(af[kt][0], b0, acc, 0, 0, 0);
        acc = __builtin_amdgcn_mfma_f32_32x32x16_bf16(af[kt][1], b1, acc, 0, 0, 0);
      }
      const int f = ft * 32 + fl;
      const bool fok = f < FPc;
      const float bf = fok ? attb[f] : 0.f;
      #pragma unroll
      for (int reg = 0; reg < 16; ++reg) {
        int rl = (reg & 3) + 8 * (reg >> 2) + 4 * (lane >> 5);
        float v = fok ? eluf(acc[reg] + SW[row0 + wv * 32 + rl] * bf) : 0.f;
        xcL[xbase + ft * 1024 + rl * 8] = (__bf16)v;
      }
    }
  }
  // (no barrier: each wave reads back only its own region; lgkmcnt orders LDS)

  // ---- h fragments into registers ----
  bf16x8 hf[7][2];
  {
    const __bf16* sh = Hin + (row0 + wv * 32 + fl) * KP + (lane >> 5) * 8;
    #pragma unroll
    for (int kt = 0; kt < 7; ++kt)
      #pragma unroll
      for (int h = 0; h < 2; ++h)
        hf[kt][h] = *(const bf16x8*)(sh + kt * 32 + h * 16);
  }

  auto stageB = [&](int ft, int kt, int buf) {
    #pragma unroll
    for (int m3 = 0; m3 < 3; ++m3) {
      int m = wv * 3 + m3;               // 0..11
      int g = m >> 1, half = m & 1;
      const __bf16* s = Wpk + ((size_t)(g * 7 + ft) * 7 + kt) * 1024 + half * 512 + lane * 8;
      glds16(s, Bs + buf * 6144 + g * 1024 + half * 512);
    }
  };
  stageB(0, 0, 0);

  f32x16 gacc[6];
  #pragma unroll
  for (int g = 0; g < 6; ++g) gacc[g] = zero16();

  for (int ft = 0; ft < 7; ++ft) {
    #pragma unroll
    for (int kt = 0; kt < 7; ++kt) {
      const int it = ft * 7 + kt;
      const int buf = it & 1;
      const int nft = (kt == 6) ? ft + 1 : ft;
      const int nkt = (kt == 6) ? 0 : kt + 1;
      __builtin_amdgcn_sched_barrier(0);
      if (it < 48) stageB(nft, nkt, buf ^ 1);
      else         stageB(6, 6, buf ^ 1);          // dummy: keep 3 outstanding
      __builtin_amdgcn_sched_barrier(0);
      asm volatile("s_waitcnt vmcnt(3)" ::: "memory");
      __builtin_amdgcn_sched_barrier(0);
      __builtin_amdgcn_s_barrier();
      __builtin_amdgcn_sched_barrier(0);
      #pragma unroll
      for (int h = 0; h < 2; ++h) {
        bf16x8 xch = *(const bf16x8*)(xcL + wv * 7168 + kt * 1024 + h * 512 + lane * 8);
        bf16x8 hh = hf[kt][h];
        const __bf16* bb = Bs + buf * 6144 + h * 512 + lane * 8;
        bf16x8 b0 = *(const bf16x8*)(bb);
        bf16x8 b1 = *(const bf16x8*)(bb + 1024);
        bf16x8 b2 = *(const bf16x8*)(bb + 2048);
        bf16x8 b3 = *(const bf16x8*)(bb + 3072);
        bf16x8 b4 = *(const bf16x8*)(bb + 4096);
        bf16x8 b5 = *(const bf16x8*)(bb + 5120);
        __builtin_amdgcn_s_setprio(1);
        gacc[0] = __builtin_amdgcn_mfma_f32_32x32x16_bf16(xch, b0, gacc[0], 0, 0, 0);
        gacc[1] = __builtin_amdgcn_mfma_f32_32x32x16_bf16(xch, b1, gacc[1], 0, 0, 0);
        gacc[2] = __builtin_amdgcn_mfma_f32_32x32x16_bf16(xch, b2, gacc[2], 0, 0, 0);
        gacc[3] = __builtin_amdgcn_mfma_f32_32x32x16_bf16(hh, b3, gacc[3], 0, 0, 0);
        gacc[4] = __builtin_amdgcn_mfma_f32_32x32x16_bf16(hh, b4, gacc[4], 0, 0, 0);
        gacc[5] = __builtin_amdgcn_mfma_f32_32x32x16_bf16(hh, b5, gacc[5], 0, 0, 0);
        __builtin_amdgcn_s_setprio(0);
      }
      if (kt == 6) {
        const int f = ft * 32 + fl;
        const bool fok = f < FPc;
        float bir = 0, biz = 0, bin_ = 0, bhr = 0, bhz = 0, bhn = 0;
        if (fok) {
          bir = bih[f]; biz = bih[FPc + f]; bin_ = bih[2 * FPc + f];
          bhr = bhh[f]; bhz = bhh[FPc + f]; bhn = bhh[2 * FPc + f];
        }
        #pragma unroll
        for (int reg = 0; reg < 16; ++reg) {
          int rl = (reg & 3) + 8 * (reg >> 2) + 4 * (lane >> 5);
          size_t row = row0 + wv * 32 + rl;
          if (fok) {
            float ho = (float)Hin[row * KP + f];
            float rg_ = sigm(gacc[0][reg] + bir + gacc[3][reg] + bhr);
            float zg  = sigm(gacc[1][reg] + biz + gacc[4][reg] + bhz);
            float ng  = tanhf(gacc[2][reg] + bin_ + rg_ * (gacc[5][reg] + bhn));
            float hp = (1.f - zg) * ng + zg * ho;
            Hout[row * KP + f] = (__bf16)hp;
            actOut[row * FPc + f] = fmaxf(hp, 0.f);
          } else {
            Hout[row * KP + f] = (__bf16)0.f;
          }
        }
        #pragma unroll
        for (int g = 0; g < 6; ++g) gacc[g] = zero16();
      }
      __builtin_amdgcn_sched_barrier(0);
      __builtin_amdgcn_s_barrier();
      __builtin_amdgcn_sched_barrier(0);
    }
  }
}

// -------------------- attn round r>=1: per-molecule, 8 waves ------------------------
__global__ __launch_bounds__(512) void attn_molN(
    const __bf16* __restrict__ Hb, const int* __restrict__ adl,
    const float* __restrict__ alW, const float* __restrict__ albp,
    float* __restrict__ attnOut, __bf16* __restrict__ WNb, float* __restrict__ SW) {
  __shared__ __align__(16) __bf16 actL[128 * 224];
  __shared__ float saL[128], snL[128];
  const int b = blockIdx.x;
  const int tid = threadIdx.x, wv = tid >> 6, lane = tid & 63;
  const bool l36 = lane < 36;

  {
    const uint4* src = (const uint4*)(Hb + (size_t)b * 128 * KP);
    uint4* dst = (uint4*)actL;
    for (int i = tid; i < 128 * 224 / 8; i += 512) {
      uint4 v = src[i];
      uint32_t c[4] = {v.x, v.y, v.z, v.w};
      #pragma unroll
      for (int j = 0; j < 4; ++j) {
        uint32_t lo = c[j] & 0xffffu, hi = c[j] >> 16;
        if (lo & 0x8000u) lo = 0;
        if (hi & 0x8000u) hi = 0;
        c[j] = lo | (hi << 16);
      }
      dst[i] = make_uint4(c[0], c[1], c[2], c[3]);
    }
  }
  float wa0x = alW[2 * lane], wa0y = alW[2 * lane + 1];
  float wa1x = l36 ? alW[128 + 2 * lane] : 0.f, wa1y = l36 ? alW[129 + 2 * lane] : 0.f;
  float wn0x = alW[FPc + 2 * lane], wn0y = alW[FPc + 2 * lane + 1];
  float wn1x = l36 ? alW[FPc + 128 + 2 * lane] : 0.f, wn1y = l36 ? alW[FPc + 129 + 2 * lane] : 0.f;
  const float ab = albp[0];
  __syncthreads();

  for (int i = 0; i < 16; ++i) {
    int l = wv * 16 + i;
    const uint32_t* rowp = (const uint32_t*)(actL + l * 224);
    uint32_t u0 = rowp[lane];
    uint32_t u1 = l36 ? rowp[64 + lane] : 0u;
    float x0 = bflo(u0), y0 = bfhi(u0), x1 = bflo(u1), y1 = bfhi(u1);
    float psa = x0 * wa0x + y0 * wa0y + x1 * wa1x + y1 * wa1y;
    float psn = x0 * wn0x + y0 * wn0y + x1 * wn1x + y1 * wn1y;
    psa = wave_sum(psa);
    psn = wave_sum(psn);
    if (lane == 0) { saL[l] = psa; snL[l] = psn; }
  }
  __syncthreads();

  for (int i = 0; i < 16; ++i) {
    const int row = wv * 16 + i;
    const size_t grow = (size_t)b * 128 + row;
    int gk = (lane < Kc) ? adl[grow * Kc + lane] : 0;
    int ai[Kc];
    #pragma unroll
    for (int k = 0; k < Kc; ++k) ai[k] = __shfl(gk, k);
    const float sarow = saL[row];
    float s[Kc]; bool pad[Kc]; float mx = -3.0e38f;
    #pragma unroll
    for (int k = 0; k < Kc; ++k) {
      pad[k] = (ai[k] == Lc - 1);
      s[k] = leaky(sarow + snL[ai[k]] + ab) + (pad[k] ? NEGC : 0.f);
      mx = fmaxf(mx, s[k]);
    }
    float e[Kc], sum = 0.f;
    #pragma unroll
    for (int k = 0; k < Kc; ++k) { e[k] = __expf(s[k] - mx); sum += e[k]; }
    float inv = 1.f / sum;
    float w[Kc], sw = 0.f;
    #pragma unroll
    for (int k = 0; k < Kc; ++k) { w[k] = pad[k] ? 0.f : e[k] * inv; sw += w[k]; }
    if (lane < Kc) attnOut[grow * Kc + lane] = w[lane];
    if (lane == 0) SW[grow] = sw;
    float a0 = 0.f, b0 = 0.f, a1 = 0.f, b1 = 0.f;
    #pragma unroll
    for (int k = 0; k < Kc; ++k) {
      const uint32_t* nr = (const uint32_t*)(actL + ai[k] * 224);
      uint32_t u0 = nr[lane];
      uint32_t u1 = l36 ? nr[64 + lane] : 0u;
      a0 = fmaf(w[k], bflo(u0), a0); b0 = fmaf(w[k], bfhi(u0), b0);
      a1 = fmaf(w[k], bflo(u1), a1); b1 = fmaf(w[k], bfhi(u1), b1);
    }
    __bf16* wr = WNb + grow * KP;
    ushort2 o0; o0.x = f2bu(a0); o0.y = f2bu(b0);
    *(ushort2*)(wr + 2 * lane) = o0;
    if (lane < 48) {
      float va = l36 ? a1 : 0.f, vb = l36 ? b1 : 0.f;
      ushort2 o1; o1.x = f2bu(va); o1.y = f2bu(vb);
      *(ushort2*)(wr + 128 + 2 * lane) = o1;
    }
  }
}

// -------------------- attn round r==0: per-molecule block, 8 waves, v-reg cache -----
__global__ __launch_bounds__(512) void attn_mol0(
    const __bf16* __restrict__ Pb, const __bf16* __restrict__ Qb,
    const float* __restrict__ nbb, const __bf16* __restrict__ Hb0,
    const int* __restrict__ adl, const int* __restrict__ bdl,
    const float* __restrict__ alW, const float* __restrict__ albp,
    float* __restrict__ attnOut, __bf16* __restrict__ WNb, float* __restrict__ SW) {
  __shared__ __align__(16) __bf16 Pl[128 * 200];
  __shared__ __align__(16) __bf16 Ql[128 * 200];
  __shared__ float nbbL[200];
  __shared__ float saL[128];
  const int b = blockIdx.x;
  const int tid = threadIdx.x, wv = tid >> 6, lane = tid & 63;
  const bool l36 = lane < 36;

  {
    const uint4* sp = (const uint4*)(Pb + (size_t)b * 128 * FPc);
    const uint4* sq = (const uint4*)(Qb + (size_t)b * 128 * FPc);
    uint4* dp = (uint4*)Pl;
    uint4* dq = (uint4*)Ql;
    for (int i = tid; i < 128 * 200 / 8; i += 512) { dp[i] = sp[i]; dq[i] = sq[i]; }
    for (int i = tid; i < FPc; i += 512) nbbL[i] = nbb[i];
  }
  float wa0x = alW[2 * lane], wa0y = alW[2 * lane + 1];
  float wa1x = l36 ? alW[128 + 2 * lane] : 0.f, wa1y = l36 ? alW[129 + 2 * lane] : 0.f;
  float wn0x = alW[FPc + 2 * lane], wn0y = alW[FPc + 2 * lane + 1];
  float wn1x = l36 ? alW[FPc + 128 + 2 * lane] : 0.f, wn1y = l36 ? alW[FPc + 129 + 2 * lane] : 0.f;
  const float ab = albp[0];

  for (int i = 0; i < 16; ++i) {
    int l = wv * 16 + i;
    const uint32_t* hr = (const uint32_t*)(Hb0 + ((size_t)b * 128 + l) * KP);
    uint32_t u0 = hr[lane];
    uint32_t u1 = l36 ? hr[64 + lane] : 0u;
    float psa = bflo(u0) * wa0x + bfhi(u0) * wa0y + bflo(u1) * wa1x + bfhi(u1) * wa1y;
    psa = wave_sum(psa);
    if (lane == 0) saL[l] = psa;
  }
  __syncthreads();

  const float n0x = nbbL[2 * lane], n0y = nbbL[2 * lane + 1];
  const float n1x = l36 ? nbbL[128 + 2 * lane] : 0.f, n1y = l36 ? nbbL[129 + 2 * lane] : 0.f;

  for (int i = 0; i < 16; ++i) {
    const int row = wv * 16 + i;
    const size_t grow = (size_t)b * 128 + row;
    int gk = (lane < Kc) ? adl[grow * Kc + lane] : 0;
    int hk = (lane < Kc) ? bdl[grow * Kc + lane] : 0;
    int ai[Kc], bi[Kc];
    #pragma unroll
    for (int k = 0; k < Kc; ++k) { ai[k] = __shfl(gk, k); bi[k] = __shfl(hk, k); }
    float v0x[Kc], v0y[Kc], v1x[Kc], v1y[Kc], p[Kc];
    #pragma unroll
    for (int k = 0; k < Kc; ++k) {
      const uint32_t* pr = (const uint32_t*)(Pl + ai[k] * 200);
      const uint32_t* qr = (const uint32_t*)(Ql + bi[k] * 200);
      uint32_t up0 = pr[lane], uq0 = qr[lane];
      uint32_t up1 = l36 ? pr[64 + lane] : 0u, uq1 = l36 ? qr[64 + lane] : 0u;
      v0x[k] = leaky(bflo(up0) + bflo(uq0) + n0x);
      v0y[k] = leaky(bfhi(up0) + bfhi(uq0) + n0y);
      v1x[k] = l36 ? leaky(bflo(up1) + bflo(uq1) + n1x) : 0.f;
      v1y[k] = l36 ? leaky(bfhi(up1) + bfhi(uq1) + n1y) : 0.f;
      p[k] = v0x[k] * wn0x + v0y[k] * wn0y + v1x[k] * wn1x + v1y[k] * wn1y;
    }
    #pragma unroll
    for (int k = 0; k < Kc; ++k) p[k] = wave_sum(p[k]);
    const float sarow = saL[row];
    float s[Kc]; bool pad[Kc]; float mx = -3.0e38f;
    #pragma unroll
    for (int k = 0; k < Kc; ++k) {
      pad[k] = (ai[k] == Lc - 1);
      s[k] = leaky(sarow + p[k] + ab) + (pad[k] ? NEGC : 0.f);
      mx = fmaxf(mx, s[k]);
    }
    float e[Kc], sum = 0.f;
    #pragma unroll
    for (int k = 0; k < Kc; ++k) { e[k] = __expf(s[k] - mx); sum += e[k]; }
    float inv = 1.f / sum;
    float w[Kc], sw = 0.f;
    #pragma unroll
    for (int k = 0; k < Kc; ++k) { w[k] = pad[k] ? 0.f : e[k] * inv; sw += w[k]; }
    if (lane < Kc) attnOut[grow * Kc + lane] = w[lane];
    if (lane == 0) SW[grow] = sw;
    float a0 = 0.f, b0v = 0.f, a1 = 0.f, b1v = 0.f;
    #pragma unroll
    for (int k = 0; k < Kc; ++k) {
      a0  = fmaf(w[k], v0x[k], a0);
      b0v = fmaf(w[k], v0y[k], b0v);
      a1  = fmaf(w[k], v1x[k], a1);
      b1v = fmaf(w[k], v1y[k], b1v);
    }
    __bf16* wr = WNb + grow * KP;
    ushort2 o0; o0.x = f2bu(a0); o0.y = f2bu(b0v);
    *(ushort2*)(wr + 2 * lane) = o0;
    if (lane < 48) {
      float va = l36 ? a1 : 0.f, vb = l36 ? b1v : 0.f;
      ushort2 o1; o1.x = f2bu(va); o1.y = f2bu(vb);
      *(ushort2*)(wr + 128 + 2 * lane) = o1;
    }
  }
}

// -------------------- fused mol phase v3: bf16-packed weights, sn hoisted ------------
__global__ __launch_bounds__(256) void mol_fused(
    const __bf16* __restrict__ Hb, const float* __restrict__ mask,
    const float* __restrict__ malW, const float* __restrict__ malb,
    const uint32_t* __restrict__ mattp, const float* __restrict__ matt_b,
    const uint32_t* __restrict__ mgpk,
    const float* __restrict__ mbih, const float* __restrict__ mbhh,
    const float* __restrict__ outW, const float* __restrict__ outb,
    float* __restrict__ MV, float* __restrict__ MU, float* __restrict__ MA,
    float* __restrict__ PRED) {
  const int b = blockIdx.x;
  __shared__ __align__(16) __bf16 actL[Lc * FPc];   // 51200 B
  __shared__ float mk[Lc];
  __shared__ float molf[FPc], actm[FPc], wact[FPc], ctx[FPc];
  __shared__ float snL[Lc], wl[Lc];
  __shared__ float red[4], red2[4];
  const int tid = threadIdx.x, wv = tid >> 6, lane = tid & 63;
  const bool l36 = lane < 36;

  for (int l = tid; l < Lc; l += 256) mk[l] = mask[b * Lc + l];
  __syncthreads();
  const int f = tid;
  if (f < FPc) {
    float s1 = 0.f, s2 = 0.f;
    for (int l = 0; l < Lc; ++l) {
      float m = mk[l];
      float h = (float)Hb[((size_t)b * Lc + l) * KP + f];
      float a = fmaxf(h, 0.f);
      actL[l * FPc + f] = (__bf16)a;
      s1 = fmaf(h, m, s1);
      s2 = fmaf(a, m, s2);
    }
    MU[b * FPc + f] = s1;
    MV[b * FPc + f] = s2;
    molf[f] = s2;
    actm[f] = fmaxf(s2, 0.f);
  }
  float wn0x = malW[FPc + 2 * lane], wn0y = malW[FPc + 2 * lane + 1];
  float wn1x = l36 ? malW[FPc + 128 + 2 * lane] : 0.f;
  float wn1y = l36 ? malW[FPc + 129 + 2 * lane] : 0.f;
  __syncthreads();

  // sn[l] is t-invariant (depends only on atom act) -> compute once
  for (int l = wv; l < Lc; l += 4) {
    const uint32_t* rowp = (const uint32_t*)(actL + l * FPc);
    uint32_t u0 = rowp[lane];
    uint32_t u1 = l36 ? rowp[64 + lane] : 0u;
    float p = bflo(u0) * wn0x + bfhi(u0) * wn0y + bflo(u1) * wn1x + bfhi(u1) * wn1y;
    p = wave_sum(p);
    if (lane == 0) snL[l] = p;
  }
  __syncthreads();

  for (int t = 0; t < Tc; ++t) {
    {
      float p = 0.f;
      for (int i = tid; i < FPc; i += 256) p = fmaf(actm[i], malW[i], p);
      p = wave_sum(p);
      if (lane == 0) red[wv] = p;
    }
    __syncthreads();
    const float sa = red[0] + red[1] + red[2] + red[3];
    const int l = tid;
    float sc = -3.0e38f, mval = 0.f;
    if (l < Lc) {
      mval = mk[l];
      sc = leaky(sa + snL[l] + malb[0]) + (mval == 0.f ? NEGC : 0.f);
    }
    float m = sc;
    #pragma unroll
    for (int o = 32; o >= 1; o >>= 1) m = fmaxf(m, __shfl_xor(m, o));
    if (lane == 0) red[wv] = m;
    __syncthreads();
    float mx = fmaxf(red[0], red[1]);
    float e = (l < Lc) ? __expf(sc - mx) : 0.f;
    float s = e;
    #pragma unroll
    for (int o = 32; o >= 1; o >>= 1) s += __shfl_xor(s, o);
    if (lane == 0) red2[wv] = s;
    __syncthreads();
    float tot = red2[0] + red2[1];
    float w = 0.f;
    if (l < Lc) {
      w = e / tot * mval;
      wl[l] = w;
      MA[(size_t)t * Bc * Lc + b * Lc + l] = w;
    }
    float swp = w;
    #pragma unroll
    for (int o = 32; o >= 1; o >>= 1) swp += __shfl_xor(swp, o);
    if (lane == 0) red[wv] = swp;
    __syncthreads();
    const float sumw = red[0] + red[1];
    if (f < FPc) {
      float a = 0.f;
      for (int l2 = 0; l2 < Lc; ++l2)
        a = fmaf(wl[l2], (float)actL[l2 * FPc + f], a);
      wact[f] = a;
    }
    __syncthreads();
    // ctx[f] = elu(sum_g wact[g]*mattT[g][f] + sumw*matt_b[f]) via packed bf16 pairs
    if (f < FPc) {
      float a = 0.f;
      #pragma unroll 8
      for (int g2 = 0; g2 < FPc / 2; ++g2) {
        uint32_t u = mattp[(size_t)g2 * FPc + f];
        a = fmaf(wact[2 * g2], bflo(u), a);
        a = fmaf(wact[2 * g2 + 1], bfhi(u), a);
      }
      ctx[f] = eluf(fmaf(sumw, matt_b[f], a));
    }
    __syncthreads();
    // GRU via 3 packed planes {wi_r,wi_z} {wi_n,wh_r} {wh_z,wh_n}
    float hp = 0.f;
    if (f < FPc) {
      float air = mbih[f], aiz = mbih[FPc + f], ain = mbih[2 * FPc + f];
      float ahr = mbhh[f], ahz = mbhh[FPc + f], ahn = mbhh[2 * FPc + f];
      const uint32_t* p0 = mgpk + f;
      const uint32_t* p1 = mgpk + FPc * FPc + f;
      const uint32_t* p2 = mgpk + 2 * FPc * FPc + f;
      #pragma unroll 8
      for (int g = 0; g < FPc; ++g) {
        float xc = ctx[g], hx = molf[g];
        uint32_t u0 = p0[g * FPc], u1 = p1[g * FPc], u2 = p2[g * FPc];
        air = fmaf(xc, bflo(u0), air);
        aiz = fmaf(xc, bfhi(u0), aiz);
        ain = fmaf(xc, bflo(u1), ain);
        ahr = fmaf(hx, bfhi(u1), ahr);
        ahz = fmaf(hx, bflo(u2), ahz);
        ahn = fmaf(hx, bfhi(u2), ahn);
      }
      float rg = sigm(air + ahr);
      float zg = sigm(aiz + ahz);
      float ng = tanhf(fmaf(rg, ahn, ain));
      hp = (1.f - zg) * ng + zg * molf[f];
      MU[(size_t)(t + 1) * Bc * FPc + b * FPc + f] = hp;
      MV[(size_t)(t + 1) * Bc * FPc + b * FPc + f] = fmaxf(hp, 0.f);
    }
    __syncthreads();
    if (f < FPc) {
      molf[f] = hp;
      actm[f] = fmaxf(hp, 0.f);
    }
    __syncthreads();
  }
  {
    float p = 0.f;
    for (int i = tid; i < FPc; i += 256) p = fmaf(molf[i], outW[i], p);
    p = wave_sum(p);
    if (lane == 0) red[wv] = p;
    __syncthreads();
    if (tid == 0) PRED[b] = red[0] + red[1] + red[2] + red[3] + outb[0];
  }
}

extern "C" void kernel_launch(void* const* d_in, const int* in_sizes, int n_in,
                              void* d_out, int out_size, void* d_ws, size_t ws_size,
                              hipStream_t stream) {
  const float* atom_list = (const float*)d_in[0];
  const float* bond_list = (const float*)d_in[1];
  const int*   adl       = (const int*)d_in[2];
  const int*   bdl       = (const int*)d_in[3];
  const float* mask      = (const float*)d_in[4];
  const float* atom_fc_W = (const float*)d_in[5];
  const float* atom_fc_b = (const float*)d_in[6];
  const float* nb_W      = (const float*)d_in[7];
  const float* nb_b      = (const float*)d_in[8];
  const float* align_W   = (const float*)d_in[9];
  const float* align_b   = (const float*)d_in[10];
  const float* attend_W  = (const float*)d_in[11];
  const float* attend_b  = (const float*)d_in[12];
  const float* gru_Wih   = (const float*)d_in[13];
  const float* gru_Whh   = (const float*)d_in[14];
  const float* gru_bih   = (const float*)d_in[15];
  const float* gru_bhh   = (const float*)d_in[16];
  const float* mal_W     = (const float*)d_in[17];
  const float* mal_b     = (const float*)d_in[18];
  const float* matt_W    = (const float*)d_in[19];
  const float* matt_b    = (const float*)d_in[20];
  const float* mWih      = (const float*)d_in[21];
  const float* mWhh      = (const float*)d_in[22];
  const float* mbih      = (const float*)d_in[23];
  const float* mbhh      = (const float*)d_in[24];
  const float* out_W     = (const float*)d_in[25];
  const float* out_b     = (const float*)d_in[26];

  float* out  = (float*)d_out;
  float* AV   = out;                                  // (4,B,L,FP)
  float* ATTN = AV + (size_t)4 * BL * FPc;            // (3,B,L,K)
  float* MV   = ATTN + (size_t)Rc * BL * Kc;          // (3,B,FP)
  float* MU   = MV + (size_t)3 * Bc * FPc;            // (3,B,FP)
  float* MA   = MU + (size_t)3 * Bc * FPc;            // (2,B,L)
  float* PRED = MA + (size_t)Tc * Bc * Lc;            // (B,1)

  char* w = (char*)d_ws;
  __bf16* Hb0  = (__bf16*)w; w += (size_t)BL * KP * 2;
  __bf16* Hb1  = (__bf16*)w; w += (size_t)BL * KP * 2;
  __bf16* WNb  = (__bf16*)w; w += (size_t)BL * KP * 2;
  __bf16* Pb   = (__bf16*)w; w += (size_t)BL * FPc * 2;
  __bf16* Qb   = (__bf16*)w; w += (size_t)BL * FPc * 2;
  __bf16* Wpk  = (__bf16*)w; w += (size_t)Rc * 6 * 49 * 1024 * 2;
  __bf16* Apk  = (__bf16*)w; w += (size_t)Rc * 49 * 1024 * 2;
  float* SW    = (float*)w;  w += (size_t)BL * 4;
  float* atomfcT = (float*)w; w += (size_t)AFc * FPc * 4;
  float* naT     = (float*)w; w += (size_t)(AFc + BFc) * FPc * 4;
  uint32_t* mgpk = (uint32_t*)w; w += (size_t)3 * FPc * FPc * 4;
  uint32_t* mattp = (uint32_t*)w; w += (size_t)(FPc / 2) * FPc * 4;

  {
    const int nprep = FPc * AFc + FPc * (AFc + BFc) + 3 * FPc * FPc + (FPc / 2) * FPc
                    + Rc * 6 * 49 * 1024 + Rc * 49 * 1024;
    prep_k<<<(nprep + 255) / 256, 256, 0, stream>>>(
        atom_fc_W, nb_W, matt_W, mWih, mWhh, gru_Wih, gru_Whh, attend_W,
        atomfcT, naT, mgpk, mattp, Wpk, Apk);
  }

  gemm_dual<<<BL / 8, 256, 0, stream>>>(atom_list, atomfcT, atom_fc_b, naT, AV, Hb0, Pb);
  gemm8x1<BFc><<<BL / 8, 256, 0, stream>>>(bond_list, naT + AFc * FPc, Qb);

  __bf16* Hbuf[2] = {Hb0, Hb1};
  for (int r = 0; r < Rc; ++r) {
    if (r == 0) {
      attn_mol0<<<Bc, 512, 0, stream>>>(Pb, Qb, nb_b, Hb0, adl, bdl,
          align_W, align_b, ATTN, WNb, SW);
    } else {
      attn_molN<<<Bc, 512, 0, stream>>>(Hbuf[r & 1], adl,
          align_W + (size_t)r * 2 * FPc, align_b + r,
          ATTN + (size_t)r * BL * Kc, WNb, SW);
    }
    attgru_mfma<<<BL / 128, 256, 0, stream>>>(WNb, Apk + (size_t)r * 49 * 1024,
        attend_b + (size_t)r * FPc, SW,
        Hbuf[r & 1], Hbuf[(r + 1) & 1],
        Wpk + (size_t)r * 6 * 49 * 1024, gru_bih + (size_t)r * 3 * FPc, gru_bhh + (size_t)r * 3 * FPc,
        AV + (size_t)(r + 1) * BL * FPc);
  }

  mol_fused<<<Bc, 256, 0, stream>>>(Hbuf[Rc & 1], mask,
      mal_W, mal_b, mattp, matt_b, mgpk, mbih, mbhh, out_W, out_b,
      MV, MU, MA, PRED);
}

// Round 15
// 700.821 us; speedup vs baseline: 1.8296x; 1.0091x over previous
//
#include <hip/hip_runtime.h>
#include <stdint.h>

#define Bc 512
#define Lc 128
#define Kc 6
#define AFc 39
#define BFc 10
#define FPc 200
#define Rc 3
#define Tc 2
constexpr int BL = Bc * Lc;          // 65536
constexpr int KP = 224;              // padded K / F for MFMA
constexpr float SLOPE = 0.01f;
constexpr float NEGC = -9e8f;

typedef __attribute__((ext_vector_type(8))) __bf16 bf16x8;
typedef __attribute__((ext_vector_type(16))) float f32x16;

__device__ __forceinline__ float leaky(float x) { return x >= 0.f ? x : SLOPE * x; }
__device__ __forceinline__ float sigm(float x) { return 1.f / (1.f + __expf(-x)); }
__device__ __forceinline__ float eluf(float x) { return x > 0.f ? x : expm1f(x); }
__device__ __forceinline__ float wave_sum(float v) {
  #pragma unroll
  for (int m = 32; m >= 1; m >>= 1) v += __shfl_xor(v, m);
  return v;
}
__device__ __forceinline__ float bflo(uint32_t u) { return __uint_as_float(u << 16); }
__device__ __forceinline__ float bfhi(uint32_t u) { return __uint_as_float(u & 0xffff0000u); }
__device__ __forceinline__ unsigned short f2bu(float x) {
  __bf16 b = (__bf16)x;
  return __builtin_bit_cast(unsigned short, b);
}
__device__ __forceinline__ uint32_t packbf(float a, float b) {
  return (uint32_t)f2bu(a) | ((uint32_t)f2bu(b) << 16);
}
__device__ __forceinline__ void glds16(const void* g, void* l) {
  __builtin_amdgcn_global_load_lds((const __attribute__((address_space(1))) uint32_t*)g,
      (__attribute__((address_space(3))) uint32_t*)l, 16, 0, 0);
}
__device__ __forceinline__ f32x16 zero16() {
  f32x16 z;
  #pragma unroll
  for (int i = 0; i < 16; ++i) z[i] = 0.f;
  return z;
}

// -------------------- unified prep: transposes + weight packs ------------------------
__global__ void prep_k(
    const float* __restrict__ atom_fc_W, const float* __restrict__ nb_W,
    const float* __restrict__ matt_W, const float* __restrict__ mWih,
    const float* __restrict__ mWhh, const float* __restrict__ gru_Wih,
    const float* __restrict__ gru_Whh, const float* __restrict__ attend_W,
    float* __restrict__ atomfcT, float* __restrict__ naT,
    uint32_t* __restrict__ mgpk, uint32_t* __restrict__ mattp,
    __bf16* __restrict__ Wpk, __bf16* __restrict__ Apk) {
  int i = blockIdx.x * 256 + threadIdx.x;
  const int n0 = FPc * AFc, n1 = FPc * (AFc + BFc);
  const int nG = 3 * FPc * FPc, nM = (FPc / 2) * FPc;
  const int nW = Rc * 6 * 49 * 1024, nA = Rc * 49 * 1024;
  if (i < n0) { int r = i / AFc, c = i % AFc; atomfcT[c * FPc + r] = atom_fc_W[i]; return; }
  i -= n0;
  if (i < n1) { int r = i / (AFc + BFc), c = i % (AFc + BFc); naT[c * FPc + r] = nb_W[i]; return; }
  i -= n1;
  if (i < nG) {
    int p = i / (FPc * FPc); int rem = i % (FPc * FPc);
    int g = rem / FPc, f = rem % FPc;
    float a, b;
    if (p == 0) {        // {wi_r, wi_z}
      a = mWih[(size_t)(0 * FPc + f) * FPc + g];
      b = mWih[(size_t)(1 * FPc + f) * FPc + g];
    } else if (p == 1) { // {wi_n, wh_r}
      a = mWih[(size_t)(2 * FPc + f) * FPc + g];
      b = mWhh[(size_t)(0 * FPc + f) * FPc + g];
    } else {             // {wh_z, wh_n}
      a = mWhh[(size_t)(1 * FPc + f) * FPc + g];
      b = mWhh[(size_t)(2 * FPc + f) * FPc + g];
    }
    mgpk[(size_t)p * FPc * FPc + g * FPc + f] = packbf(a, b);
    return;
  }
  i -= nG;
  if (i < nM) {
    int g2 = i / FPc, f = i % FPc;
    float a = matt_W[(size_t)f * FPc + 2 * g2];
    float b = matt_W[(size_t)f * FPc + 2 * g2 + 1];
    mattp[(size_t)g2 * FPc + f] = packbf(a, b);
    return;
  }
  i -= nM;
  if (i < nW) {
    int j = i & 7, fl = (i >> 3) & 31, c = (i >> 8) & 3;
    int T = i >> 10;
    int kt = T % 7; T /= 7;
    int ft = T % 7; T /= 7;
    int g = T % 6;  int r = T / 6;
    int f = ft * 32 + fl, k = kt * 32 + c * 8 + j;
    float v = 0.f;
    if (f < FPc && k < FPc) {
      if (g < 3) v = gru_Wih[((size_t)r * 3 * FPc + g * FPc + f) * FPc + k];
      else       v = gru_Whh[((size_t)r * 3 * FPc + (g - 3) * FPc + f) * FPc + k];
    }
    Wpk[i] = (__bf16)v;
    return;
  }
  i -= nW;
  if (i < nA) {
    int j = i & 7, fl = (i >> 3) & 31, c = (i >> 8) & 3;
    int T = i >> 10;
    int kt = T % 7; T /= 7;
    int ft = T % 7; int r = T / 7;
    int f = ft * 32 + fl, k = kt * 32 + c * 8 + j;
    float v = (f < FPc && k < FPc) ? attend_W[((size_t)r * FPc + f) * FPc + k] : 0.f;
    Apk[i] = (__bf16)v;
  }
}

// -------------------- generic small GEMM (f32): Yb[rows][200] bf16 -------------------
template<int KD>
__global__ __launch_bounds__(256) void gemm8x1(
    const float* __restrict__ X, const float* __restrict__ WT,
    __bf16* __restrict__ Yb) {
  constexpr int TR = 8, LDP = 12;
  __shared__ float xT[KD * LDP];
  const int row0 = blockIdx.x * TR;
  const int tid = threadIdx.x;
  for (int e = tid; e < TR * KD; e += 256) {
    int r = e / KD, g = e - r * KD;
    xT[g * LDP + r] = X[(size_t)row0 * KD + e];
  }
  __syncthreads();
  const int f = tid;
  if (f < FPc) {
    float acc[TR];
    #pragma unroll
    for (int r = 0; r < TR; ++r) acc[r] = 0.f;
    #pragma unroll 4
    for (int g = 0; g < KD; ++g) {
      float w = WT[(size_t)g * FPc + f];
      float4 x0 = *reinterpret_cast<const float4*>(&xT[g * LDP]);
      float4 x1 = *reinterpret_cast<const float4*>(&xT[g * LDP + 4]);
      acc[0] = fmaf(x0.x, w, acc[0]); acc[1] = fmaf(x0.y, w, acc[1]);
      acc[2] = fmaf(x0.z, w, acc[2]); acc[3] = fmaf(x0.w, w, acc[3]);
      acc[4] = fmaf(x1.x, w, acc[4]); acc[5] = fmaf(x1.y, w, acc[5]);
      acc[6] = fmaf(x1.z, w, acc[6]); acc[7] = fmaf(x1.w, w, acc[7]);
    }
    #pragma unroll
    for (int r = 0; r < TR; ++r)
      Yb[(size_t)(row0 + r) * FPc + f] = (__bf16)acc[r];
  }
}

// -------------------- fused atom_list GEMM: atom_fc + neighbor-P ---------------------
__global__ __launch_bounds__(256) void gemm_dual(
    const float* __restrict__ X, const float* __restrict__ W1T,
    const float* __restrict__ b1, const float* __restrict__ W2T,
    float* __restrict__ Yraw, __bf16* __restrict__ Hb, __bf16* __restrict__ Pb) {
  constexpr int KD = AFc, TR = 8, LDP = 12;
  __shared__ float xT[KD * LDP];
  const int row0 = blockIdx.x * TR;
  const int tid = threadIdx.x;
  for (int e = tid; e < TR * KD; e += 256) {
    int r = e / KD, g = e - r * KD;
    xT[g * LDP + r] = X[(size_t)row0 * KD + e];
  }
  __syncthreads();
  const int f = tid;
  if (f < FPc) {
    float a1[TR], a2[TR];
    #pragma unroll
    for (int r = 0; r < TR; ++r) { a1[r] = 0.f; a2[r] = 0.f; }
    #pragma unroll 2
    for (int g = 0; g < KD; ++g) {
      float w1 = W1T[(size_t)g * FPc + f];
      float w2 = W2T[(size_t)g * FPc + f];
      float4 x0 = *reinterpret_cast<const float4*>(&xT[g * LDP]);
      float4 x1 = *reinterpret_cast<const float4*>(&xT[g * LDP + 4]);
      float xs[8] = {x0.x, x0.y, x0.z, x0.w, x1.x, x1.y, x1.z, x1.w};
      #pragma unroll
      for (int r = 0; r < TR; ++r) {
        a1[r] = fmaf(xs[r], w1, a1[r]);
        a2[r] = fmaf(xs[r], w2, a2[r]);
      }
    }
    const float bf = b1[f];
    #pragma unroll
    for (int r = 0; r < TR; ++r) {
      float v = a1[r] + bf;
      Yraw[(size_t)(row0 + r) * FPc + f] = v;
      Hb[(size_t)(row0 + r) * KP + f] = (__bf16)leaky(v);
      Pb[(size_t)(row0 + r) * FPc + f] = (__bf16)a2[r];
    }
  } else if (f < KP) {
    #pragma unroll
    for (int r = 0; r < TR; ++r) Hb[(size_t)(row0 + r) * KP + f] = (__bf16)0.f;
  }
}

// -------------------- fused attend + GRU v2.1: SW hoisted to regs --------------------
__global__ __launch_bounds__(256, 2) void attgru_mfma(
    const __bf16* __restrict__ WNb, const __bf16* __restrict__ Apk,
    const float* __restrict__ attb, const float* __restrict__ SW,
    const __bf16* __restrict__ Hin, __bf16* __restrict__ Hout,
    const __bf16* __restrict__ Wpk,
    const float* __restrict__ bih, const float* __restrict__ bhh,
    float* __restrict__ actOut) {
  __shared__ __align__(16) __bf16 smem[40960];   // 81920 B
  __bf16* xcL = smem;                             // [wv4][kt7][1024] = 57344 B
  __bf16* Bs  = smem + 28672;                     // [buf2][g6][1024] = 24576 B
  const int tid = threadIdx.x, wv = tid >> 6, lane = tid & 63;
  const size_t row0 = (size_t)blockIdx.x * 128;
  const int fl = lane & 31;

  // SW for this wave's rows, rl-mapped (ft-invariant; broadcast loads, hoisted once)
  float swv[16];
  #pragma unroll
  for (int reg = 0; reg < 16; ++reg) {
    int rl = (reg & 3) + 8 * (reg >> 2) + 4 * (lane >> 5);
    swv[reg] = SW[row0 + wv * 32 + rl];
  }

  // ---- attend phase: xc = elu(WN @ attW.T + sumw*b) -> LDS (A-frag layout) ----
  {
    bf16x8 af[7][2];
    const __bf16* sw_ = WNb + (row0 + wv * 32 + fl) * KP + (lane >> 5) * 8;
    #pragma unroll
    for (int kt = 0; kt < 7; ++kt)
      #pragma unroll
      for (int h = 0; h < 2; ++h)
        af[kt][h] = *(const bf16x8*)(sw_ + kt * 32 + h * 16);

    const int xbase = wv * 7168 + ((fl >> 3) & 3) * 256 + (fl & 7);
    #pragma unroll
    for (int ft = 0; ft < 7; ++ft) {
      f32x16 acc = zero16();
      #pragma unroll
      for (int kt = 0; kt < 7; ++kt) {
        const __bf16* bt = Apk + ((size_t)ft * 7 + kt) * 1024 + lane * 8;
        bf16x8 b0 = *(const bf16x8*)(bt);
        bf16x8 b1 = *(const bf16x8*)(bt + 512);
        acc = __builtin_amdgcn_mfma_f32_32x32x16_bf16(af[kt][0], b0, acc, 0, 0, 0);
        acc = __builtin_amdgcn_mfma_f32_32x32x16_bf16(af[kt][1], b1, acc, 0, 0, 0);
      }
      const int f = ft * 32 + fl;
      const bool fok = f < FPc;
      const float bf = fok ? attb[f] : 0.f;
      #pragma unroll
      for (int reg = 0; reg < 16; ++reg) {
        int rl = (reg & 3) + 8 * (reg >> 2) + 4 * (lane >> 5);
        float v = fok ? eluf(acc[reg] + swv[reg] * bf) : 0.f;
        xcL[xbase + ft * 1024 + rl * 8] = (__bf16)v;
      }
    }
  }
  // (no barrier: each wave reads back only its own region; lgkmcnt orders LDS)

  // ---- h fragments into registers ----
  bf16x8 hf[7][2];
  {
    const __bf16* sh = Hin + (row0 + wv * 32 + fl) * KP + (lane >> 5) * 8;
    #pragma unroll
    for (int kt = 0; kt < 7; ++kt)
      #pragma unroll
      for (int h = 0; h < 2; ++h)
        hf[kt][h] = *(const bf16x8*)(sh + kt * 32 + h * 16);
  }

  auto stageB = [&](int ft, int kt, int buf) {
    #pragma unroll
    for (int m3 = 0; m3 < 3; ++m3) {
      int m = wv * 3 + m3;               // 0..11
      int g = m >> 1, half = m & 1;
      const __bf16* s = Wpk + ((size_t)(g * 7 + ft) * 7 + kt) * 1024 + half * 512 + lane * 8;
      glds16(s, Bs + buf * 6144 + g * 1024 + half * 512);
    }
  };
  stageB(0, 0, 0);

  f32x16 gacc[6];
  #pragma unroll
  for (int g = 0; g < 6; ++g) gacc[g] = zero16();

  for (int ft = 0; ft < 7; ++ft) {
    #pragma unroll
    for (int kt = 0; kt < 7; ++kt) {
      const int it = ft * 7 + kt;
      const int buf = it & 1;
      const int nft = (kt == 6) ? ft + 1 : ft;
      const int nkt = (kt == 6) ? 0 : kt + 1;
      __builtin_amdgcn_sched_barrier(0);
      if (it < 48) stageB(nft, nkt, buf ^ 1);
      else         stageB(6, 6, buf ^ 1);          // dummy: keep 3 outstanding
      __builtin_amdgcn_sched_barrier(0);
      asm volatile("s_waitcnt vmcnt(3)" ::: "memory");
      __builtin_amdgcn_sched_barrier(0);
      __builtin_amdgcn_s_barrier();
      __builtin_amdgcn_sched_barrier(0);
      #pragma unroll
      for (int h = 0; h < 2; ++h) {
        bf16x8 xch = *(const bf16x8*)(xcL + wv * 7168 + kt * 1024 + h * 512 + lane * 8);
        bf16x8 hh = hf[kt][h];
        const __bf16* bb = Bs + buf * 6144 + h * 512 + lane * 8;
        bf16x8 b0 = *(const bf16x8*)(bb);
        bf16x8 b1 = *(const bf16x8*)(bb + 1024);
        bf16x8 b2 = *(const bf16x8*)(bb + 2048);
        bf16x8 b3 = *(const bf16x8*)(bb + 3072);
        bf16x8 b4 = *(const bf16x8*)(bb + 4096);
        bf16x8 b5 = *(const bf16x8*)(bb + 5120);
        __builtin_amdgcn_s_setprio(1);
        gacc[0] = __builtin_amdgcn_mfma_f32_32x32x16_bf16(xch, b0, gacc[0], 0, 0, 0);
        gacc[1] = __builtin_amdgcn_mfma_f32_32x32x16_bf16(xch, b1, gacc[1], 0, 0, 0);
        gacc[2] = __builtin_amdgcn_mfma_f32_32x32x16_bf16(xch, b2, gacc[2], 0, 0, 0);
        gacc[3] = __builtin_amdgcn_mfma_f32_32x32x16_bf16(hh, b3, gacc[3], 0, 0, 0);
        gacc[4] = __builtin_amdgcn_mfma_f32_32x32x16_bf16(hh, b4, gacc[4], 0, 0, 0);
        gacc[5] = __builtin_amdgcn_mfma_f32_32x32x16_bf16(hh, b5, gacc[5], 0, 0, 0);
        __builtin_amdgcn_s_setprio(0);
      }
      if (kt == 6) {
        const int f = ft * 32 + fl;
        const bool fok = f < FPc;
        float bir = 0, biz = 0, bin_ = 0, bhr = 0, bhz = 0, bhn = 0;
        if (fok) {
          bir = bih[f]; biz = bih[FPc + f]; bin_ = bih[2 * FPc + f];
          bhr = bhh[f]; bhz = bhh[FPc + f]; bhn = bhh[2 * FPc + f];
        }
        #pragma unroll
        for (int reg = 0; reg < 16; ++reg) {
          int rl = (reg & 3) + 8 * (reg >> 2) + 4 * (lane >> 5);
          size_t row = row0 + wv * 32 + rl;
          if (fok) {
            float ho = (float)Hin[row * KP + f];
            float rg_ = sigm(gacc[0][reg] + bir + gacc[3][reg] + bhr);
            float zg  = sigm(gacc[1][reg] + biz + gacc[4][reg] + bhz);
            float ng  = tanhf(gacc[2][reg] + bin_ + rg_ * (gacc[5][reg] + bhn));
            float hp = (1.f - zg) * ng + zg * ho;
            Hout[row * KP + f] = (__bf16)hp;
            actOut[row * FPc + f] = fmaxf(hp, 0.f);
          } else {
            Hout[row * KP + f] = (__bf16)0.f;
          }
        }
        #pragma unroll
        for (int g = 0; g < 6; ++g) gacc[g] = zero16();
      }
      __builtin_amdgcn_sched_barrier(0);
      __builtin_amdgcn_s_barrier();
      __builtin_amdgcn_sched_barrier(0);
    }
  }
}

// -------------------- attn round r>=1: per-molecule, 8 waves ------------------------
__global__ __launch_bounds__(512) void attn_molN(
    const __bf16* __restrict__ Hb, const int* __restrict__ adl,
    const float* __restrict__ alW, const float* __restrict__ albp,
    float* __restrict__ attnOut, __bf16* __restrict__ WNb, float* __restrict__ SW) {
  __shared__ __align__(16) __bf16 actL[128 * 224];
  __shared__ float saL[128], snL[128];
  const int b = blockIdx.x;
  const int tid = threadIdx.x, wv = tid >> 6, lane = tid & 63;
  const bool l36 = lane < 36;

  {
    const uint4* src = (const uint4*)(Hb + (size_t)b * 128 * KP);
    uint4* dst = (uint4*)actL;
    for (int i = tid; i < 128 * 224 / 8; i += 512) {
      uint4 v = src[i];
      uint32_t c[4] = {v.x, v.y, v.z, v.w};
      #pragma unroll
      for (int j = 0; j < 4; ++j) {
        uint32_t lo = c[j] & 0xffffu, hi = c[j] >> 16;
        if (lo & 0x8000u) lo = 0;
        if (hi & 0x8000u) hi = 0;
        c[j] = lo | (hi << 16);
      }
      dst[i] = make_uint4(c[0], c[1], c[2], c[3]);
    }
  }
  float wa0x = alW[2 * lane], wa0y = alW[2 * lane + 1];
  float wa1x = l36 ? alW[128 + 2 * lane] : 0.f, wa1y = l36 ? alW[129 + 2 * lane] : 0.f;
  float wn0x = alW[FPc + 2 * lane], wn0y = alW[FPc + 2 * lane + 1];
  float wn1x = l36 ? alW[FPc + 128 + 2 * lane] : 0.f, wn1y = l36 ? alW[FPc + 129 + 2 * lane] : 0.f;
  const float ab = albp[0];
  __syncthreads();

  for (int i = 0; i < 16; ++i) {
    int l = wv * 16 + i;
    const uint32_t* rowp = (const uint32_t*)(actL + l * 224);
    uint32_t u0 = rowp[lane];
    uint32_t u1 = l36 ? rowp[64 + lane] : 0u;
    float x0 = bflo(u0), y0 = bfhi(u0), x1 = bflo(u1), y1 = bfhi(u1);
    float psa = x0 * wa0x + y0 * wa0y + x1 * wa1x + y1 * wa1y;
    float psn = x0 * wn0x + y0 * wn0y + x1 * wn1x + y1 * wn1y;
    psa = wave_sum(psa);
    psn = wave_sum(psn);
    if (lane == 0) { saL[l] = psa; snL[l] = psn; }
  }
  __syncthreads();

  for (int i = 0; i < 16; ++i) {
    const int row = wv * 16 + i;
    const size_t grow = (size_t)b * 128 + row;
    int gk = (lane < Kc) ? adl[grow * Kc + lane] : 0;
    int ai[Kc];
    #pragma unroll
    for (int k = 0; k < Kc; ++k) ai[k] = __shfl(gk, k);
    const float sarow = saL[row];
    float s[Kc]; bool pad[Kc]; float mx = -3.0e38f;
    #pragma unroll
    for (int k = 0; k < Kc; ++k) {
      pad[k] = (ai[k] == Lc - 1);
      s[k] = leaky(sarow + snL[ai[k]] + ab) + (pad[k] ? NEGC : 0.f);
      mx = fmaxf(mx, s[k]);
    }
    float e[Kc], sum = 0.f;
    #pragma unroll
    for (int k = 0; k < Kc; ++k) { e[k] = __expf(s[k] - mx); sum += e[k]; }
    float inv = 1.f / sum;
    float w[Kc], sw = 0.f;
    #pragma unroll
    for (int k = 0; k < Kc; ++k) { w[k] = pad[k] ? 0.f : e[k] * inv; sw += w[k]; }
    if (lane < Kc) attnOut[grow * Kc + lane] = w[lane];
    if (lane == 0) SW[grow] = sw;
    float a0 = 0.f, b0 = 0.f, a1 = 0.f, b1 = 0.f;
    #pragma unroll
    for (int k = 0; k < Kc; ++k) {
      const uint32_t* nr = (const uint32_t*)(actL + ai[k] * 224);
      uint32_t u0 = nr[lane];
      uint32_t u1 = l36 ? nr[64 + lane] : 0u;
      a0 = fmaf(w[k], bflo(u0), a0); b0 = fmaf(w[k], bfhi(u0), b0);
      a1 = fmaf(w[k], bflo(u1), a1); b1 = fmaf(w[k], bfhi(u1), b1);
    }
    __bf16* wr = WNb + grow * KP;
    ushort2 o0; o0.x = f2bu(a0); o0.y = f2bu(b0);
    *(ushort2*)(wr + 2 * lane) = o0;
    if (lane < 48) {
      float va = l36 ? a1 : 0.f, vb = l36 ? b1 : 0.f;
      ushort2 o1; o1.x = f2bu(va); o1.y = f2bu(vb);
      *(ushort2*)(wr + 128 + 2 * lane) = o1;
    }
  }
}

// -------------------- attn round r==0: per-molecule block, 8 waves, v-reg cache -----
__global__ __launch_bounds__(512) void attn_mol0(
    const __bf16* __restrict__ Pb, const __bf16* __restrict__ Qb,
    const float* __restrict__ nbb, const __bf16* __restrict__ Hb0,
    const int* __restrict__ adl, const int* __restrict__ bdl,
    const float* __restrict__ alW, const float* __restrict__ albp,
    float* __restrict__ attnOut, __bf16* __restrict__ WNb, float* __restrict__ SW) {
  __shared__ __align__(16) __bf16 Pl[128 * 200];
  __shared__ __align__(16) __bf16 Ql[128 * 200];
  __shared__ float nbbL[200];
  __shared__ float saL[128];
  const int b = blockIdx.x;
  const int tid = threadIdx.x, wv = tid >> 6, lane = tid & 63;
  const bool l36 = lane < 36;

  {
    const uint4* sp = (const uint4*)(Pb + (size_t)b * 128 * FPc);
    const uint4* sq = (const uint4*)(Qb + (size_t)b * 128 * FPc);
    uint4* dp = (uint4*)Pl;
    uint4* dq = (uint4*)Ql;
    for (int i = tid; i < 128 * 200 / 8; i += 512) { dp[i] = sp[i]; dq[i] = sq[i]; }
    for (int i = tid; i < FPc; i += 512) nbbL[i] = nbb[i];
  }
  float wa0x = alW[2 * lane], wa0y = alW[2 * lane + 1];
  float wa1x = l36 ? alW[128 + 2 * lane] : 0.f, wa1y = l36 ? alW[129 + 2 * lane] : 0.f;
  float wn0x = alW[FPc + 2 * lane], wn0y = alW[FPc + 2 * lane + 1];
  float wn1x = l36 ? alW[FPc + 128 + 2 * lane] : 0.f, wn1y = l36 ? alW[FPc + 129 + 2 * lane] : 0.f;
  const float ab = albp[0];

  for (int i = 0; i < 16; ++i) {
    int l = wv * 16 + i;
    const uint32_t* hr = (const uint32_t*)(Hb0 + ((size_t)b * 128 + l) * KP);
    uint32_t u0 = hr[lane];
    uint32_t u1 = l36 ? hr[64 + lane] : 0u;
    float psa = bflo(u0) * wa0x + bfhi(u0) * wa0y + bflo(u1) * wa1x + bfhi(u1) * wa1y;
    psa = wave_sum(psa);
    if (lane == 0) saL[l] = psa;
  }
  __syncthreads();

  const float n0x = nbbL[2 * lane], n0y = nbbL[2 * lane + 1];
  const float n1x = l36 ? nbbL[128 + 2 * lane] : 0.f, n1y = l36 ? nbbL[129 + 2 * lane] : 0.f;

  for (int i = 0; i < 16; ++i) {
    const int row = wv * 16 + i;
    const size_t grow = (size_t)b * 128 + row;
    int gk = (lane < Kc) ? adl[grow * Kc + lane] : 0;
    int hk = (lane < Kc) ? bdl[grow * Kc + lane] : 0;
    int ai[Kc], bi[Kc];
    #pragma unroll
    for (int k = 0; k < Kc; ++k) { ai[k] = __shfl(gk, k); bi[k] = __shfl(hk, k); }
    float v0x[Kc], v0y[Kc], v1x[Kc], v1y[Kc], p[Kc];
    #pragma unroll
    for (int k = 0; k < Kc; ++k) {
      const uint32_t* pr = (const uint32_t*)(Pl + ai[k] * 200);
      const uint32_t* qr = (const uint32_t*)(Ql + bi[k] * 200);
      uint32_t up0 = pr[lane], uq0 = qr[lane];
      uint32_t up1 = l36 ? pr[64 + lane] : 0u, uq1 = l36 ? qr[64 + lane] : 0u;
      v0x[k] = leaky(bflo(up0) + bflo(uq0) + n0x);
      v0y[k] = leaky(bfhi(up0) + bfhi(uq0) + n0y);
      v1x[k] = l36 ? leaky(bflo(up1) + bflo(uq1) + n1x) : 0.f;
      v1y[k] = l36 ? leaky(bfhi(up1) + bfhi(uq1) + n1y) : 0.f;
      p[k] = v0x[k] * wn0x + v0y[k] * wn0y + v1x[k] * wn1x + v1y[k] * wn1y;
    }
    #pragma unroll
    for (int k = 0; k < Kc; ++k) p[k] = wave_sum(p[k]);
    const float sarow = saL[row];
    float s[Kc]; bool pad[Kc]; float mx = -3.0e38f;
    #pragma unroll
    for (int k = 0; k < Kc; ++k) {
      pad[k] = (ai[k] == Lc - 1);
      s[k] = leaky(sarow + p[k] + ab) + (pad[k] ? NEGC : 0.f);
      mx = fmaxf(mx, s[k]);
    }
    float e[Kc], sum = 0.f;
    #pragma unroll
    for (int k = 0; k < Kc; ++k) { e[k] = __expf(s[k] - mx); sum += e[k]; }
    float inv = 1.f / sum;
    float w[Kc], sw = 0.f;
    #pragma unroll
    for (int k = 0; k < Kc; ++k) { w[k] = pad[k] ? 0.f : e[k] * inv; sw += w[k]; }
    if (lane < Kc) attnOut[grow * Kc + lane] = w[lane];
    if (lane == 0) SW[grow] = sw;
    float a0 = 0.f, b0v = 0.f, a1 = 0.f, b1v = 0.f;
    #pragma unroll
    for (int k = 0; k < Kc; ++k) {
      a0  = fmaf(w[k], v0x[k], a0);
      b0v = fmaf(w[k], v0y[k], b0v);
      a1  = fmaf(w[k], v1x[k], a1);
      b1v = fmaf(w[k], v1y[k], b1v);
    }
    __bf16* wr = WNb + grow * KP;
    ushort2 o0; o0.x = f2bu(a0); o0.y = f2bu(b0v);
    *(ushort2*)(wr + 2 * lane) = o0;
    if (lane < 48) {
      float va = l36 ? a1 : 0.f, vb = l36 ? b1v : 0.f;
      ushort2 o1; o1.x = f2bu(va); o1.y = f2bu(vb);
      *(ushort2*)(wr + 128 + 2 * lane) = o1;
    }
  }
}

// -------------------- fused mol phase v3: bf16-packed weights, sn hoisted ------------
__global__ __launch_bounds__(256) void mol_fused(
    const __bf16* __restrict__ Hb, const float* __restrict__ mask,
    const float* __restrict__ malW, const float* __restrict__ malb,
    const uint32_t* __restrict__ mattp, const float* __restrict__ matt_b,
    const uint32_t* __restrict__ mgpk,
    const float* __restrict__ mbih, const float* __restrict__ mbhh,
    const float* __restrict__ outW, const float* __restrict__ outb,
    float* __restrict__ MV, float* __restrict__ MU, float* __restrict__ MA,
    float* __restrict__ PRED) {
  const int b = blockIdx.x;
  __shared__ __align__(16) __bf16 actL[Lc * FPc];   // 51200 B
  __shared__ float mk[Lc];
  __shared__ float molf[FPc], actm[FPc], wact[FPc], ctx[FPc];
  __shared__ float snL[Lc], wl[Lc];
  __shared__ float red[4], red2[4];
  const int tid = threadIdx.x, wv = tid >> 6, lane = tid & 63;
  const bool l36 = lane < 36;

  for (int l = tid; l < Lc; l += 256) mk[l] = mask[b * Lc + l];
  __syncthreads();
  const int f = tid;
  if (f < FPc) {
    float s1 = 0.f, s2 = 0.f;
    for (int l = 0; l < Lc; ++l) {
      float m = mk[l];
      float h = (float)Hb[((size_t)b * Lc + l) * KP + f];
      float a = fmaxf(h, 0.f);
      actL[l * FPc + f] = (__bf16)a;
      s1 = fmaf(h, m, s1);
      s2 = fmaf(a, m, s2);
    }
    MU[b * FPc + f] = s1;
    MV[b * FPc + f] = s2;
    molf[f] = s2;
    actm[f] = fmaxf(s2, 0.f);
  }
  float wn0x = malW[FPc + 2 * lane], wn0y = malW[FPc + 2 * lane + 1];
  float wn1x = l36 ? malW[FPc + 128 + 2 * lane] : 0.f;
  float wn1y = l36 ? malW[FPc + 129 + 2 * lane] : 0.f;
  __syncthreads();

  // sn[l] is t-invariant (depends only on atom act) -> compute once
  for (int l = wv; l < Lc; l += 4) {
    const uint32_t* rowp = (const uint32_t*)(actL + l * FPc);
    uint32_t u0 = rowp[lane];
    uint32_t u1 = l36 ? rowp[64 + lane] : 0u;
    float p = bflo(u0) * wn0x + bfhi(u0) * wn0y + bflo(u1) * wn1x + bfhi(u1) * wn1y;
    p = wave_sum(p);
    if (lane == 0) snL[l] = p;
  }
  __syncthreads();

  for (int t = 0; t < Tc; ++t) {
    {
      float p = 0.f;
      for (int i = tid; i < FPc; i += 256) p = fmaf(actm[i], malW[i], p);
      p = wave_sum(p);
      if (lane == 0) red[wv] = p;
    }
    __syncthreads();
    const float sa = red[0] + red[1] + red[2] + red[3];
    const int l = tid;
    float sc = -3.0e38f, mval = 0.f;
    if (l < Lc) {
      mval = mk[l];
      sc = leaky(sa + snL[l] + malb[0]) + (mval == 0.f ? NEGC : 0.f);
    }
    float m = sc;
    #pragma unroll
    for (int o = 32; o >= 1; o >>= 1) m = fmaxf(m, __shfl_xor(m, o));
    if (lane == 0) red[wv] = m;
    __syncthreads();
    float mx = fmaxf(red[0], red[1]);
    float e = (l < Lc) ? __expf(sc - mx) : 0.f;
    float s = e;
    #pragma unroll
    for (int o = 32; o >= 1; o >>= 1) s += __shfl_xor(s, o);
    if (lane == 0) red2[wv] = s;
    __syncthreads();
    float tot = red2[0] + red2[1];
    float w = 0.f;
    if (l < Lc) {
      w = e / tot * mval;
      wl[l] = w;
      MA[(size_t)t * Bc * Lc + b * Lc + l] = w;
    }
    float swp = w;
    #pragma unroll
    for (int o = 32; o >= 1; o >>= 1) swp += __shfl_xor(swp, o);
    if (lane == 0) red[wv] = swp;
    __syncthreads();
    const float sumw = red[0] + red[1];
    if (f < FPc) {
      float a = 0.f;
      for (int l2 = 0; l2 < Lc; ++l2)
        a = fmaf(wl[l2], (float)actL[l2 * FPc + f], a);
      wact[f] = a;
    }
    __syncthreads();
    if (f < FPc) {
      float a = 0.f;
      #pragma unroll 8
      for (int g2 = 0; g2 < FPc / 2; ++g2) {
        uint32_t u = mattp[(size_t)g2 * FPc + f];
        a = fmaf(wact[2 * g2], bflo(u), a);
        a = fmaf(wact[2 * g2 + 1], bfhi(u), a);
      }
      ctx[f] = eluf(fmaf(sumw, matt_b[f], a));
    }
    __syncthreads();
    float hp = 0.f;
    if (f < FPc) {
      float air = mbih[f], aiz = mbih[FPc + f], ain = mbih[2 * FPc + f];
      float ahr = mbhh[f], ahz = mbhh[FPc + f], ahn = mbhh[2 * FPc + f];
      const uint32_t* p0 = mgpk + f;
      const uint32_t* p1 = mgpk + FPc * FPc + f;
      const uint32_t* p2 = mgpk + 2 * FPc * FPc + f;
      #pragma unroll 8
      for (int g = 0; g < FPc; ++g) {
        float xc = ctx[g], hx = molf[g];
        uint32_t u0 = p0[g * FPc], u1 = p1[g * FPc], u2 = p2[g * FPc];
        air = fmaf(xc, bflo(u0), air);
        aiz = fmaf(xc, bfhi(u0), aiz);
        ain = fmaf(xc, bflo(u1), ain);
        ahr = fmaf(hx, bfhi(u1), ahr);
        ahz = fmaf(hx, bflo(u2), ahz);
        ahn = fmaf(hx, bfhi(u2), ahn);
      }
      float rg = sigm(air + ahr);
      float zg = sigm(aiz + ahz);
      float ng = tanhf(fmaf(rg, ahn, ain));
      hp = (1.f - zg) * ng + zg * molf[f];
      MU[(size_t)(t + 1) * Bc * FPc + b * FPc + f] = hp;
      MV[(size_t)(t + 1) * Bc * FPc + b * FPc + f] = fmaxf(hp, 0.f);
    }
    __syncthreads();
    if (f < FPc) {
      molf[f] = hp;
      actm[f] = fmaxf(hp, 0.f);
    }
    __syncthreads();
  }
  {
    float p = 0.f;
    for (int i = tid; i < FPc; i += 256) p = fmaf(molf[i], outW[i], p);
    p = wave_sum(p);
    if (lane == 0) red[wv] = p;
    __syncthreads();
    if (tid == 0) PRED[b] = red[0] + red[1] + red[2] + red[3] + outb[0];
  }
}

extern "C" void kernel_launch(void* const* d_in, const int* in_sizes, int n_in,
                              void* d_out, int out_size, void* d_ws, size_t ws_size,
                              hipStream_t stream) {
  const float* atom_list = (const float*)d_in[0];
  const float* bond_list = (const float*)d_in[1];
  const int*   adl       = (const int*)d_in[2];
  const int*   bdl       = (const int*)d_in[3];
  const float* mask      = (const float*)d_in[4];
  const float* atom_fc_W = (const float*)d_in[5];
  const float* atom_fc_b = (const float*)d_in[6];
  const float* nb_W      = (const float*)d_in[7];
  const float* nb_b      = (const float*)d_in[8];
  const float* align_W   = (const float*)d_in[9];
  const float* align_b   = (const float*)d_in[10];
  const float* attend_W  = (const float*)d_in[11];
  const float* attend_b  = (const float*)d_in[12];
  const float* gru_Wih   = (const float*)d_in[13];
  const float* gru_Whh   = (const float*)d_in[14];
  const float* gru_bih   = (const float*)d_in[15];
  const float* gru_bhh   = (const float*)d_in[16];
  const float* mal_W     = (const float*)d_in[17];
  const float* mal_b     = (const float*)d_in[18];
  const float* matt_W    = (const float*)d_in[19];
  const float* matt_b    = (const float*)d_in[20];
  const float* mWih      = (const float*)d_in[21];
  const float* mWhh      = (const float*)d_in[22];
  const float* mbih      = (const float*)d_in[23];
  const float* mbhh      = (const float*)d_in[24];
  const float* out_W     = (const float*)d_in[25];
  const float* out_b     = (const float*)d_in[26];

  float* out  = (float*)d_out;
  float* AV   = out;                                  // (4,B,L,FP)
  float* ATTN = AV + (size_t)4 * BL * FPc;            // (3,B,L,K)
  float* MV   = ATTN + (size_t)Rc * BL * Kc;          // (3,B,FP)
  float* MU   = MV + (size_t)3 * Bc * FPc;            // (3,B,FP)
  float* MA   = MU + (size_t)3 * Bc * FPc;            // (2,B,L)
  float* PRED = MA + (size_t)Tc * Bc * Lc;            // (B,1)

  char* w = (char*)d_ws;
  __bf16* Hb0  = (__bf16*)w; w += (size_t)BL * KP * 2;
  __bf16* Hb1  = (__bf16*)w; w += (size_t)BL * KP * 2;
  __bf16* WNb  = (__bf16*)w; w += (size_t)BL * KP * 2;
  __bf16* Pb   = (__bf16*)w; w += (size_t)BL * FPc * 2;
  __bf16* Qb   = (__bf16*)w; w += (size_t)BL * FPc * 2;
  __bf16* Wpk  = (__bf16*)w; w += (size_t)Rc * 6 * 49 * 1024 * 2;
  __bf16* Apk  = (__bf16*)w; w += (size_t)Rc * 49 * 1024 * 2;
  float* SW    = (float*)w;  w += (size_t)BL * 4;
  float* atomfcT = (float*)w; w += (size_t)AFc * FPc * 4;
  float* naT     = (float*)w; w += (size_t)(AFc + BFc) * FPc * 4;
  uint32_t* mgpk = (uint32_t*)w; w += (size_t)3 * FPc * FPc * 4;
  uint32_t* mattp = (uint32_t*)w; w += (size_t)(FPc / 2) * FPc * 4;

  {
    const int nprep = FPc * AFc + FPc * (AFc + BFc) + 3 * FPc * FPc + (FPc / 2) * FPc
                    + Rc * 6 * 49 * 1024 + Rc * 49 * 1024;
    prep_k<<<(nprep + 255) / 256, 256, 0, stream>>>(
        atom_fc_W, nb_W, matt_W, mWih, mWhh, gru_Wih, gru_Whh, attend_W,
        atomfcT, naT, mgpk, mattp, Wpk, Apk);
  }

  gemm_dual<<<BL / 8, 256, 0, stream>>>(atom_list, atomfcT, atom_fc_b, naT, AV, Hb0, Pb);
  gemm8x1<BFc><<<BL / 8, 256, 0, stream>>>(bond_list, naT + AFc * FPc, Qb);

  __bf16* Hbuf[2] = {Hb0, Hb1};
  for (int r = 0; r < Rc; ++r) {
    if (r == 0) {
      attn_mol0<<<Bc, 512, 0, stream>>>(Pb, Qb, nb_b, Hb0, adl, bdl,
          align_W, align_b, ATTN, WNb, SW);
    } else {
      attn_molN<<<Bc, 512, 0, stream>>>(Hbuf[r & 1], adl,
          align_W + (size_t)r * 2 * FPc, align_b + r,
          ATTN + (size_t)r * BL * Kc, WNb, SW);
    }
    attgru_mfma<<<BL / 128, 256, 0, stream>>>(WNb, Apk + (size_t)r * 49 * 1024,
        attend_b + (size_t)r * FPc, SW,
        Hbuf[r & 1], Hbuf[(r + 1) & 1],
        Wpk + (size_t)r * 6 * 49 * 1024, gru_bih + (size_t)r * 3 * FPc, gru_bhh + (size_t)r * 3 * FPc,
        AV + (size_t)(r + 1) * BL * FPc);
  }

  mol_fused<<<Bc, 256, 0, stream>>>(Hbuf[Rc & 1], mask,
      mal_W, mal_b, mattp, matt_b, mgpk, mbih, mbhh, out_W, out_b,
      MV, MU, MA, PRED);
}

// Round 16
// 685.294 us; speedup vs baseline: 1.8711x; 1.0227x over previous
//
#include <hip/hip_runtime.h>
#include <stdint.h>

#define Bc 512
#define Lc 128
#define Kc 6
#define AFc 39
#define BFc 10
#define FPc 200
#define Rc 3
#define Tc 2
constexpr int BL = Bc * Lc;          // 65536
constexpr int KP = 224;              // padded K / F for MFMA
constexpr float SLOPE = 0.01f;
constexpr float NEGC = -9e8f;

typedef __attribute__((ext_vector_type(8))) __bf16 bf16x8;
typedef __attribute__((ext_vector_type(16))) float f32x16;

__device__ __forceinline__ float leaky(float x) { return x >= 0.f ? x : SLOPE * x; }
__device__ __forceinline__ float sigm(float x) { return 1.f / (1.f + __expf(-x)); }
__device__ __forceinline__ float eluf(float x) { return x > 0.f ? x : expm1f(x); }
__device__ __forceinline__ float wave_sum(float v) {
  #pragma unroll
  for (int m = 32; m >= 1; m >>= 1) v += __shfl_xor(v, m);
  return v;
}
__device__ __forceinline__ float bflo(uint32_t u) { return __uint_as_float(u << 16); }
__device__ __forceinline__ float bfhi(uint32_t u) { return __uint_as_float(u & 0xffff0000u); }
__device__ __forceinline__ unsigned short f2bu(float x) {
  __bf16 b = (__bf16)x;
  return __builtin_bit_cast(unsigned short, b);
}
__device__ __forceinline__ uint32_t packbf(float a, float b) {
  return (uint32_t)f2bu(a) | ((uint32_t)f2bu(b) << 16);
}
__device__ __forceinline__ void glds16(const void* g, void* l) {
  __builtin_amdgcn_global_load_lds((const __attribute__((address_space(1))) uint32_t*)g,
      (__attribute__((address_space(3))) uint32_t*)l, 16, 0, 0);
}
__device__ __forceinline__ f32x16 zero16() {
  f32x16 z;
  #pragma unroll
  for (int i = 0; i < 16; ++i) z[i] = 0.f;
  return z;
}

// -------------------- unified prep: transposes + weight packs ------------------------
__global__ void prep_k(
    const float* __restrict__ atom_fc_W, const float* __restrict__ nb_W,
    const float* __restrict__ matt_W, const float* __restrict__ mWih,
    const float* __restrict__ mWhh, const float* __restrict__ gru_Wih,
    const float* __restrict__ gru_Whh, const float* __restrict__ attend_W,
    float* __restrict__ atomfcT, float* __restrict__ naT,
    uint32_t* __restrict__ mgpk, uint32_t* __restrict__ mattp,
    __bf16* __restrict__ Wpk, __bf16* __restrict__ Apk) {
  int i = blockIdx.x * 256 + threadIdx.x;
  const int n0 = FPc * AFc, n1 = FPc * (AFc + BFc);
  const int nG = 3 * FPc * FPc, nM = (FPc / 2) * FPc;
  const int nW = Rc * 6 * 49 * 1024, nA = Rc * 49 * 1024;
  if (i < n0) { int r = i / AFc, c = i % AFc; atomfcT[c * FPc + r] = atom_fc_W[i]; return; }
  i -= n0;
  if (i < n1) { int r = i / (AFc + BFc), c = i % (AFc + BFc); naT[c * FPc + r] = nb_W[i]; return; }
  i -= n1;
  if (i < nG) {
    int p = i / (FPc * FPc); int rem = i % (FPc * FPc);
    int g = rem / FPc, f = rem % FPc;
    float a, b;
    if (p == 0) {        // {wi_r, wi_z}
      a = mWih[(size_t)(0 * FPc + f) * FPc + g];
      b = mWih[(size_t)(1 * FPc + f) * FPc + g];
    } else if (p == 1) { // {wi_n, wh_r}
      a = mWih[(size_t)(2 * FPc + f) * FPc + g];
      b = mWhh[(size_t)(0 * FPc + f) * FPc + g];
    } else {             // {wh_z, wh_n}
      a = mWhh[(size_t)(1 * FPc + f) * FPc + g];
      b = mWhh[(size_t)(2 * FPc + f) * FPc + g];
    }
    mgpk[(size_t)p * FPc * FPc + g * FPc + f] = packbf(a, b);
    return;
  }
  i -= nG;
  if (i < nM) {
    int g2 = i / FPc, f = i % FPc;
    float a = matt_W[(size_t)f * FPc + 2 * g2];
    float b = matt_W[(size_t)f * FPc + 2 * g2 + 1];
    mattp[(size_t)g2 * FPc + f] = packbf(a, b);
    return;
  }
  i -= nM;
  if (i < nW) {
    int j = i & 7, fl = (i >> 3) & 31, c = (i >> 8) & 3;
    int T = i >> 10;
    int kt = T % 7; T /= 7;
    int ft = T % 7; T /= 7;
    int g = T % 6;  int r = T / 6;
    int f = ft * 32 + fl, k = kt * 32 + c * 8 + j;
    float v = 0.f;
    if (f < FPc && k < FPc) {
      if (g < 3) v = gru_Wih[((size_t)r * 3 * FPc + g * FPc + f) * FPc + k];
      else       v = gru_Whh[((size_t)r * 3 * FPc + (g - 3) * FPc + f) * FPc + k];
    }
    Wpk[i] = (__bf16)v;
    return;
  }
  i -= nW;
  if (i < nA) {
    int j = i & 7, fl = (i >> 3) & 31, c = (i >> 8) & 3;
    int T = i >> 10;
    int kt = T % 7; T /= 7;
    int ft = T % 7; int r = T / 7;
    int f = ft * 32 + fl, k = kt * 32 + c * 8 + j;
    float v = (f < FPc && k < FPc) ? attend_W[((size_t)r * FPc + f) * FPc + k] : 0.f;
    Apk[i] = (__bf16)v;
  }
}

// -------------------- generic small GEMM (f32): Yb[rows][200] bf16 -------------------
template<int KD>
__global__ __launch_bounds__(256) void gemm8x1(
    const float* __restrict__ X, const float* __restrict__ WT,
    __bf16* __restrict__ Yb) {
  constexpr int TR = 8, LDP = 12;
  __shared__ float xT[KD * LDP];
  const int row0 = blockIdx.x * TR;
  const int tid = threadIdx.x;
  for (int e = tid; e < TR * KD; e += 256) {
    int r = e / KD, g = e - r * KD;
    xT[g * LDP + r] = X[(size_t)row0 * KD + e];
  }
  __syncthreads();
  const int f = tid;
  if (f < FPc) {
    float acc[TR];
    #pragma unroll
    for (int r = 0; r < TR; ++r) acc[r] = 0.f;
    #pragma unroll 4
    for (int g = 0; g < KD; ++g) {
      float w = WT[(size_t)g * FPc + f];
      float4 x0 = *reinterpret_cast<const float4*>(&xT[g * LDP]);
      float4 x1 = *reinterpret_cast<const float4*>(&xT[g * LDP + 4]);
      acc[0] = fmaf(x0.x, w, acc[0]); acc[1] = fmaf(x0.y, w, acc[1]);
      acc[2] = fmaf(x0.z, w, acc[2]); acc[3] = fmaf(x0.w, w, acc[3]);
      acc[4] = fmaf(x1.x, w, acc[4]); acc[5] = fmaf(x1.y, w, acc[5]);
      acc[6] = fmaf(x1.z, w, acc[6]); acc[7] = fmaf(x1.w, w, acc[7]);
    }
    #pragma unroll
    for (int r = 0; r < TR; ++r)
      Yb[(size_t)(row0 + r) * FPc + f] = (__bf16)acc[r];
  }
}

// -------------------- fused atom_list GEMM: atom_fc + neighbor-P ---------------------
__global__ __launch_bounds__(256) void gemm_dual(
    const float* __restrict__ X, const float* __restrict__ W1T,
    const float* __restrict__ b1, const float* __restrict__ W2T,
    float* __restrict__ Yraw, __bf16* __restrict__ Hb, __bf16* __restrict__ Pb) {
  constexpr int KD = AFc, TR = 8, LDP = 12;
  __shared__ float xT[KD * LDP];
  const int row0 = blockIdx.x * TR;
  const int tid = threadIdx.x;
  for (int e = tid; e < TR * KD; e += 256) {
    int r = e / KD, g = e - r * KD;
    xT[g * LDP + r] = X[(size_t)row0 * KD + e];
  }
  __syncthreads();
  const int f = tid;
  if (f < FPc) {
    float a1[TR], a2[TR];
    #pragma unroll
    for (int r = 0; r < TR; ++r) { a1[r] = 0.f; a2[r] = 0.f; }
    #pragma unroll 2
    for (int g = 0; g < KD; ++g) {
      float w1 = W1T[(size_t)g * FPc + f];
      float w2 = W2T[(size_t)g * FPc + f];
      float4 x0 = *reinterpret_cast<const float4*>(&xT[g * LDP]);
      float4 x1 = *reinterpret_cast<const float4*>(&xT[g * LDP + 4]);
      float xs[8] = {x0.x, x0.y, x0.z, x0.w, x1.x, x1.y, x1.z, x1.w};
      #pragma unroll
      for (int r = 0; r < TR; ++r) {
        a1[r] = fmaf(xs[r], w1, a1[r]);
        a2[r] = fmaf(xs[r], w2, a2[r]);
      }
    }
    const float bf = b1[f];
    #pragma unroll
    for (int r = 0; r < TR; ++r) {
      float v = a1[r] + bf;
      Yraw[(size_t)(row0 + r) * FPc + f] = v;
      Hb[(size_t)(row0 + r) * KP + f] = (__bf16)leaky(v);
      Pb[(size_t)(row0 + r) * FPc + f] = (__bf16)a2[r];
    }
  } else if (f < KP) {
    #pragma unroll
    for (int r = 0; r < TR; ++r) Hb[(size_t)(row0 + r) * KP + f] = (__bf16)0.f;
  }
}

// -------------------- fused attend + GRU v2.1: SW hoisted to regs --------------------
__global__ __launch_bounds__(256, 2) void attgru_mfma(
    const __bf16* __restrict__ WNb, const __bf16* __restrict__ Apk,
    const float* __restrict__ attb, const float* __restrict__ SW,
    const __bf16* __restrict__ Hin, __bf16* __restrict__ Hout,
    const __bf16* __restrict__ Wpk,
    const float* __restrict__ bih, const float* __restrict__ bhh,
    float* __restrict__ actOut) {
  __shared__ __align__(16) __bf16 smem[40960];   // 81920 B
  __bf16* xcL = smem;                             // [wv4][kt7][1024] = 57344 B
  __bf16* Bs  = smem + 28672;                     // [buf2][g6][1024] = 24576 B
  const int tid = threadIdx.x, wv = tid >> 6, lane = tid & 63;
  const size_t row0 = (size_t)blockIdx.x * 128;
  const int fl = lane & 31;

  // SW for this wave's rows, rl-mapped (ft-invariant; broadcast loads, hoisted once)
  float swv[16];
  #pragma unroll
  for (int reg = 0; reg < 16; ++reg) {
    int rl = (reg & 3) + 8 * (reg >> 2) + 4 * (lane >> 5);
    swv[reg] = SW[row0 + wv * 32 + rl];
  }

  // ---- attend phase: xc = elu(WN @ attW.T + sumw*b) -> LDS (A-frag layout) ----
  {
    bf16x8 af[7][2];
    const __bf16* sw_ = WNb + (row0 + wv * 32 + fl) * KP + (lane >> 5) * 8;
    #pragma unroll
    for (int kt = 0; kt < 7; ++kt)
      #pragma unroll
      for (int h = 0; h < 2; ++h)
        af[kt][h] = *(const bf16x8*)(sw_ + kt * 32 + h * 16);

    const int xbase = wv * 7168 + ((fl >> 3) & 3) * 256 + (fl & 7);
    #pragma unroll
    for (int ft = 0; ft < 7; ++ft) {
      f32x16 acc = zero16();
      #pragma unroll
      for (int kt = 0; kt < 7; ++kt) {
        const __bf16* bt = Apk + ((size_t)ft * 7 + kt) * 1024 + lane * 8;
        bf16x8 b0 = *(const bf16x8*)(bt);
        bf16x8 b1 = *(const bf16x8*)(bt + 512);
        acc = __builtin_amdgcn_mfma_f32_32x32x16_bf16(af[kt][0], b0, acc, 0, 0, 0);
        acc = __builtin_amdgcn_mfma_f32_32x32x16_bf16(af[kt][1], b1, acc, 0, 0, 0);
      }
      const int f = ft * 32 + fl;
      const bool fok = f < FPc;
      const float bf = fok ? attb[f] : 0.f;
      #pragma unroll
      for (int reg = 0; reg < 16; ++reg) {
        int rl = (reg & 3) + 8 * (reg >> 2) + 4 * (lane >> 5);
        float v = fok ? eluf(acc[reg] + swv[reg] * bf) : 0.f;
        xcL[xbase + ft * 1024 + rl * 8] = (__bf16)v;
      }
    }
  }
  // (no barrier: each wave reads back only its own region; lgkmcnt orders LDS)

  // ---- h fragments into registers ----
  bf16x8 hf[7][2];
  {
    const __bf16* sh = Hin + (row0 + wv * 32 + fl) * KP + (lane >> 5) * 8;
    #pragma unroll
    for (int kt = 0; kt < 7; ++kt)
      #pragma unroll
      for (int h = 0; h < 2; ++h)
        hf[kt][h] = *(const bf16x8*)(sh + kt * 32 + h * 16);
  }

  auto stageB = [&](int ft, int kt, int buf) {
    #pragma unroll
    for (int m3 = 0; m3 < 3; ++m3) {
      int m = wv * 3 + m3;               // 0..11
      int g = m >> 1, half = m & 1;
      const __bf16* s = Wpk + ((size_t)(g * 7 + ft) * 7 + kt) * 1024 + half * 512 + lane * 8;
      glds16(s, Bs + buf * 6144 + g * 1024 + half * 512);
    }
  };
  stageB(0, 0, 0);

  f32x16 gacc[6];
  #pragma unroll
  for (int g = 0; g < 6; ++g) gacc[g] = zero16();

  for (int ft = 0; ft < 7; ++ft) {
    #pragma unroll
    for (int kt = 0; kt < 7; ++kt) {
      const int it = ft * 7 + kt;
      const int buf = it & 1;
      const int nft = (kt == 6) ? ft + 1 : ft;
      const int nkt = (kt == 6) ? 0 : kt + 1;
      __builtin_amdgcn_sched_barrier(0);
      if (it < 48) stageB(nft, nkt, buf ^ 1);
      else         stageB(6, 6, buf ^ 1);          // dummy: keep 3 outstanding
      __builtin_amdgcn_sched_barrier(0);
      asm volatile("s_waitcnt vmcnt(3)" ::: "memory");
      __builtin_amdgcn_sched_barrier(0);
      __builtin_amdgcn_s_barrier();
      __builtin_amdgcn_sched_barrier(0);
      #pragma unroll
      for (int h = 0; h < 2; ++h) {
        bf16x8 xch = *(const bf16x8*)(xcL + wv * 7168 + kt * 1024 + h * 512 + lane * 8);
        bf16x8 hh = hf[kt][h];
        const __bf16* bb = Bs + buf * 6144 + h * 512 + lane * 8;
        bf16x8 b0 = *(const bf16x8*)(bb);
        bf16x8 b1 = *(const bf16x8*)(bb + 1024);
        bf16x8 b2 = *(const bf16x8*)(bb + 2048);
        bf16x8 b3 = *(const bf16x8*)(bb + 3072);
        bf16x8 b4 = *(const bf16x8*)(bb + 4096);
        bf16x8 b5 = *(const bf16x8*)(bb + 5120);
        __builtin_amdgcn_s_setprio(1);
        gacc[0] = __builtin_amdgcn_mfma_f32_32x32x16_bf16(xch, b0, gacc[0], 0, 0, 0);
        gacc[1] = __builtin_amdgcn_mfma_f32_32x32x16_bf16(xch, b1, gacc[1], 0, 0, 0);
        gacc[2] = __builtin_amdgcn_mfma_f32_32x32x16_bf16(xch, b2, gacc[2], 0, 0, 0);
        gacc[3] = __builtin_amdgcn_mfma_f32_32x32x16_bf16(hh, b3, gacc[3], 0, 0, 0);
        gacc[4] = __builtin_amdgcn_mfma_f32_32x32x16_bf16(hh, b4, gacc[4], 0, 0, 0);
        gacc[5] = __builtin_amdgcn_mfma_f32_32x32x16_bf16(hh, b5, gacc[5], 0, 0, 0);
        __builtin_amdgcn_s_setprio(0);
      }
      if (kt == 6) {
        const int f = ft * 32 + fl;
        const bool fok = f < FPc;
        float bir = 0, biz = 0, bin_ = 0, bhr = 0, bhz = 0, bhn = 0;
        if (fok) {
          bir = bih[f]; biz = bih[FPc + f]; bin_ = bih[2 * FPc + f];
          bhr = bhh[f]; bhz = bhh[FPc + f]; bhn = bhh[2 * FPc + f];
        }
        #pragma unroll
        for (int reg = 0; reg < 16; ++reg) {
          int rl = (reg & 3) + 8 * (reg >> 2) + 4 * (lane >> 5);
          size_t row = row0 + wv * 32 + rl;
          if (fok) {
            float ho = (float)Hin[row * KP + f];
            float rg_ = sigm(gacc[0][reg] + bir + gacc[3][reg] + bhr);
            float zg  = sigm(gacc[1][reg] + biz + gacc[4][reg] + bhz);
            float ng  = tanhf(gacc[2][reg] + bin_ + rg_ * (gacc[5][reg] + bhn));
            float hp = (1.f - zg) * ng + zg * ho;
            Hout[row * KP + f] = (__bf16)hp;
            actOut[row * FPc + f] = fmaxf(hp, 0.f);
          } else {
            Hout[row * KP + f] = (__bf16)0.f;
          }
        }
        #pragma unroll
        for (int g = 0; g < 6; ++g) gacc[g] = zero16();
      }
      __builtin_amdgcn_sched_barrier(0);
      __builtin_amdgcn_s_barrier();
      __builtin_amdgcn_sched_barrier(0);
    }
  }
}

// -------------------- attn round r>=1: per-molecule, 8 waves ------------------------
__global__ __launch_bounds__(512) void attn_molN(
    const __bf16* __restrict__ Hb, const int* __restrict__ adl,
    const float* __restrict__ alW, const float* __restrict__ albp,
    float* __restrict__ attnOut, __bf16* __restrict__ WNb, float* __restrict__ SW) {
  __shared__ __align__(16) __bf16 actL[128 * 224];
  __shared__ float saL[128], snL[128];
  const int b = blockIdx.x;
  const int tid = threadIdx.x, wv = tid >> 6, lane = tid & 63;
  const bool l36 = lane < 36;

  {
    const uint4* src = (const uint4*)(Hb + (size_t)b * 128 * KP);
    uint4* dst = (uint4*)actL;
    for (int i = tid; i < 128 * 224 / 8; i += 512) {
      uint4 v = src[i];
      uint32_t c[4] = {v.x, v.y, v.z, v.w};
      #pragma unroll
      for (int j = 0; j < 4; ++j) {
        uint32_t lo = c[j] & 0xffffu, hi = c[j] >> 16;
        if (lo & 0x8000u) lo = 0;
        if (hi & 0x8000u) hi = 0;
        c[j] = lo | (hi << 16);
      }
      dst[i] = make_uint4(c[0], c[1], c[2], c[3]);
    }
  }
  float wa0x = alW[2 * lane], wa0y = alW[2 * lane + 1];
  float wa1x = l36 ? alW[128 + 2 * lane] : 0.f, wa1y = l36 ? alW[129 + 2 * lane] : 0.f;
  float wn0x = alW[FPc + 2 * lane], wn0y = alW[FPc + 2 * lane + 1];
  float wn1x = l36 ? alW[FPc + 128 + 2 * lane] : 0.f, wn1y = l36 ? alW[FPc + 129 + 2 * lane] : 0.f;
  const float ab = albp[0];
  __syncthreads();

  for (int i = 0; i < 16; ++i) {
    int l = wv * 16 + i;
    const uint32_t* rowp = (const uint32_t*)(actL + l * 224);
    uint32_t u0 = rowp[lane];
    uint32_t u1 = l36 ? rowp[64 + lane] : 0u;
    float x0 = bflo(u0), y0 = bfhi(u0), x1 = bflo(u1), y1 = bfhi(u1);
    float psa = x0 * wa0x + y0 * wa0y + x1 * wa1x + y1 * wa1y;
    float psn = x0 * wn0x + y0 * wn0y + x1 * wn1x + y1 * wn1y;
    psa = wave_sum(psa);
    psn = wave_sum(psn);
    if (lane == 0) { saL[l] = psa; snL[l] = psn; }
  }
  __syncthreads();

  for (int i = 0; i < 16; ++i) {
    const int row = wv * 16 + i;
    const size_t grow = (size_t)b * 128 + row;
    int gk = (lane < Kc) ? adl[grow * Kc + lane] : 0;
    int ai[Kc];
    #pragma unroll
    for (int k = 0; k < Kc; ++k) ai[k] = __shfl(gk, k);
    const float sarow = saL[row];
    float s[Kc]; bool pad[Kc]; float mx = -3.0e38f;
    #pragma unroll
    for (int k = 0; k < Kc; ++k) {
      pad[k] = (ai[k] == Lc - 1);
      s[k] = leaky(sarow + snL[ai[k]] + ab) + (pad[k] ? NEGC : 0.f);
      mx = fmaxf(mx, s[k]);
    }
    float e[Kc], sum = 0.f;
    #pragma unroll
    for (int k = 0; k < Kc; ++k) { e[k] = __expf(s[k] - mx); sum += e[k]; }
    float inv = 1.f / sum;
    float w[Kc], sw = 0.f;
    #pragma unroll
    for (int k = 0; k < Kc; ++k) { w[k] = pad[k] ? 0.f : e[k] * inv; sw += w[k]; }
    if (lane < Kc) attnOut[grow * Kc + lane] = w[lane];
    if (lane == 0) SW[grow] = sw;
    float a0 = 0.f, b0 = 0.f, a1 = 0.f, b1 = 0.f;
    #pragma unroll
    for (int k = 0; k < Kc; ++k) {
      const uint32_t* nr = (const uint32_t*)(actL + ai[k] * 224);
      uint32_t u0 = nr[lane];
      uint32_t u1 = l36 ? nr[64 + lane] : 0u;
      a0 = fmaf(w[k], bflo(u0), a0); b0 = fmaf(w[k], bfhi(u0), b0);
      a1 = fmaf(w[k], bflo(u1), a1); b1 = fmaf(w[k], bfhi(u1), b1);
    }
    __bf16* wr = WNb + grow * KP;
    ushort2 o0; o0.x = f2bu(a0); o0.y = f2bu(b0);
    *(ushort2*)(wr + 2 * lane) = o0;
    if (lane < 48) {
      float va = l36 ? a1 : 0.f, vb = l36 ? b1 : 0.f;
      ushort2 o1; o1.x = f2bu(va); o1.y = f2bu(vb);
      *(ushort2*)(wr + 128 + 2 * lane) = o1;
    }
  }
}

// -------------------- attn round r==0: per-molecule block, 8 waves, v-reg cache -----
__global__ __launch_bounds__(512) void attn_mol0(
    const __bf16* __restrict__ Pb, const __bf16* __restrict__ Qb,
    const float* __restrict__ nbb, const __bf16* __restrict__ Hb0,
    const int* __restrict__ adl, const int* __restrict__ bdl,
    const float* __restrict__ alW, const float* __restrict__ albp,
    float* __restrict__ attnOut, __bf16* __restrict__ WNb, float* __restrict__ SW) {
  __shared__ __align__(16) __bf16 Pl[128 * 200];
  __shared__ __align__(16) __bf16 Ql[128 * 200];
  __shared__ float nbbL[200];
  __shared__ float saL[128];
  const int b = blockIdx.x;
  const int tid = threadIdx.x, wv = tid >> 6, lane = tid & 63;
  const bool l36 = lane < 36;

  {
    const uint4* sp = (const uint4*)(Pb + (size_t)b * 128 * FPc);
    const uint4* sq = (const uint4*)(Qb + (size_t)b * 128 * FPc);
    uint4* dp = (uint4*)Pl;
    uint4* dq = (uint4*)Ql;
    for (int i = tid; i < 128 * 200 / 8; i += 512) { dp[i] = sp[i]; dq[i] = sq[i]; }
    for (int i = tid; i < FPc; i += 512) nbbL[i] = nbb[i];
  }
  float wa0x = alW[2 * lane], wa0y = alW[2 * lane + 1];
  float wa1x = l36 ? alW[128 + 2 * lane] : 0.f, wa1y = l36 ? alW[129 + 2 * lane] : 0.f;
  float wn0x = alW[FPc + 2 * lane], wn0y = alW[FPc + 2 * lane + 1];
  float wn1x = l36 ? alW[FPc + 128 + 2 * lane] : 0.f, wn1y = l36 ? alW[FPc + 129 + 2 * lane] : 0.f;
  const float ab = albp[0];

  for (int i = 0; i < 16; ++i) {
    int l = wv * 16 + i;
    const uint32_t* hr = (const uint32_t*)(Hb0 + ((size_t)b * 128 + l) * KP);
    uint32_t u0 = hr[lane];
    uint32_t u1 = l36 ? hr[64 + lane] : 0u;
    float psa = bflo(u0) * wa0x + bfhi(u0) * wa0y + bflo(u1) * wa1x + bfhi(u1) * wa1y;
    psa = wave_sum(psa);
    if (lane == 0) saL[l] = psa;
  }
  __syncthreads();

  const float n0x = nbbL[2 * lane], n0y = nbbL[2 * lane + 1];
  const float n1x = l36 ? nbbL[128 + 2 * lane] : 0.f, n1y = l36 ? nbbL[129 + 2 * lane] : 0.f;

  for (int i = 0; i < 16; ++i) {
    const int row = wv * 16 + i;
    const size_t grow = (size_t)b * 128 + row;
    int gk = (lane < Kc) ? adl[grow * Kc + lane] : 0;
    int hk = (lane < Kc) ? bdl[grow * Kc + lane] : 0;
    int ai[Kc], bi[Kc];
    #pragma unroll
    for (int k = 0; k < Kc; ++k) { ai[k] = __shfl(gk, k); bi[k] = __shfl(hk, k); }
    float v0x[Kc], v0y[Kc], v1x[Kc], v1y[Kc], p[Kc];
    #pragma unroll
    for (int k = 0; k < Kc; ++k) {
      const uint32_t* pr = (const uint32_t*)(Pl + ai[k] * 200);
      const uint32_t* qr = (const uint32_t*)(Ql + bi[k] * 200);
      uint32_t up0 = pr[lane], uq0 = qr[lane];
      uint32_t up1 = l36 ? pr[64 + lane] : 0u, uq1 = l36 ? qr[64 + lane] : 0u;
      v0x[k] = leaky(bflo(up0) + bflo(uq0) + n0x);
      v0y[k] = leaky(bfhi(up0) + bfhi(uq0) + n0y);
      v1x[k] = l36 ? leaky(bflo(up1) + bflo(uq1) + n1x) : 0.f;
      v1y[k] = l36 ? leaky(bfhi(up1) + bfhi(uq1) + n1y) : 0.f;
      p[k] = v0x[k] * wn0x + v0y[k] * wn0y + v1x[k] * wn1x + v1y[k] * wn1y;
    }
    #pragma unroll
    for (int k = 0; k < Kc; ++k) p[k] = wave_sum(p[k]);
    const float sarow = saL[row];
    float s[Kc]; bool pad[Kc]; float mx = -3.0e38f;
    #pragma unroll
    for (int k = 0; k < Kc; ++k) {
      pad[k] = (ai[k] == Lc - 1);
      s[k] = leaky(sarow + p[k] + ab) + (pad[k] ? NEGC : 0.f);
      mx = fmaxf(mx, s[k]);
    }
    float e[Kc], sum = 0.f;
    #pragma unroll
    for (int k = 0; k < Kc; ++k) { e[k] = __expf(s[k] - mx); sum += e[k]; }
    float inv = 1.f / sum;
    float w[Kc], sw = 0.f;
    #pragma unroll
    for (int k = 0; k < Kc; ++k) { w[k] = pad[k] ? 0.f : e[k] * inv; sw += w[k]; }
    if (lane < Kc) attnOut[grow * Kc + lane] = w[lane];
    if (lane == 0) SW[grow] = sw;
    float a0 = 0.f, b0v = 0.f, a1 = 0.f, b1v = 0.f;
    #pragma unroll
    for (int k = 0; k < Kc; ++k) {
      a0  = fmaf(w[k], v0x[k], a0);
      b0v = fmaf(w[k], v0y[k], b0v);
      a1  = fmaf(w[k], v1x[k], a1);
      b1v = fmaf(w[k], v1y[k], b1v);
    }
    __bf16* wr = WNb + grow * KP;
    ushort2 o0; o0.x = f2bu(a0); o0.y = f2bu(b0v);
    *(ushort2*)(wr + 2 * lane) = o0;
    if (lane < 48) {
      float va = l36 ? a1 : 0.f, vb = l36 ? b1v : 0.f;
      ushort2 o1; o1.x = f2bu(va); o1.y = f2bu(vb);
      *(ushort2*)(wr + 128 + 2 * lane) = o1;
    }
  }
}

// -------------------- fused mol phase v4: 512 thr, g-split GEMV/GRU ------------------
__global__ __launch_bounds__(512) void mol_fused(
    const __bf16* __restrict__ Hb, const float* __restrict__ mask,
    const float* __restrict__ malW, const float* __restrict__ malb,
    const uint32_t* __restrict__ mattp, const float* __restrict__ matt_b,
    const uint32_t* __restrict__ mgpk,
    const float* __restrict__ mbih, const float* __restrict__ mbhh,
    const float* __restrict__ outW, const float* __restrict__ outb,
    float* __restrict__ MV, float* __restrict__ MU, float* __restrict__ MA,
    float* __restrict__ PRED) {
  const int b = blockIdx.x;
  __shared__ __align__(16) __bf16 actL[Lc * FPc];   // 51200 B
  __shared__ float mk[Lc];
  __shared__ float molf[FPc], actm[FPc], wact[FPc], ctx[FPc];
  __shared__ float snL[Lc], wl[Lc];
  __shared__ float red[8], red2[8];
  __shared__ float sp1[2][FPc], sp2[2][FPc];
  __shared__ float wactp[FPc], ctxp[FPc];
  __shared__ float gp[FPc][6];
  const int tid = threadIdx.x, wv = tid >> 6, lane = tid & 63;
  const int half = tid >> 8;        // 0 or 1
  const int f = tid & 255;
  const bool fok = f < FPc;
  const bool l36 = lane < 36;

  for (int l = tid; l < Lc; l += 512) mk[l] = mask[b * Lc + l];
  __syncthreads();
  // staging split by l-half: act=relu(Hb) -> LDS + partial masked sums
  if (fok) {
    float s1 = 0.f, s2 = 0.f;
    for (int l = half * 64; l < half * 64 + 64; ++l) {
      float m = mk[l];
      float h = (float)Hb[((size_t)b * Lc + l) * KP + f];
      float a = fmaxf(h, 0.f);
      actL[l * FPc + f] = (__bf16)a;
      s1 = fmaf(h, m, s1);
      s2 = fmaf(a, m, s2);
    }
    sp1[half][f] = s1;
    sp2[half][f] = s2;
  }
  float wn0x = malW[FPc + 2 * lane], wn0y = malW[FPc + 2 * lane + 1];
  float wn1x = l36 ? malW[FPc + 128 + 2 * lane] : 0.f;
  float wn1y = l36 ? malW[FPc + 129 + 2 * lane] : 0.f;
  __syncthreads();
  if (fok && half == 0) {
    float s1 = sp1[0][f] + sp1[1][f];
    float s2 = sp2[0][f] + sp2[1][f];
    MU[b * FPc + f] = s1;
    MV[b * FPc + f] = s2;
    molf[f] = s2;
    actm[f] = fmaxf(s2, 0.f);
  }
  // sn[l] is t-invariant -> compute once (8 waves)
  for (int l = wv; l < Lc; l += 8) {
    const uint32_t* rowp = (const uint32_t*)(actL + l * FPc);
    uint32_t u0 = rowp[lane];
    uint32_t u1 = l36 ? rowp[64 + lane] : 0u;
    float p = bflo(u0) * wn0x + bfhi(u0) * wn0y + bflo(u1) * wn1x + bfhi(u1) * wn1y;
    p = wave_sum(p);
    if (lane == 0) snL[l] = p;
  }
  __syncthreads();

  for (int t = 0; t < Tc; ++t) {
    {
      float p = 0.f;
      for (int i = tid; i < FPc; i += 512) p = fmaf(actm[i], malW[i], p);
      p = wave_sum(p);
      if (lane == 0) red[wv] = p;
    }
    __syncthreads();
    float sa = 0.f;
    #pragma unroll
    for (int i = 0; i < 8; ++i) sa += red[i];
    const int l = tid;
    float sc = -3.0e38f, mval = 0.f;
    if (l < Lc) {
      mval = mk[l];
      sc = leaky(sa + snL[l] + malb[0]) + (mval == 0.f ? NEGC : 0.f);
    }
    float m = sc;
    #pragma unroll
    for (int o = 32; o >= 1; o >>= 1) m = fmaxf(m, __shfl_xor(m, o));
    if (lane == 0) red[wv] = m;
    __syncthreads();
    float mx = -3.0e38f;
    #pragma unroll
    for (int i = 0; i < 8; ++i) mx = fmaxf(mx, red[i]);
    float e = (l < Lc) ? __expf(sc - mx) : 0.f;
    float s = e;
    #pragma unroll
    for (int o = 32; o >= 1; o >>= 1) s += __shfl_xor(s, o);
    if (lane == 0) red2[wv] = s;
    __syncthreads();
    float tot = 0.f;
    #pragma unroll
    for (int i = 0; i < 8; ++i) tot += red2[i];
    float w = 0.f;
    if (l < Lc) {
      w = e / tot * mval;
      wl[l] = w;
      MA[(size_t)t * Bc * Lc + b * Lc + l] = w;
    }
    float swp = w;
    #pragma unroll
    for (int o = 32; o >= 1; o >>= 1) swp += __shfl_xor(swp, o);
    if (lane == 0) red[wv] = swp;
    __syncthreads();
    float sumw = 0.f;
    #pragma unroll
    for (int i = 0; i < 8; ++i) sumw += red[i];
    // wact split by l-half
    if (fok) {
      float a = 0.f;
      for (int l2 = half * 64; l2 < half * 64 + 64; ++l2)
        a = fmaf(wl[l2], (float)actL[l2 * FPc + f], a);
      if (half) wactp[f] = a; else wact[f] = a;
    }
    __syncthreads();
    if (fok && half == 0) wact[f] += wactp[f];
    __syncthreads();
    // ctx GEMV split by g-half (50 packed pairs each)
    float actx = 0.f;
    if (fok) {
      const int g20 = half * 50;
      #pragma unroll 5
      for (int g2 = g20; g2 < g20 + 50; ++g2) {
        uint32_t u = mattp[(size_t)g2 * FPc + f];
        actx = fmaf(wact[2 * g2], bflo(u), actx);
        actx = fmaf(wact[2 * g2 + 1], bfhi(u), actx);
      }
      if (half) ctxp[f] = actx;
    }
    __syncthreads();
    if (fok && half == 0)
      ctx[f] = eluf(fmaf(sumw, matt_b[f], actx + ctxp[f]));
    __syncthreads();
    // GRU split by g-half (100 each), partials combined by half 0
    float air = 0.f, aiz = 0.f, ain = 0.f, ahr = 0.f, ahz = 0.f, ahn = 0.f;
    if (fok) {
      const int g0 = half * 100;
      const uint32_t* p0 = mgpk + f;
      const uint32_t* p1 = mgpk + FPc * FPc + f;
      const uint32_t* p2 = mgpk + 2 * FPc * FPc + f;
      #pragma unroll 5
      for (int g = g0; g < g0 + 100; ++g) {
        float xc = ctx[g], hx = molf[g];
        uint32_t u0 = p0[g * FPc], u1 = p1[g * FPc], u2 = p2[g * FPc];
        air = fmaf(xc, bflo(u0), air);
        aiz = fmaf(xc, bfhi(u0), aiz);
        ain = fmaf(xc, bflo(u1), ain);
        ahr = fmaf(hx, bfhi(u1), ahr);
        ahz = fmaf(hx, bflo(u2), ahz);
        ahn = fmaf(hx, bfhi(u2), ahn);
      }
      if (half) {
        gp[f][0] = air; gp[f][1] = aiz; gp[f][2] = ain;
        gp[f][3] = ahr; gp[f][4] = ahz; gp[f][5] = ahn;
      }
    }
    __syncthreads();
    if (fok && half == 0) {
      air += gp[f][0] + mbih[f];
      aiz += gp[f][1] + mbih[FPc + f];
      ain += gp[f][2] + mbih[2 * FPc + f];
      ahr += gp[f][3] + mbhh[f];
      ahz += gp[f][4] + mbhh[FPc + f];
      ahn += gp[f][5] + mbhh[2 * FPc + f];
      float rg = sigm(air + ahr);
      float zg = sigm(aiz + ahz);
      float ng = tanhf(fmaf(rg, ahn, ain));
      float hp = (1.f - zg) * ng + zg * molf[f];
      MU[(size_t)(t + 1) * Bc * FPc + b * FPc + f] = hp;
      MV[(size_t)(t + 1) * Bc * FPc + b * FPc + f] = fmaxf(hp, 0.f);
      molf[f] = hp;
      actm[f] = fmaxf(hp, 0.f);
    }
    __syncthreads();
  }
  {
    float p = 0.f;
    for (int i = tid; i < FPc; i += 512) p = fmaf(molf[i], outW[i], p);
    p = wave_sum(p);
    if (lane == 0) red[wv] = p;
    __syncthreads();
    if (tid == 0) {
      float tot = 0.f;
      #pragma unroll
      for (int i = 0; i < 8; ++i) tot += red[i];
      PRED[b] = tot + outb[0];
    }
  }
}

extern "C" void kernel_launch(void* const* d_in, const int* in_sizes, int n_in,
                              void* d_out, int out_size, void* d_ws, size_t ws_size,
                              hipStream_t stream) {
  const float* atom_list = (const float*)d_in[0];
  const float* bond_list = (const float*)d_in[1];
  const int*   adl       = (const int*)d_in[2];
  const int*   bdl       = (const int*)d_in[3];
  const float* mask      = (const float*)d_in[4];
  const float* atom_fc_W = (const float*)d_in[5];
  const float* atom_fc_b = (const float*)d_in[6];
  const float* nb_W      = (const float*)d_in[7];
  const float* nb_b      = (const float*)d_in[8];
  const float* align_W   = (const float*)d_in[9];
  const float* align_b   = (const float*)d_in[10];
  const float* attend_W  = (const float*)d_in[11];
  const float* attend_b  = (const float*)d_in[12];
  const float* gru_Wih   = (const float*)d_in[13];
  const float* gru_Whh   = (const float*)d_in[14];
  const float* gru_bih   = (const float*)d_in[15];
  const float* gru_bhh   = (const float*)d_in[16];
  const float* mal_W     = (const float*)d_in[17];
  const float* mal_b     = (const float*)d_in[18];
  const float* matt_W    = (const float*)d_in[19];
  const float* matt_b    = (const float*)d_in[20];
  const float* mWih      = (const float*)d_in[21];
  const float* mWhh      = (const float*)d_in[22];
  const float* mbih      = (const float*)d_in[23];
  const float* mbhh      = (const float*)d_in[24];
  const float* out_W     = (const float*)d_in[25];
  const float* out_b     = (const float*)d_in[26];

  float* out  = (float*)d_out;
  float* AV   = out;                                  // (4,B,L,FP)
  float* ATTN = AV + (size_t)4 * BL * FPc;            // (3,B,L,K)
  float* MV   = ATTN + (size_t)Rc * BL * Kc;          // (3,B,FP)
  float* MU   = MV + (size_t)3 * Bc * FPc;            // (3,B,FP)
  float* MA   = MU + (size_t)3 * Bc * FPc;            // (2,B,L)
  float* PRED = MA + (size_t)Tc * Bc * Lc;            // (B,1)

  char* w = (char*)d_ws;
  __bf16* Hb0  = (__bf16*)w; w += (size_t)BL * KP * 2;
  __bf16* Hb1  = (__bf16*)w; w += (size_t)BL * KP * 2;
  __bf16* WNb  = (__bf16*)w; w += (size_t)BL * KP * 2;
  __bf16* Pb   = (__bf16*)w; w += (size_t)BL * FPc * 2;
  __bf16* Qb   = (__bf16*)w; w += (size_t)BL * FPc * 2;
  __bf16* Wpk  = (__bf16*)w; w += (size_t)Rc * 6 * 49 * 1024 * 2;
  __bf16* Apk  = (__bf16*)w; w += (size_t)Rc * 49 * 1024 * 2;
  float* SW    = (float*)w;  w += (size_t)BL * 4;
  float* atomfcT = (float*)w; w += (size_t)AFc * FPc * 4;
  float* naT     = (float*)w; w += (size_t)(AFc + BFc) * FPc * 4;
  uint32_t* mgpk = (uint32_t*)w; w += (size_t)3 * FPc * FPc * 4;
  uint32_t* mattp = (uint32_t*)w; w += (size_t)(FPc / 2) * FPc * 4;

  {
    const int nprep = FPc * AFc + FPc * (AFc + BFc) + 3 * FPc * FPc + (FPc / 2) * FPc
                    + Rc * 6 * 49 * 1024 + Rc * 49 * 1024;
    prep_k<<<(nprep + 255) / 256, 256, 0, stream>>>(
        atom_fc_W, nb_W, matt_W, mWih, mWhh, gru_Wih, gru_Whh, attend_W,
        atomfcT, naT, mgpk, mattp, Wpk, Apk);
  }

  gemm_dual<<<BL / 8, 256, 0, stream>>>(atom_list, atomfcT, atom_fc_b, naT, AV, Hb0, Pb);
  gemm8x1<BFc><<<BL / 8, 256, 0, stream>>>(bond_list, naT + AFc * FPc, Qb);

  __bf16* Hbuf[2] = {Hb0, Hb1};
  for (int r = 0; r < Rc; ++r) {
    if (r == 0) {
      attn_mol0<<<Bc, 512, 0, stream>>>(Pb, Qb, nb_b, Hb0, adl, bdl,
          align_W, align_b, ATTN, WNb, SW);
    } else {
      attn_molN<<<Bc, 512, 0, stream>>>(Hbuf[r & 1], adl,
          align_W + (size_t)r * 2 * FPc, align_b + r,
          ATTN + (size_t)r * BL * Kc, WNb, SW);
    }
    attgru_mfma<<<BL / 128, 256, 0, stream>>>(WNb, Apk + (size_t)r * 49 * 1024,
        attend_b + (size_t)r * FPc, SW,
        Hbuf[r & 1], Hbuf[(r + 1) & 1],
        Wpk + (size_t)r * 6 * 49 * 1024, gru_bih + (size_t)r * 3 * FPc, gru_bhh + (size_t)r * 3 * FPc,
        AV + (size_t)(r + 1) * BL * FPc);
  }

  mol_fused<<<Bc, 512, 0, stream>>>(Hbuf[Rc & 1], mask,
      mal_W, mal_b, mattp, matt_b, mgpk, mbih, mbhh, out_W, out_b,
      MV, MU, MA, PRED);
}